// Round 12
// baseline (499.079 us; speedup 1.0000x reference)
//
#include <hip/hip_runtime.h>
#include <math.h>

// ---------------------------------------------------------------------------
// ResCNN_ASP_SpeakerEncoder — v11 (resubmit; round-11 bench was an infra
// failure): conv2+conv3 fused (s lives only in LDS). Intermediates as bf16
// hi/lo planes; DMA staging; frag-order weights.
// ---------------------------------------------------------------------------

constexpr int B_  = 64;
constexpr int T_  = 3000;
constexpr int NB_ = 257;   // NBINS
constexpr int R_  = B_ * T_;           // 192000 rows
constexpr int NCH = 24;                // softmax T-chunks (24 x 128)
constexpr int CHL = 128;

// workspace layout (float offsets)
constexpr size_t OFF_BS    = 0;
constexpr size_t OFF_WEFF  = 128;                          // ushort hi[64*320]+lo
constexpr size_t OFF_WTAIL = OFF_WEFF + 20480;
constexpr size_t OFF_W1    = OFF_WTAIL + 128;              // ushort hi+lo 3*128*64
constexpr size_t OFF_W2    = OFF_W1  + 3*64*128;
constexpr size_t OFF_W3    = OFF_W2  + 3*128*128;
constexpr size_t OFF_WA1   = OFF_W3  + 3*128*128;
constexpr size_t OFF_WA2   = OFF_WA1 + 8192;
constexpr size_t SZ_P      = (size_t)B_*NCH*128;
constexpr size_t OFF_PM    = OFF_WA2 + 8192;
constexpr size_t OFF_PS    = OFF_PM  + SZ_P;
constexpr size_t OFF_MS    = OFF_PS  + SZ_P;
constexpr size_t OFF_SS    = OFF_MS  + (size_t)B_*128;
constexpr size_t OFF_PCM   = OFF_SS  + (size_t)B_*128;
constexpr size_t OFF_PCQ   = OFF_PCM + SZ_P;
// bf16 planes (ushort counts -> float counts /2)
constexpr size_t OFF_HH    = OFF_PCQ + SZ_P;               // h hi  [R*64]u
constexpr size_t OFF_HL    = OFF_HH  + (size_t)R_*32;      // h lo
constexpr size_t OFF_AH    = OFF_HL  + (size_t)R_*32;      // i1 hi [R*128]u
constexpr size_t OFF_AL    = OFF_AH  + (size_t)R_*64;
constexpr size_t OFF_BH    = OFF_AL  + (size_t)R_*64;      // i3 hi
constexpr size_t OFF_BL    = OFF_BH  + (size_t)R_*64;      // i3 lo

typedef __attribute__((ext_vector_type(8))) short  bf16x8;
typedef __attribute__((ext_vector_type(4))) float  f32x4;
typedef __attribute__((ext_vector_type(4), aligned(4))) float float4a;
typedef unsigned short ushort_t;

typedef __attribute__((address_space(3))) unsigned int        as3_u32;
typedef const __attribute__((address_space(1))) unsigned int  as1_u32c;
__device__ __forceinline__ void gload16(const void* g, void* l) {
    __builtin_amdgcn_global_load_lds((as1_u32c*)g, (as3_u32*)l, 16, 0, 0);
}

__device__ inline ushort_t f2bf(float f) {                // RNE f32->bf16
    unsigned u = __float_as_uint(f);
    unsigned r = u + 0x7FFFu + ((u >> 16) & 1u);
    return (ushort_t)(r >> 16);
}
__device__ inline float bf2f(ushort_t h) {
    return __uint_as_float(((unsigned)h) << 16);
}
__device__ inline void split2(float v, ushort_t &h, ushort_t &l) {
    h = f2bf(v);
    l = f2bf(v - bf2f(h));
}

// hw-packed split for lin1's fp32-input staging
__device__ inline void split_pack(float x, float y, float z, float w,
                                  uint2 &ph, uint2 &pl) {
    unsigned hx, hy;
    asm("v_cvt_pk_bf16_f32 %0, %1, %2" : "=v"(hx) : "v"(x), "v"(y));
    asm("v_cvt_pk_bf16_f32 %0, %1, %2" : "=v"(hy) : "v"(z), "v"(w));
    float l0 = x - __uint_as_float(hx << 16);
    float l1 = y - __uint_as_float(hx & 0xFFFF0000u);
    float l2 = z - __uint_as_float(hy << 16);
    float l3 = w - __uint_as_float(hy & 0xFFFF0000u);
    unsigned lx, ly;
    asm("v_cvt_pk_bf16_f32 %0, %1, %2" : "=v"(lx) : "v"(l0), "v"(l1));
    asm("v_cvt_pk_bf16_f32 %0, %1, %2" : "=v"(ly) : "v"(l2), "v"(l3));
    ph.x = hx; ph.y = hy; pl.x = lx; pl.y = ly;
}

// ---------------------------------------------------------------------------
__global__ void sort_kernel(const float* __restrict__ bp, float* __restrict__ bs) {
    if (threadIdx.x == 0) {
        float tmp[82];
        for (int i = 0; i < 82; ++i) tmp[i] = bp[i];
        for (int i = 1; i < 82; ++i) {
            float key = tmp[i];
            int j = i - 1;
            while (j >= 0 && tmp[j] > key) { tmp[j+1] = tmp[j]; --j; }
            tmp[j+1] = key;
        }
        for (int i = 0; i < 82; ++i) bs[i] = tmp[i];
    }
}

// Fragment-order packing (B: lane&15=col, lane>>4=k-octet; A: lane&15=row).
__global__ void prep_kernel(const float* __restrict__ bs, const float* __restrict__ wl1,
                            const float* __restrict__ wc1, const float* __restrict__ wc2,
                            const float* __restrict__ wc3, const float* __restrict__ wa1,
                            const float* __restrict__ wa2,
                            ushort_t* __restrict__ weh, ushort_t* __restrict__ wel,
                            float* __restrict__ wtail,
                            ushort_t* __restrict__ w1h, ushort_t* __restrict__ w1l,
                            ushort_t* __restrict__ w2h, ushort_t* __restrict__ w2l,
                            ushort_t* __restrict__ w3h, ushort_t* __restrict__ w3l,
                            ushort_t* __restrict__ wa1h, ushort_t* __restrict__ wa1l,
                            ushort_t* __restrict__ wa2h, ushort_t* __restrict__ wa2l) {
    int gid = blockIdx.x * 256 + threadIdx.x;
    if (gid < 64*320) {                            // Weff[o][f]
        int o = gid / 320, f = gid % 320;
        if (f > 256) return;
        float acc = 0.0f;
        if (f == 0) acc = wl1[o*80];               // filt[:,:,0] = x[:,:,0]
        else {
            for (int n = 1; n < 79; ++n) {
                float bn = bs[n], bn1 = bs[n+1], bn2 = bs[n+2];
                int ibn  = (int)floorf(bn);
                int ibn1 = (int)floorf(bn1);
                int ibn2 = (int)floorf(bn2);
                float fbv = 0.0f;
                if (f >= ibn && f < ibn1) {
                    float d = (bn1-bn)*(bn1-bn);
                    fbv = ((float)f - bn) / (d > 0.0f ? d : 1.0f);
                } else if (f >= ibn1 && f < ibn2) {
                    float d = (bn2-bn1)*(bn2-bn1);
                    fbv = (bn2 - (float)f) / (d > 0.0f ? d : 1.0f);
                }
                acc += wl1[o*80 + n] * fbv;
            }
        }
        if (f == 256) { wtail[o] = acc; return; }
        int kc = f >> 5, lane = ((f & 31) >> 3)*16 + (o & 15), e = f & 7;
        size_t dst = (((size_t)kc*4 + (o >> 4))*64 + lane)*8 + e;
        split2(acc, weh[dst], wel[dst]);
        return;
    }
    gid -= 64*320;
    if (gid < 3*128*64) {                          // conv1: [k][c][ci=64]
        int k = gid / (128*64), rem = gid % (128*64);
        int c = rem >> 6, ci = rem & 63;
        float v = wc1[(c*64 + ci)*3 + k];
        int lane = ((ci & 31) >> 3)*16 + (c & 15), e = ci & 7;
        size_t dst = ((((size_t)k*2 + (ci >> 5))*8 + (c >> 4))*64 + lane)*8 + e;
        split2(v, w1h[dst], w1l[dst]);
        return;
    }
    gid -= 3*128*64;
    if (gid < 3*128*128) {                         // conv2
        int k = gid / (128*128), rem = gid % (128*128);
        int c = rem >> 7, ci = rem & 127;
        float v = wc2[(c*128 + ci)*3 + k];
        int lane = ((ci & 31) >> 3)*16 + (c & 15), e = ci & 7;
        size_t dst = ((((size_t)k*4 + (ci >> 5))*8 + (c >> 4))*64 + lane)*8 + e;
        split2(v, w2h[dst], w2l[dst]);
        return;
    }
    gid -= 3*128*128;
    if (gid < 3*128*128) {                         // conv3
        int k = gid / (128*128), rem = gid % (128*128);
        int c = rem >> 7, ci = rem & 127;
        float v = wc3[(c*128 + ci)*3 + k];
        int lane = ((ci & 31) >> 3)*16 + (c & 15), e = ci & 7;
        size_t dst = ((((size_t)k*4 + (ci >> 5))*8 + (c >> 4))*64 + lane)*8 + e;
        split2(v, w3h[dst], w3l[dst]);
        return;
    }
    gid -= 3*128*128;
    if (gid < 64*128) {                            // wa1 [c=64][ci=128]
        int c = gid >> 7, ci = gid & 127;
        float v = wa1[gid];
        int lane = ((ci & 31) >> 3)*16 + (c & 15), e = ci & 7;
        size_t dst = (((size_t)(ci >> 5)*4 + (c >> 4))*64 + lane)*8 + e;
        split2(v, wa1h[dst], wa1l[dst]);
        return;
    }
    gid -= 64*128;
    if (gid < 128*64) {                            // wa2 [n=128][ci=64] (A op)
        int n = gid >> 6, ci = gid & 63;
        float v = wa2[gid];
        int lane = ((ci & 31) >> 3)*16 + (n & 15), e = ci & 7;
        size_t dst = (((size_t)(ci >> 5)*8 + (n >> 4))*64 + lane)*8 + e;
        split2(v, wa2h[dst], wa2l[dst]);
        return;
    }
}

// ---------------------------------------------------------------------------
// lin1: h = relu(x @ Weff^T + b); writes h as bf16 hi/lo planes.
__launch_bounds__(256)
__global__ void lin1_mfma(const float* __restrict__ X,
                          const ushort_t* __restrict__ Wh, const ushort_t* __restrict__ Wl,
                          const float* __restrict__ wtail,
                          const float* __restrict__ bias,
                          ushort_t* __restrict__ Hh, ushort_t* __restrict__ Hl) {
    __shared__ __align__(16) ushort_t ash[128*64];
    __shared__ __align__(16) ushort_t asl[128*64];
    __shared__ float xs[128];
    __shared__ float wts[64];
    const int tid  = threadIdx.x;
    const int lane = tid & 63;
    const int wid  = tid >> 6;
    const int wy   = wid >> 1, wx = wid & 1;
    const int l16  = lane & 15, l4 = lane >> 4;
    const int r0   = blockIdx.x * 128;

    if (tid < 128)       xs[tid] = X[(size_t)(r0 + tid)*NB_ + 256];
    else if (tid < 192)  wts[tid - 128] = wtail[tid - 128];

#define LIN1_LOAD(dst, k0)                                            \
    _Pragma("unroll")                                                 \
    for (int i = 0; i < 8; ++i) {                                     \
        int q = tid + i*256; int r = q >> 4, cc = (q & 15) << 2;      \
        dst[i] = *(const float4a*)(X + (size_t)(r0 + r)*NB_ + (k0) + cc); \
    }
#define LIN1_CW(src)                                                  \
    _Pragma("unroll")                                                 \
    for (int i = 0; i < 8; ++i) {                                     \
        int q = tid + i*256; int r = q >> 4, cc = (q & 15) << 2;      \
        uint2 ph, pl;                                                 \
        split_pack(src[i].x, src[i].y, src[i].z, src[i].w, ph, pl);   \
        unsigned byte = ((unsigned)(r*64 + cc))*2u ^ ((unsigned)((r & 7) << 4)); \
        *(uint2*)((char*)ash + byte) = ph;                            \
        *(uint2*)((char*)asl + byte) = pl;                            \
    }

    float4a bufA[8], bufB[8];
    LIN1_LOAD(bufA, 0);

    f32x4 acc[4][2];
    const f32x4 z = {0.f,0.f,0.f,0.f};
#pragma unroll
    for (int m = 0; m < 4; ++m) { acc[m][0] = z; acc[m][1] = z; }

#pragma unroll
    for (int ck = 0; ck < 4; ++ck) {
        const float4a* cur = (ck & 1) ? bufB : bufA;
        float4a*       nxt = (ck & 1) ? bufA : bufB;
        if (ck < 3) LIN1_LOAD(nxt, (ck + 1)*64);
        LIN1_CW(cur);
        __syncthreads();
#pragma unroll
        for (int kk = 0; kk < 64; kk += 32) {
            bf16x8 bh[2], bl[2];
#pragma unroll
            for (int n = 0; n < 2; ++n) {
                size_t off = (((size_t)(ck*2 + (kk >> 5))*4 + wx*2 + n)*64 + lane)*8;
                bh[n] = *(const bf16x8*)(Wh + off);
                bl[n] = *(const bf16x8*)(Wl + off);
            }
            bf16x8 fh[4], fl[4];
#pragma unroll
            for (int m = 0; m < 4; ++m) {
                int r = wy*64 + m*16 + l16;
                unsigned byte = ((unsigned)(r*64 + kk + l4*8))*2u ^ ((unsigned)((r & 7) << 4));
                fh[m] = *(const bf16x8*)((const char*)ash + byte);
                fl[m] = *(const bf16x8*)((const char*)asl + byte);
            }
#pragma unroll
            for (int m = 0; m < 4; ++m)
#pragma unroll
                for (int n = 0; n < 2; ++n) {
                    acc[m][n] = __builtin_amdgcn_mfma_f32_16x16x32_bf16(fh[m], bh[n], acc[m][n], 0, 0, 0);
                    acc[m][n] = __builtin_amdgcn_mfma_f32_16x16x32_bf16(fh[m], bl[n], acc[m][n], 0, 0, 0);
                    acc[m][n] = __builtin_amdgcn_mfma_f32_16x16x32_bf16(fl[m], bh[n], acc[m][n], 0, 0, 0);
                }
        }
        __syncthreads();
    }
#undef LIN1_LOAD
#undef LIN1_CW

#pragma unroll
    for (int m = 0; m < 4; ++m)
#pragma unroll
        for (int n = 0; n < 2; ++n) {
            int c = wx*32 + n*16 + l16;
            float bv = bias[c];
            float wc = wts[c];
            int rbl = wy*64 + m*16 + l4*4;
#pragma unroll
            for (int rg = 0; rg < 4; ++rg) {
                int rl = rbl + rg;
                float v = fmaxf(acc[m][n][rg] + bv + xs[rl]*wc, 0.0f);
                size_t o = (size_t)(r0 + rl)*64 + c;
                ushort_t h, l;
                split2(v, h, l);
                Hh[o] = h; Hl[o] = l;
            }
        }
}

// ---------------------------------------------------------------------------
// conv1 (CIN=64, DIL=2, no residual): planes in/out, DMA staging, TT=64.
__launch_bounds__(256, 4)
__global__ void dconv1_mfma(const ushort_t* __restrict__ Xh, const ushort_t* __restrict__ Xl,
                            const ushort_t* __restrict__ Wh, const ushort_t* __restrict__ Wl,
                            const float* __restrict__ bias,
                            ushort_t* __restrict__ Yh, ushort_t* __restrict__ Yl) {
    constexpr int CIN = 64, DIL = 2;
    constexpr int TT  = 64;
    constexpr int HS  = TT + 2*DIL;        // 68
    constexpr int NCK = HS*8;              // 16B chunks/plane (8 per row)
    constexpr int NCKP = ((NCK + 255)/256)*256;
    __shared__ __align__(16) ushort_t hsh[NCKP*8];
    __shared__ __align__(16) ushort_t hsl[NCKP*8];

    const int tid  = threadIdx.x;
    const int lane = tid & 63;
    const int wid  = tid >> 6;
    const int wy   = wid >> 1;
    const int wx   = wid & 1;
    const int l16  = lane & 15;
    const int l4   = lane >> 4;
    const int t0   = blockIdx.x * TT;
    const int b    = blockIdx.y;

    const long long rowbase = ((long long)b*T_ + (t0 - DIL)) * CIN;
    for (int c0 = wid*64; c0 < NCKP; c0 += 256) {
        int ck = c0 + lane;
        int r  = ck >> 3;
        int sc = ck ^ (r & 7);
        gload16(Xh + rowbase + (long long)sc*8, (char*)hsh + (size_t)c0*16);
        gload16(Xl + rowbase + (long long)sc*8, (char*)hsl + (size_t)c0*16);
    }
    __syncthreads();
    if (t0 < DIL || t0 + TT + DIL > T_) {
        for (int idx = tid; idx < HS*CIN/4; idx += 256) {
            int e = idx << 2;
            int r = e / CIN, ci = e % CIN;
            int t = t0 - DIL + r;
            if (t < 0 || t >= T_) {
                unsigned byte = ((unsigned)(r*CIN + ci))*2u ^ ((unsigned)((r & 7) << 4));
                *(uint2*)((char*)hsh + byte) = make_uint2(0u, 0u);
                *(uint2*)((char*)hsl + byte) = make_uint2(0u, 0u);
            }
        }
        __syncthreads();
    }

    f32x4 acc[2][4];
    const f32x4 z = {0.f, 0.f, 0.f, 0.f};
#pragma unroll
    for (int m = 0; m < 2; ++m)
#pragma unroll
        for (int n = 0; n < 4; ++n) acc[m][n] = z;

#pragma unroll
    for (int k = 0; k < 3; ++k) {
#pragma unroll
        for (int cb = 0; cb < 2; ++cb) {
            bf16x8 bh[4], bl[4];
#pragma unroll
            for (int n = 0; n < 4; ++n) {
                size_t off = ((((size_t)k*2 + cb)*8 + wx*4 + n)*64 + lane)*8;
                bh[n] = *(const bf16x8*)(Wh + off);
                bl[n] = *(const bf16x8*)(Wl + off);
            }
            bf16x8 ah[2], al[2];
#pragma unroll
            for (int m = 0; m < 2; ++m) {
                int r = wy*32 + m*16 + l16 + k*DIL;
                unsigned byte = ((unsigned)(r*CIN + cb*32 + l4*8))*2u
                              ^ ((unsigned)((r & 7) << 4));
                ah[m] = *(const bf16x8*)((const char*)hsh + byte);
                al[m] = *(const bf16x8*)((const char*)hsl + byte);
            }
#pragma unroll
            for (int m = 0; m < 2; ++m)
#pragma unroll
                for (int n = 0; n < 4; ++n) {
                    acc[m][n] = __builtin_amdgcn_mfma_f32_16x16x32_bf16(ah[m], bh[n], acc[m][n], 0, 0, 0);
                    acc[m][n] = __builtin_amdgcn_mfma_f32_16x16x32_bf16(ah[m], bl[n], acc[m][n], 0, 0, 0);
                    acc[m][n] = __builtin_amdgcn_mfma_f32_16x16x32_bf16(al[m], bh[n], acc[m][n], 0, 0, 0);
                }
        }
    }

#pragma unroll
    for (int m = 0; m < 2; ++m) {
        int tl_base = wy*32 + m*16 + l4*4;
#pragma unroll
        for (int n = 0; n < 4; ++n) {
            int c = wx*64 + n*16 + l16;
            float bv = bias[c];
#pragma unroll
            for (int rg = 0; rg < 4; ++rg) {
                int tl = tl_base + rg;
                int t  = t0 + tl;
                if (t < T_) {
                    float v = acc[m][n][rg] + bv;
                    size_t o = ((size_t)b*T_ + t)*128 + c;
                    ushort_t h, l;
                    split2(v, h, l);
                    Yh[o] = h; Yl[o] = l;
                }
            }
        }
    }
}

// ---------------------------------------------------------------------------
// Fused conv2+conv3: per (48-row tile, b): stage i1 rows [t0-8,t0+56),
// conv2 -> s (LDS only, identical split2 bf16), conv3 -> i3 planes.
__launch_bounds__(512, 4)
__global__ void dconv23_fused(const ushort_t* __restrict__ Xh, const ushort_t* __restrict__ Xl,
                              const ushort_t* __restrict__ W2h, const ushort_t* __restrict__ W2l,
                              const ushort_t* __restrict__ W3h, const ushort_t* __restrict__ W3l,
                              const float* __restrict__ bc2, const float* __restrict__ bc3,
                              ushort_t* __restrict__ Yh, ushort_t* __restrict__ Yl) {
    constexpr int TT = 48;
    // both buffers: local row 0 == global t = t0-8; 64 rows x 128 ch
    __shared__ __align__(16) ushort_t i1h[64*128];
    __shared__ __align__(16) ushort_t i1l[64*128];
    __shared__ __align__(16) ushort_t sh_[64*128];
    __shared__ __align__(16) ushort_t sl_[64*128];

    const int tid  = threadIdx.x;
    const int lane = tid & 63;
    const int wid  = tid >> 6;            // 0..7
    const int l16  = lane & 15, l4 = lane >> 4;
    const int t0   = blockIdx.x * TT;
    const int b    = blockIdx.y;

    // ---- stage i1 rows [t0-8, t0+56) via DMA (linear LDS, pre-swz source) ----
    const long long rowbase = ((long long)b*T_ + (t0 - 8)) * 128;
    for (int c0 = wid*64; c0 < 1024; c0 += 512) {
        int ck = c0 + lane;
        int r  = ck >> 4;
        int sc = ck ^ (r & 7);
        gload16(Xh + rowbase + (long long)sc*8, (char*)i1h + (size_t)c0*16);
        gload16(Xl + rowbase + (long long)sc*8, (char*)i1l + (size_t)c0*16);
    }
    __syncthreads();
    if (t0 < 8 || t0 + 56 > T_) {         // zero OOB-global rows (block-uniform)
        for (int idx = tid; idx < 64*128/4; idx += 512) {
            int e = idx << 2;
            int r = e >> 7, ci = e & 127;
            int t = t0 - 8 + r;
            if (t < 0 || t >= T_) {
                unsigned byte = ((unsigned)(r*128 + ci))*2u ^ ((unsigned)((r & 7) << 4));
                *(uint2*)((char*)i1h + byte) = make_uint2(0u, 0u);
                *(uint2*)((char*)i1l + byte) = make_uint2(0u, 0u);
            }
        }
        __syncthreads();
    }

    // ---- phase 1: conv2 over all 64 local rows -> s = conv2 + bc2 + 2*i1 ----
    {
        const int wy2 = wid >> 1;         // 0..3: rows wy2*16 + l16
        const int wx2 = wid & 1;          // cols wx2*64 + n*16
        f32x4 acc[4];
        const f32x4 z = {0.f,0.f,0.f,0.f};
#pragma unroll
        for (int n = 0; n < 4; ++n) acc[n] = z;
#pragma unroll
        for (int k = 0; k < 3; ++k) {
#pragma unroll
            for (int cb = 0; cb < 4; ++cb) {
                bf16x8 bh[4], bl[4];
#pragma unroll
                for (int n = 0; n < 4; ++n) {
                    size_t off = ((((size_t)k*4 + cb)*8 + wx2*4 + n)*64 + lane)*8;
                    bh[n] = *(const bf16x8*)(W2h + off);
                    bl[n] = *(const bf16x8*)(W2l + off);
                }
                int r = wy2*16 + l16 + k*3 - 3;
                r = min(max(r, 0), 63);   // garbage edge rows only; never consumed
                unsigned byte = ((unsigned)(r*128 + cb*32 + l4*8))*2u
                              ^ ((unsigned)((r & 7) << 4));
                bf16x8 ah = *(const bf16x8*)((const char*)i1h + byte);
                bf16x8 al = *(const bf16x8*)((const char*)i1l + byte);
#pragma unroll
                for (int n = 0; n < 4; ++n) {
                    acc[n] = __builtin_amdgcn_mfma_f32_16x16x32_bf16(ah, bh[n], acc[n], 0, 0, 0);
                    acc[n] = __builtin_amdgcn_mfma_f32_16x16x32_bf16(ah, bl[n], acc[n], 0, 0, 0);
                    acc[n] = __builtin_amdgcn_mfma_f32_16x16x32_bf16(al, bh[n], acc[n], 0, 0, 0);
                }
            }
        }
        const int rbase = wy2*16 + l4*4;
#pragma unroll
        for (int n = 0; n < 4; ++n) {
            int c = wx2*64 + n*16 + l16;
            float bv = bc2[c];
#pragma unroll
            for (int rg = 0; rg < 4; ++rg) {
                int rl = rbase + rg;
                int t  = t0 - 8 + rl;
                float v = 0.0f;
                unsigned byte = ((unsigned)(rl*128 + c))*2u ^ ((unsigned)((rl & 7) << 4));
                if (t >= 0 && t < T_) {
                    float cen = bf2f(*(const ushort_t*)((const char*)i1h + byte))
                              + bf2f(*(const ushort_t*)((const char*)i1l + byte));
                    v = acc[n][rg] + bv + 2.0f*cen;
                }
                ushort_t h, l;
                split2(v, h, l);
                *(ushort_t*)((char*)sh_ + byte) = h;
                *(ushort_t*)((char*)sl_ + byte) = l;
            }
        }
    }
    __syncthreads();

    // ---- phase 2: conv3 over 48 output rows -> i3 = conv3 + bc3 + s ----
    {
        f32x4 acc[3];
        const f32x4 z = {0.f,0.f,0.f,0.f};
#pragma unroll
        for (int m = 0; m < 3; ++m) acc[m] = z;
#pragma unroll
        for (int k = 0; k < 3; ++k) {
#pragma unroll
            for (int cb = 0; cb < 4; ++cb) {
                size_t off = ((((size_t)k*4 + cb)*8 + wid)*64 + lane)*8;
                bf16x8 bh = *(const bf16x8*)(W3h + off);
                bf16x8 bl = *(const bf16x8*)(W3l + off);
                bf16x8 ah[3], al[3];
#pragma unroll
                for (int m = 0; m < 3; ++m) {
                    int r = 4 + m*16 + l16 + k*4;      // in [4,59]
                    unsigned byte = ((unsigned)(r*128 + cb*32 + l4*8))*2u
                                  ^ ((unsigned)((r & 7) << 4));
                    ah[m] = *(const bf16x8*)((const char*)sh_ + byte);
                    al[m] = *(const bf16x8*)((const char*)sl_ + byte);
                }
#pragma unroll
                for (int m = 0; m < 3; ++m) {
                    acc[m] = __builtin_amdgcn_mfma_f32_16x16x32_bf16(ah[m], bh, acc[m], 0, 0, 0);
                    acc[m] = __builtin_amdgcn_mfma_f32_16x16x32_bf16(ah[m], bl, acc[m], 0, 0, 0);
                    acc[m] = __builtin_amdgcn_mfma_f32_16x16x32_bf16(al[m], bh, acc[m], 0, 0, 0);
                }
            }
        }
        const int c = wid*16 + l16;
        const float bv = bc3[c];
#pragma unroll
        for (int m = 0; m < 3; ++m) {
#pragma unroll
            for (int rg = 0; rg < 4; ++rg) {
                int rl = 8 + m*16 + l4*4 + rg;         // s local row
                int t  = t0 - 8 + rl;                  // global out t
                if (t < T_) {
                    unsigned byte = ((unsigned)(rl*128 + c))*2u ^ ((unsigned)((rl & 7) << 4));
                    float cen = bf2f(*(const ushort_t*)((const char*)sh_ + byte))
                              + bf2f(*(const ushort_t*)((const char*)sl_ + byte));
                    float v = acc[m][rg] + bv + cen;
                    size_t o = ((size_t)b*T_ + t)*128 + c;
                    ushort_t h, l;
                    split2(v, h, l);
                    Yh[o] = h; Yl[o] = l;
                }
            }
        }
    }
}

// ---------------------------------------------------------------------------
// Fused ASP on bf16 planes of i3; logits register-only; chunk-local softmax
// partials + weighted stats (x reconstructed hi+lo).
__launch_bounds__(256)
__global__ void asp_fused(const ushort_t* __restrict__ Ah, const ushort_t* __restrict__ Al,
                          const ushort_t* __restrict__ Wa1h, const ushort_t* __restrict__ Wa1l,
                          const ushort_t* __restrict__ Wa2h, const ushort_t* __restrict__ Wa2l,
                          const float* __restrict__ ba1, const float* __restrict__ ba2,
                          float* __restrict__ pm, float* __restrict__ ps,
                          float* __restrict__ pcm, float* __restrict__ pcq) {
    __shared__ __align__(16) char smem[65536];
    ushort_t* ah_ = (ushort_t*)smem;               // [128][64] stage-1 A hi
    ushort_t* al_ = (ushort_t*)(smem + 16384);
    ushort_t* vh_ = (ushort_t*)(smem + 32768);     // v hi
    ushort_t* vl_ = (ushort_t*)(smem + 49152);
    ushort_t* xh_ = (ushort_t*)smem;               // [128][128] i3 hi (after st2)
    ushort_t* xl_ = (ushort_t*)(smem + 32768);
    __shared__ float redM[2][128];
    __shared__ float redS[2][128];
    __shared__ float redAM[2][128];
    __shared__ float redAQ[2][128];

    const int tid  = threadIdx.x;
    const int lane = tid & 63;
    const int wid  = tid >> 6;
    const int wy   = wid >> 1, wx = wid & 1;
    const int l16  = lane & 15, l4 = lane >> 4;
    const int ch   = blockIdx.x;
    const int b    = blockIdx.y;
    const int t0   = ch * CHL;
    const size_t xrow = ((size_t)b*T_ + t0) * 128;

    // ---- stage 1: v = tanh(i3 @ wa1^T + ba1), K=128 in 2 chunks ----
    f32x4 acc1[4][2];
    const f32x4 z = {0.f,0.f,0.f,0.f};
#pragma unroll
    for (int m = 0; m < 4; ++m) { acc1[m][0] = z; acc1[m][1] = z; }

    for (int k0 = 0; k0 < 128; k0 += 64) {
        __syncthreads();
        for (int c0 = wid*64; c0 < 1024; c0 += 256) {
            int ck = c0 + lane;
            int r  = ck >> 3, wc = ck & 7;
            int sc = wc ^ (r & 7);
            gload16(Ah + xrow + (size_t)r*128 + k0 + sc*8, (char*)ah_ + (size_t)c0*16);
            gload16(Al + xrow + (size_t)r*128 + k0 + sc*8, (char*)al_ + (size_t)c0*16);
        }
        __syncthreads();
#pragma unroll
        for (int kk = 0; kk < 64; kk += 32) {
            bf16x8 bh[2], bl[2];
#pragma unroll
            for (int n = 0; n < 2; ++n) {
                size_t off = (((size_t)((k0 + kk) >> 5)*4 + wx*2 + n)*64 + lane)*8;
                bh[n] = *(const bf16x8*)(Wa1h + off);
                bl[n] = *(const bf16x8*)(Wa1l + off);
            }
            bf16x8 fh[4], fl[4];
#pragma unroll
            for (int m = 0; m < 4; ++m) {
                int r = wy*64 + m*16 + l16;
                unsigned byte = ((unsigned)(r*64 + kk + l4*8))*2u ^ ((unsigned)((r & 7) << 4));
                fh[m] = *(const bf16x8*)((const char*)ah_ + byte);
                fl[m] = *(const bf16x8*)((const char*)al_ + byte);
            }
#pragma unroll
            for (int m = 0; m < 4; ++m)
#pragma unroll
                for (int n = 0; n < 2; ++n) {
                    acc1[m][n] = __builtin_amdgcn_mfma_f32_16x16x32_bf16(fh[m], bh[n], acc1[m][n], 0, 0, 0);
                    acc1[m][n] = __builtin_amdgcn_mfma_f32_16x16x32_bf16(fh[m], bl[n], acc1[m][n], 0, 0, 0);
                    acc1[m][n] = __builtin_amdgcn_mfma_f32_16x16x32_bf16(fl[m], bh[n], acc1[m][n], 0, 0, 0);
                }
        }
    }
    // epilogue 1: tanh, write v to LDS bf16 hi/lo
#pragma unroll
    for (int m = 0; m < 4; ++m)
#pragma unroll
        for (int n = 0; n < 2; ++n) {
            int c = wx*32 + n*16 + l16;
            float bv = ba1[c];
            int rb = wy*64 + m*16 + l4*4;
#pragma unroll
            for (int rg = 0; rg < 4; ++rg) {
                float v = tanhf(acc1[m][n][rg] + bv);
                int r = rb + rg;
                unsigned byte = ((unsigned)(r*64 + c))*2u ^ ((unsigned)((r & 7) << 4));
                ushort_t h, l;
                split2(v, h, l);
                *(ushort_t*)((char*)vh_ + byte) = h;
                *(ushort_t*)((char*)vl_ + byte) = l;
            }
        }
    __syncthreads();

    // ---- stage 2: D[n][t] = wa2 . v ----
    f32x4 acc2[4][4];
#pragma unroll
    for (int m = 0; m < 4; ++m)
#pragma unroll
        for (int j = 0; j < 4; ++j) acc2[m][j] = z;

#pragma unroll
    for (int kk = 0; kk < 64; kk += 32) {
        bf16x8 awh[4], awl[4];
#pragma unroll
        for (int m = 0; m < 4; ++m) {
            size_t off = (((size_t)(kk >> 5)*8 + wy*4 + m)*64 + lane)*8;
            awh[m] = *(const bf16x8*)(Wa2h + off);
            awl[m] = *(const bf16x8*)(Wa2l + off);
        }
        bf16x8 bvh[4], bvl[4];
#pragma unroll
        for (int j = 0; j < 4; ++j) {
            int r = wx*64 + j*16 + l16;
            unsigned byte = ((unsigned)(r*64 + kk + l4*8))*2u ^ ((unsigned)((r & 7) << 4));
            bvh[j] = *(const bf16x8*)((const char*)vh_ + byte);
            bvl[j] = *(const bf16x8*)((const char*)vl_ + byte);
        }
#pragma unroll
        for (int m = 0; m < 4; ++m)
#pragma unroll
            for (int j = 0; j < 4; ++j) {
                acc2[m][j] = __builtin_amdgcn_mfma_f32_16x16x32_bf16(awh[m], bvh[j], acc2[m][j], 0, 0, 0);
                acc2[m][j] = __builtin_amdgcn_mfma_f32_16x16x32_bf16(awh[m], bvl[j], acc2[m][j], 0, 0, 0);
                acc2[m][j] = __builtin_amdgcn_mfma_f32_16x16x32_bf16(awl[m], bvh[j], acc2[m][j], 0, 0, 0);
            }
    }

    // epilogue 2: bias; chunk max; DMA restage i3 planes; weighted sums
#pragma unroll
    for (int m = 0; m < 4; ++m) {
        const float4 bv = *(const float4*)&ba2[wy*64 + m*16 + l4*4];
#pragma unroll
        for (int j = 0; j < 4; ++j) {
            acc2[m][j][0] += bv.x; acc2[m][j][1] += bv.y;
            acc2[m][j][2] += bv.z; acc2[m][j][3] += bv.w;
        }
    }
#pragma unroll
    for (int m = 0; m < 4; ++m)
#pragma unroll
        for (int rg = 0; rg < 4; ++rg) {
            int n = wy*64 + m*16 + l4*4 + rg;
            float mx = -INFINITY;
#pragma unroll
            for (int j = 0; j < 4; ++j) {
                int tg = t0 + wx*64 + j*16 + l16;
                if (tg < T_) mx = fmaxf(mx, acc2[m][j][rg]);
            }
            mx = fmaxf(mx, __shfl_xor(mx, 1));
            mx = fmaxf(mx, __shfl_xor(mx, 2));
            mx = fmaxf(mx, __shfl_xor(mx, 4));
            mx = fmaxf(mx, __shfl_xor(mx, 8));
            if (l16 == 0) redM[wx][n] = mx;
        }
    __syncthreads();
    for (int c0 = wid*64; c0 < 2048; c0 += 256) {
        int ck = c0 + lane;
        int r  = ck >> 4, wc = ck & 15;
        int sc = wc ^ (r & 7);
        gload16(Ah + xrow + (size_t)r*128 + sc*8, (char*)xh_ + (size_t)c0*16);
        gload16(Al + xrow + (size_t)r*128 + sc*8, (char*)xl_ + (size_t)c0*16);
    }
    __syncthreads();
#pragma unroll
    for (int m = 0; m < 4; ++m)
#pragma unroll
        for (int rg = 0; rg < 4; ++rg) {
            int n = wy*64 + m*16 + l4*4 + rg;
            const float mch = fmaxf(redM[0][n], redM[1][n]);
            float se = 0.0f, am = 0.0f, aq = 0.0f;
#pragma unroll
            for (int j = 0; j < 4; ++j) {
                int tl = wx*64 + j*16 + l16;
                int tg = t0 + tl;
                if (tg < T_) {
                    float p = expf(acc2[m][j][rg] - mch);
                    unsigned byte = ((unsigned)(tl*128 + n))*2u ^ ((unsigned)((tl & 7) << 4));
                    float x = bf2f(*(const ushort_t*)((const char*)xh_ + byte))
                            + bf2f(*(const ushort_t*)((const char*)xl_ + byte));
                    se += p; am += p*x; aq += p*x*x;
                }
            }
#pragma unroll
            for (int d = 1; d <= 8; d <<= 1) {
                se += __shfl_xor(se, d);
                am += __shfl_xor(am, d);
                aq += __shfl_xor(aq, d);
            }
            if (l16 == 0) { redS[wx][n] = se; redAM[wx][n] = am; redAQ[wx][n] = aq; }
        }
    __syncthreads();
    if (tid < 128) {
        float m0 = redM[0][tid], m1 = redM[1][tid];
        float M  = fmaxf(m0, m1);
        size_t o = ((size_t)b*NCH + ch)*128 + tid;
        pm[o]  = M;
        ps[o]  = redS[0][tid]  + redS[1][tid];
        pcm[o] = redAM[0][tid] + redAM[1][tid];
        pcq[o] = redAQ[0][tid] + redAQ[1][tid];
    }
}

// ---------------------------------------------------------------------------
__global__ void sm_pass_b(const float* __restrict__ pm, const float* __restrict__ ps,
                          float* __restrict__ Ms, float* __restrict__ Ss) {
    const int c = threadIdx.x, b = blockIdx.x;
    float M = -INFINITY;
    for (int ch = 0; ch < NCH; ++ch) M = fmaxf(M, pm[((size_t)b*NCH + ch)*128 + c]);
    float S = 0.0f;
    for (int ch = 0; ch < NCH; ++ch) {
        float m = pm[((size_t)b*NCH + ch)*128 + c];
        if (m > -INFINITY) S += ps[((size_t)b*NCH + ch)*128 + c] * expf(m - M);
    }
    Ms[b*128 + c] = M;
    Ss[b*128 + c] = S;
}

// stats (rescaled chunk partials) -> layernorm(256) -> linear 256->512
__global__ void final_kernel(const float* __restrict__ pcm, const float* __restrict__ pcq,
                             const float* __restrict__ pm,
                             const float* __restrict__ Ms, const float* __restrict__ Ss,
                             const float* __restrict__ gamma, const float* __restrict__ beta,
                             const float* __restrict__ w2, const float* __restrict__ b2,
                             float* __restrict__ out) {
    __shared__ float row[256];
    __shared__ float nrm[256];
    __shared__ float red[8];
    const int tid = threadIdx.x, b = blockIdx.x;
    if (tid < 128) {
        const float M = Ms[b*128 + tid];
        float sm = 0.0f, sq = 0.0f;
        for (int ch = 0; ch < NCH; ++ch) {
            size_t o = ((size_t)b*NCH + ch)*128 + tid;
            float m = pm[o];
            if (m > -INFINITY) {
                float e = expf(m - M);
                sm += pcm[o]*e;
                sq += pcq[o]*e;
            }
        }
        float S = Ss[b*128 + tid];
        float mean = sm / S;
        float q    = sq / S;
        float resid = q - mean*mean;
        float stdv  = sqrtf(fmaxf(resid, 1e-9f));
        row[tid]       = mean;
        row[128 + tid] = stdv;
    }
    __syncthreads();
    float v  = row[tid];
    float s1 = v, s2 = v*v;
    for (int off = 32; off >= 1; off >>= 1) {
        s1 += __shfl_down(s1, off, 64);
        s2 += __shfl_down(s2, off, 64);
    }
    if ((tid & 63) == 0) { red[tid >> 6] = s1; red[4 + (tid >> 6)] = s2; }
    __syncthreads();
    float S1 = red[0] + red[1] + red[2] + red[3];
    float S2 = red[4] + red[5] + red[6] + red[7];
    float mu  = S1 / 256.0f;
    float var = S2 / 256.0f - mu*mu;
    float inv = 1.0f / sqrtf(var + 1e-5f);
    nrm[tid] = (v - mu)*inv*gamma[tid] + beta[tid];
    __syncthreads();
#pragma unroll
    for (int oo = 0; oo < 2; ++oo) {
        int o = tid + oo*256;
        float acc = b2[o];
        const float4* wr = (const float4*)&w2[(size_t)o*256];
        for (int j = 0; j < 64; ++j) {
            float4 w = wr[j];
            acc += w.x*nrm[j*4] + w.y*nrm[j*4+1] + w.z*nrm[j*4+2] + w.w*nrm[j*4+3];
        }
        out[(size_t)b*512 + o] = acc;
    }
}

// ---------------------------------------------------------------------------
extern "C" void kernel_launch(void* const* d_in, const int* in_sizes, int n_in,
                              void* d_out, int out_size, void* d_ws, size_t ws_size,
                              hipStream_t stream) {
    const float* x      = (const float*)d_in[0];
    const float* bp     = (const float*)d_in[1];
    const float* w_lin1 = (const float*)d_in[2];
    const float* b_lin1 = (const float*)d_in[3];
    const float* wc1    = (const float*)d_in[4];
    const float* bc1    = (const float*)d_in[5];
    const float* wc2    = (const float*)d_in[6];
    const float* bc2    = (const float*)d_in[7];
    const float* wc3    = (const float*)d_in[8];
    const float* bc3    = (const float*)d_in[9];
    const float* wa1    = (const float*)d_in[10];
    const float* ba1    = (const float*)d_in[11];
    const float* wa2    = (const float*)d_in[12];
    const float* ba2    = (const float*)d_in[13];
    const float* gamma  = (const float*)d_in[14];
    const float* beta   = (const float*)d_in[15];
    const float* wl2    = (const float*)d_in[16];
    const float* bl2    = (const float*)d_in[17];

    float* ws   = (float*)d_ws;
    float* bs   = ws + OFF_BS;
    ushort_t* weh  = (ushort_t*)(ws + OFF_WEFF);
    ushort_t* wel  = weh + 64*320;
    float* wtail   = ws + OFF_WTAIL;
    ushort_t* w1h  = (ushort_t*)(ws + OFF_W1);
    ushort_t* w1l  = w1h + 3*128*64;
    ushort_t* w2h  = (ushort_t*)(ws + OFF_W2);
    ushort_t* w2l  = w2h + 3*128*128;
    ushort_t* w3h  = (ushort_t*)(ws + OFF_W3);
    ushort_t* w3l  = w3h + 3*128*128;
    ushort_t* wa1h = (ushort_t*)(ws + OFF_WA1);
    ushort_t* wa1l = wa1h + 64*128;
    ushort_t* wa2h = (ushort_t*)(ws + OFF_WA2);
    ushort_t* wa2l = wa2h + 128*64;
    float* pm   = ws + OFF_PM;
    float* ps   = ws + OFF_PS;
    float* Ms   = ws + OFF_MS;
    float* Ss   = ws + OFF_SS;
    float* pcm  = ws + OFF_PCM;
    float* pcq  = ws + OFF_PCQ;
    ushort_t* Hh = (ushort_t*)(ws + OFF_HH);
    ushort_t* Hl = (ushort_t*)(ws + OFF_HL);
    ushort_t* Ah = (ushort_t*)(ws + OFF_AH);
    ushort_t* Al = (ushort_t*)(ws + OFF_AL);
    ushort_t* Bh = (ushort_t*)(ws + OFF_BH);
    ushort_t* Bl = (ushort_t*)(ws + OFF_BL);

    sort_kernel<<<dim3(1), dim3(64), 0, stream>>>(bp, bs);
    prep_kernel<<<dim3(624), dim3(256), 0, stream>>>(bs, w_lin1, wc1, wc2, wc3, wa1, wa2,
                                                     weh, wel, wtail, w1h, w1l, w2h, w2l,
                                                     w3h, w3l, wa1h, wa1l, wa2h, wa2l);
    // h = relu(x @ Weff^T + b_lin1) -> H planes
    lin1_mfma<<<dim3(R_/128), dim3(256), 0, stream>>>(x, weh, wel, wtail, b_lin1, Hh, Hl);
    // i1 = conv1(h) + b -> A planes
    dconv1_mfma<<<dim3(47, B_), dim3(256), 0, stream>>>(Hh, Hl, w1h, w1l, bc1, Ah, Al);
    // i3 = conv3(conv2(i1)+b2+2*i1) + b3 + s  (s in LDS only) -> B planes
    dconv23_fused<<<dim3(63, B_), dim3(512), 0, stream>>>(Ah, Al, w2h, w2l, w3h, w3l,
                                                          bc2, bc3, Bh, Bl);
    // fused asp1+asp2+softmax partials+weighted stats
    asp_fused<<<dim3(NCH, B_), dim3(256), 0, stream>>>(Bh, Bl, wa1h, wa1l, wa2h, wa2l,
                                                       ba1, ba2, pm, ps, pcm, pcq);
    sm_pass_b<<<dim3(B_), dim3(128), 0, stream>>>(pm, ps, Ms, Ss);
    final_kernel<<<dim3(B_), dim3(256), 0, stream>>>(pcm, pcq, pm, Ms, Ss, gamma, beta,
                                                     wl2, bl2, (float*)d_out);
}

// Round 13
// 402.552 us; speedup vs baseline: 1.2398x; 1.2398x over previous
//
#include <hip/hip_runtime.h>
#include <math.h>

// ---------------------------------------------------------------------------
// ResCNN_ASP_SpeakerEncoder — v12: activations stored as SINGLE bf16 plane
// (weights remain hi/lo split => 2-pass MFMA; only activation-rounding error).
// conv2+conv3 fused; ASP fused; DMA staging with pre-swizzled sources.
// ---------------------------------------------------------------------------

constexpr int B_  = 64;
constexpr int T_  = 3000;
constexpr int NB_ = 257;   // NBINS
constexpr int R_  = B_ * T_;           // 192000 rows
constexpr int NCH = 24;                // softmax T-chunks (24 x 128)
constexpr int CHL = 128;

// workspace layout (float offsets)
constexpr size_t OFF_BS    = 0;
constexpr size_t OFF_WEFF  = 128;                          // ushort hi[64*320]+lo
constexpr size_t OFF_WTAIL = OFF_WEFF + 20480;
constexpr size_t OFF_W1    = OFF_WTAIL + 128;              // ushort hi+lo 3*128*64
constexpr size_t OFF_W2    = OFF_W1  + 3*64*128;
constexpr size_t OFF_W3    = OFF_W2  + 3*128*128;
constexpr size_t OFF_WA1   = OFF_W3  + 3*128*128;
constexpr size_t OFF_WA2   = OFF_WA1 + 8192;
constexpr size_t SZ_P      = (size_t)B_*NCH*128;
constexpr size_t OFF_PM    = OFF_WA2 + 8192;
constexpr size_t OFF_PS    = OFF_PM  + SZ_P;
constexpr size_t OFF_MS    = OFF_PS  + SZ_P;
constexpr size_t OFF_SS    = OFF_MS  + (size_t)B_*128;
constexpr size_t OFF_PCM   = OFF_SS  + (size_t)B_*128;
constexpr size_t OFF_PCQ   = OFF_PCM + SZ_P;
// single bf16 planes (ushort counts -> float counts /2)
constexpr size_t OFF_HS    = OFF_PCQ + SZ_P;               // h  [R*64]u
constexpr size_t OFF_AS    = OFF_HS  + (size_t)R_*32;      // i1 [R*128]u
constexpr size_t OFF_BSP   = OFF_AS  + (size_t)R_*64;      // i3 [R*128]u (+pad after)

typedef __attribute__((ext_vector_type(8))) short  bf16x8;
typedef __attribute__((ext_vector_type(4))) float  f32x4;
typedef __attribute__((ext_vector_type(4), aligned(4))) float float4a;
typedef unsigned short ushort_t;

typedef __attribute__((address_space(3))) unsigned int        as3_u32;
typedef const __attribute__((address_space(1))) unsigned int  as1_u32c;
__device__ __forceinline__ void gload16(const void* g, void* l) {
    __builtin_amdgcn_global_load_lds((as1_u32c*)g, (as3_u32*)l, 16, 0, 0);
}

__device__ inline ushort_t f2bf(float f) {                // RNE f32->bf16
    unsigned u = __float_as_uint(f);
    unsigned r = u + 0x7FFFu + ((u >> 16) & 1u);
    return (ushort_t)(r >> 16);
}
__device__ inline float bf2f(ushort_t h) {
    return __uint_as_float(((unsigned)h) << 16);
}
__device__ inline void split2(float v, ushort_t &h, ushort_t &l) {
    h = f2bf(v);
    l = f2bf(v - bf2f(h));
}

// pack 4 f32 -> 4 bf16 (RNE, 2 u32) — same bytes as 4 scalar f2bf stores
__device__ inline void pack_hi4(float x, float y, float z, float w, uint2 &ph) {
    unsigned hx, hy;
    asm("v_cvt_pk_bf16_f32 %0, %1, %2" : "=v"(hx) : "v"(x), "v"(y));
    asm("v_cvt_pk_bf16_f32 %0, %1, %2" : "=v"(hy) : "v"(z), "v"(w));
    ph.x = hx; ph.y = hy;
}

// ---------------------------------------------------------------------------
__global__ void sort_kernel(const float* __restrict__ bp, float* __restrict__ bs) {
    if (threadIdx.x == 0) {
        float tmp[82];
        for (int i = 0; i < 82; ++i) tmp[i] = bp[i];
        for (int i = 1; i < 82; ++i) {
            float key = tmp[i];
            int j = i - 1;
            while (j >= 0 && tmp[j] > key) { tmp[j+1] = tmp[j]; --j; }
            tmp[j+1] = key;
        }
        for (int i = 0; i < 82; ++i) bs[i] = tmp[i];
    }
}

// Fragment-order packing (B: lane&15=col, lane>>4=k-octet; A: lane&15=row).
__global__ void prep_kernel(const float* __restrict__ bs, const float* __restrict__ wl1,
                            const float* __restrict__ wc1, const float* __restrict__ wc2,
                            const float* __restrict__ wc3, const float* __restrict__ wa1,
                            const float* __restrict__ wa2,
                            ushort_t* __restrict__ weh, ushort_t* __restrict__ wel,
                            float* __restrict__ wtail,
                            ushort_t* __restrict__ w1h, ushort_t* __restrict__ w1l,
                            ushort_t* __restrict__ w2h, ushort_t* __restrict__ w2l,
                            ushort_t* __restrict__ w3h, ushort_t* __restrict__ w3l,
                            ushort_t* __restrict__ wa1h, ushort_t* __restrict__ wa1l,
                            ushort_t* __restrict__ wa2h, ushort_t* __restrict__ wa2l) {
    int gid = blockIdx.x * 256 + threadIdx.x;
    if (gid < 64*320) {                            // Weff[o][f]
        int o = gid / 320, f = gid % 320;
        if (f > 256) return;
        float acc = 0.0f;
        if (f == 0) acc = wl1[o*80];               // filt[:,:,0] = x[:,:,0]
        else {
            for (int n = 1; n < 79; ++n) {
                float bn = bs[n], bn1 = bs[n+1], bn2 = bs[n+2];
                int ibn  = (int)floorf(bn);
                int ibn1 = (int)floorf(bn1);
                int ibn2 = (int)floorf(bn2);
                float fbv = 0.0f;
                if (f >= ibn && f < ibn1) {
                    float d = (bn1-bn)*(bn1-bn);
                    fbv = ((float)f - bn) / (d > 0.0f ? d : 1.0f);
                } else if (f >= ibn1 && f < ibn2) {
                    float d = (bn2-bn1)*(bn2-bn1);
                    fbv = (bn2 - (float)f) / (d > 0.0f ? d : 1.0f);
                }
                acc += wl1[o*80 + n] * fbv;
            }
        }
        if (f == 256) { wtail[o] = acc; return; }
        int kc = f >> 5, lane = ((f & 31) >> 3)*16 + (o & 15), e = f & 7;
        size_t dst = (((size_t)kc*4 + (o >> 4))*64 + lane)*8 + e;
        split2(acc, weh[dst], wel[dst]);
        return;
    }
    gid -= 64*320;
    if (gid < 3*128*64) {                          // conv1: [k][c][ci=64]
        int k = gid / (128*64), rem = gid % (128*64);
        int c = rem >> 6, ci = rem & 63;
        float v = wc1[(c*64 + ci)*3 + k];
        int lane = ((ci & 31) >> 3)*16 + (c & 15), e = ci & 7;
        size_t dst = ((((size_t)k*2 + (ci >> 5))*8 + (c >> 4))*64 + lane)*8 + e;
        split2(v, w1h[dst], w1l[dst]);
        return;
    }
    gid -= 3*128*64;
    if (gid < 3*128*128) {                         // conv2
        int k = gid / (128*128), rem = gid % (128*128);
        int c = rem >> 7, ci = rem & 127;
        float v = wc2[(c*128 + ci)*3 + k];
        int lane = ((ci & 31) >> 3)*16 + (c & 15), e = ci & 7;
        size_t dst = ((((size_t)k*4 + (ci >> 5))*8 + (c >> 4))*64 + lane)*8 + e;
        split2(v, w2h[dst], w2l[dst]);
        return;
    }
    gid -= 3*128*128;
    if (gid < 3*128*128) {                         // conv3
        int k = gid / (128*128), rem = gid % (128*128);
        int c = rem >> 7, ci = rem & 127;
        float v = wc3[(c*128 + ci)*3 + k];
        int lane = ((ci & 31) >> 3)*16 + (c & 15), e = ci & 7;
        size_t dst = ((((size_t)k*4 + (ci >> 5))*8 + (c >> 4))*64 + lane)*8 + e;
        split2(v, w3h[dst], w3l[dst]);
        return;
    }
    gid -= 3*128*128;
    if (gid < 64*128) {                            // wa1 [c=64][ci=128]
        int c = gid >> 7, ci = gid & 127;
        float v = wa1[gid];
        int lane = ((ci & 31) >> 3)*16 + (c & 15), e = ci & 7;
        size_t dst = (((size_t)(ci >> 5)*4 + (c >> 4))*64 + lane)*8 + e;
        split2(v, wa1h[dst], wa1l[dst]);
        return;
    }
    gid -= 64*128;
    if (gid < 128*64) {                            // wa2 [n=128][ci=64] (A op)
        int n = gid >> 6, ci = gid & 63;
        float v = wa2[gid];
        int lane = ((ci & 31) >> 3)*16 + (n & 15), e = ci & 7;
        size_t dst = (((size_t)(ci >> 5)*8 + (n >> 4))*64 + lane)*8 + e;
        split2(v, wa2h[dst], wa2l[dst]);
        return;
    }
}

// ---------------------------------------------------------------------------
// lin1: h = relu(x @ Weff^T + b); x staged as single bf16; 2-pass MFMA.
__launch_bounds__(256)
__global__ void lin1_mfma(const float* __restrict__ X,
                          const ushort_t* __restrict__ Wh, const ushort_t* __restrict__ Wl,
                          const float* __restrict__ wtail,
                          const float* __restrict__ bias,
                          ushort_t* __restrict__ Hs) {
    __shared__ __align__(16) ushort_t ash[128*64];
    __shared__ float xs[128];
    __shared__ float wts[64];
    const int tid  = threadIdx.x;
    const int lane = tid & 63;
    const int wid  = tid >> 6;
    const int wy   = wid >> 1, wx = wid & 1;
    const int l16  = lane & 15, l4 = lane >> 4;
    const int r0   = blockIdx.x * 128;

    if (tid < 128)       xs[tid] = X[(size_t)(r0 + tid)*NB_ + 256];
    else if (tid < 192)  wts[tid - 128] = wtail[tid - 128];

#define LIN1_LOAD(dst, k0)                                            \
    _Pragma("unroll")                                                 \
    for (int i = 0; i < 8; ++i) {                                     \
        int q = tid + i*256; int r = q >> 4, cc = (q & 15) << 2;      \
        dst[i] = *(const float4a*)(X + (size_t)(r0 + r)*NB_ + (k0) + cc); \
    }
#define LIN1_CW(src)                                                  \
    _Pragma("unroll")                                                 \
    for (int i = 0; i < 8; ++i) {                                     \
        int q = tid + i*256; int r = q >> 4, cc = (q & 15) << 2;      \
        uint2 ph;                                                     \
        pack_hi4(src[i].x, src[i].y, src[i].z, src[i].w, ph);         \
        unsigned byte = ((unsigned)(r*64 + cc))*2u ^ ((unsigned)((r & 7) << 4)); \
        *(uint2*)((char*)ash + byte) = ph;                            \
    }

    float4a bufA[8], bufB[8];
    LIN1_LOAD(bufA, 0);

    f32x4 acc[4][2];
    const f32x4 z = {0.f,0.f,0.f,0.f};
#pragma unroll
    for (int m = 0; m < 4; ++m) { acc[m][0] = z; acc[m][1] = z; }

#pragma unroll
    for (int ck = 0; ck < 4; ++ck) {
        const float4a* cur = (ck & 1) ? bufB : bufA;
        float4a*       nxt = (ck & 1) ? bufA : bufB;
        if (ck < 3) LIN1_LOAD(nxt, (ck + 1)*64);
        LIN1_CW(cur);
        __syncthreads();
#pragma unroll
        for (int kk = 0; kk < 64; kk += 32) {
            bf16x8 bh[2], bl[2];
#pragma unroll
            for (int n = 0; n < 2; ++n) {
                size_t off = (((size_t)(ck*2 + (kk >> 5))*4 + wx*2 + n)*64 + lane)*8;
                bh[n] = *(const bf16x8*)(Wh + off);
                bl[n] = *(const bf16x8*)(Wl + off);
            }
            bf16x8 fh[4];
#pragma unroll
            for (int m = 0; m < 4; ++m) {
                int r = wy*64 + m*16 + l16;
                unsigned byte = ((unsigned)(r*64 + kk + l4*8))*2u ^ ((unsigned)((r & 7) << 4));
                fh[m] = *(const bf16x8*)((const char*)ash + byte);
            }
#pragma unroll
            for (int m = 0; m < 4; ++m)
#pragma unroll
                for (int n = 0; n < 2; ++n) {
                    acc[m][n] = __builtin_amdgcn_mfma_f32_16x16x32_bf16(fh[m], bh[n], acc[m][n], 0, 0, 0);
                    acc[m][n] = __builtin_amdgcn_mfma_f32_16x16x32_bf16(fh[m], bl[n], acc[m][n], 0, 0, 0);
                }
        }
        __syncthreads();
    }
#undef LIN1_LOAD
#undef LIN1_CW

#pragma unroll
    for (int m = 0; m < 4; ++m)
#pragma unroll
        for (int n = 0; n < 2; ++n) {
            int c = wx*32 + n*16 + l16;
            float bv = bias[c];
            float wc = wts[c];
            int rbl = wy*64 + m*16 + l4*4;
#pragma unroll
            for (int rg = 0; rg < 4; ++rg) {
                int rl = rbl + rg;
                float v = fmaxf(acc[m][n][rg] + bv + xs[rl]*wc, 0.0f);
                Hs[(size_t)(r0 + rl)*64 + c] = f2bf(v);
            }
        }
}

// ---------------------------------------------------------------------------
// conv1 (CIN=64, DIL=2): single-plane input, DMA staging, 2-pass MFMA.
__launch_bounds__(256, 4)
__global__ void dconv1_mfma(const ushort_t* __restrict__ Xs,
                            const ushort_t* __restrict__ Wh, const ushort_t* __restrict__ Wl,
                            const float* __restrict__ bias,
                            ushort_t* __restrict__ Ys) {
    constexpr int CIN = 64, DIL = 2;
    constexpr int TT  = 64;
    constexpr int HS  = TT + 2*DIL;        // 68
    constexpr int NCK = HS*8;              // 16B chunks (8 per row)
    constexpr int NCKP = ((NCK + 255)/256)*256;
    __shared__ __align__(16) ushort_t hs_[NCKP*8];

    const int tid  = threadIdx.x;
    const int lane = tid & 63;
    const int wid  = tid >> 6;
    const int wy   = wid >> 1;
    const int wx   = wid & 1;
    const int l16  = lane & 15;
    const int l4   = lane >> 4;
    const int t0   = blockIdx.x * TT;
    const int b    = blockIdx.y;

    const long long rowbase = ((long long)b*T_ + (t0 - DIL)) * CIN;
    for (int c0 = wid*64; c0 < NCKP; c0 += 256) {
        int ck = c0 + lane;
        int r  = ck >> 3;
        int sc = ck ^ (r & 7);
        gload16(Xs + rowbase + (long long)sc*8, (char*)hs_ + (size_t)c0*16);
    }
    __syncthreads();
    if (t0 < DIL || t0 + TT + DIL > T_) {
        for (int idx = tid; idx < HS*CIN/4; idx += 256) {
            int e = idx << 2;
            int r = e / CIN, ci = e % CIN;
            int t = t0 - DIL + r;
            if (t < 0 || t >= T_) {
                unsigned byte = ((unsigned)(r*CIN + ci))*2u ^ ((unsigned)((r & 7) << 4));
                *(uint2*)((char*)hs_ + byte) = make_uint2(0u, 0u);
            }
        }
        __syncthreads();
    }

    f32x4 acc[2][4];
    const f32x4 z = {0.f, 0.f, 0.f, 0.f};
#pragma unroll
    for (int m = 0; m < 2; ++m)
#pragma unroll
        for (int n = 0; n < 4; ++n) acc[m][n] = z;

#pragma unroll
    for (int k = 0; k < 3; ++k) {
#pragma unroll
        for (int cb = 0; cb < 2; ++cb) {
            bf16x8 bh[4], bl[4];
#pragma unroll
            for (int n = 0; n < 4; ++n) {
                size_t off = ((((size_t)k*2 + cb)*8 + wx*4 + n)*64 + lane)*8;
                bh[n] = *(const bf16x8*)(Wh + off);
                bl[n] = *(const bf16x8*)(Wl + off);
            }
            bf16x8 ah[2];
#pragma unroll
            for (int m = 0; m < 2; ++m) {
                int r = wy*32 + m*16 + l16 + k*DIL;
                unsigned byte = ((unsigned)(r*CIN + cb*32 + l4*8))*2u
                              ^ ((unsigned)((r & 7) << 4));
                ah[m] = *(const bf16x8*)((const char*)hs_ + byte);
            }
#pragma unroll
            for (int m = 0; m < 2; ++m)
#pragma unroll
                for (int n = 0; n < 4; ++n) {
                    acc[m][n] = __builtin_amdgcn_mfma_f32_16x16x32_bf16(ah[m], bh[n], acc[m][n], 0, 0, 0);
                    acc[m][n] = __builtin_amdgcn_mfma_f32_16x16x32_bf16(ah[m], bl[n], acc[m][n], 0, 0, 0);
                }
        }
    }

#pragma unroll
    for (int m = 0; m < 2; ++m) {
        int tl_base = wy*32 + m*16 + l4*4;
#pragma unroll
        for (int n = 0; n < 4; ++n) {
            int c = wx*64 + n*16 + l16;
            float bv = bias[c];
#pragma unroll
            for (int rg = 0; rg < 4; ++rg) {
                int tl = tl_base + rg;
                int t  = t0 + tl;
                if (t < T_) {
                    float v = acc[m][n][rg] + bv;
                    Ys[((size_t)b*T_ + t)*128 + c] = f2bf(v);
                }
            }
        }
    }
}

// ---------------------------------------------------------------------------
// Fused conv2+conv3 (single-plane activations, 2-pass MFMA). LDS 32KB.
__launch_bounds__(512, 8)
__global__ void dconv23_fused(const ushort_t* __restrict__ Xs,
                              const ushort_t* __restrict__ W2h, const ushort_t* __restrict__ W2l,
                              const ushort_t* __restrict__ W3h, const ushort_t* __restrict__ W3l,
                              const float* __restrict__ bc2, const float* __restrict__ bc3,
                              ushort_t* __restrict__ Ys) {
    constexpr int TT = 48;
    __shared__ __align__(16) ushort_t i1s[64*128];   // rows t0-8 .. t0+55
    __shared__ __align__(16) ushort_t ss_[64*128];

    const int tid  = threadIdx.x;
    const int lane = tid & 63;
    const int wid  = tid >> 6;            // 0..7
    const int l16  = lane & 15, l4 = lane >> 4;
    const int t0   = blockIdx.x * TT;
    const int b    = blockIdx.y;

    const long long rowbase = ((long long)b*T_ + (t0 - 8)) * 128;
    for (int c0 = wid*64; c0 < 1024; c0 += 512) {
        int ck = c0 + lane;
        int r  = ck >> 4;
        int sc = ck ^ (r & 7);
        gload16(Xs + rowbase + (long long)sc*8, (char*)i1s + (size_t)c0*16);
    }
    __syncthreads();
    if (t0 < 8 || t0 + 56 > T_) {
        for (int idx = tid; idx < 64*128/4; idx += 512) {
            int e = idx << 2;
            int r = e >> 7, ci = e & 127;
            int t = t0 - 8 + r;
            if (t < 0 || t >= T_) {
                unsigned byte = ((unsigned)(r*128 + ci))*2u ^ ((unsigned)((r & 7) << 4));
                *(uint2*)((char*)i1s + byte) = make_uint2(0u, 0u);
            }
        }
        __syncthreads();
    }

    // ---- phase 1: conv2 over all 64 local rows -> s = conv2 + bc2 + 2*i1 ----
    {
        const int wy2 = wid >> 1;
        const int wx2 = wid & 1;
        f32x4 acc[4];
        const f32x4 z = {0.f,0.f,0.f,0.f};
#pragma unroll
        for (int n = 0; n < 4; ++n) acc[n] = z;
#pragma unroll
        for (int k = 0; k < 3; ++k) {
#pragma unroll
            for (int cb = 0; cb < 4; ++cb) {
                bf16x8 bh[4], bl[4];
#pragma unroll
                for (int n = 0; n < 4; ++n) {
                    size_t off = ((((size_t)k*4 + cb)*8 + wx2*4 + n)*64 + lane)*8;
                    bh[n] = *(const bf16x8*)(W2h + off);
                    bl[n] = *(const bf16x8*)(W2l + off);
                }
                int r = wy2*16 + l16 + k*3 - 3;
                r = min(max(r, 0), 63);   // garbage edge rows only; never consumed
                unsigned byte = ((unsigned)(r*128 + cb*32 + l4*8))*2u
                              ^ ((unsigned)((r & 7) << 4));
                bf16x8 ah = *(const bf16x8*)((const char*)i1s + byte);
#pragma unroll
                for (int n = 0; n < 4; ++n) {
                    acc[n] = __builtin_amdgcn_mfma_f32_16x16x32_bf16(ah, bh[n], acc[n], 0, 0, 0);
                    acc[n] = __builtin_amdgcn_mfma_f32_16x16x32_bf16(ah, bl[n], acc[n], 0, 0, 0);
                }
            }
        }
        const int rbase = wy2*16 + l4*4;
#pragma unroll
        for (int n = 0; n < 4; ++n) {
            int c = wx2*64 + n*16 + l16;
            float bv = bc2[c];
#pragma unroll
            for (int rg = 0; rg < 4; ++rg) {
                int rl = rbase + rg;
                int t  = t0 - 8 + rl;
                float v = 0.0f;
                unsigned byte = ((unsigned)(rl*128 + c))*2u ^ ((unsigned)((rl & 7) << 4));
                if (t >= 0 && t < T_) {
                    float cen = bf2f(*(const ushort_t*)((const char*)i1s + byte));
                    v = acc[n][rg] + bv + 2.0f*cen;
                }
                *(ushort_t*)((char*)ss_ + byte) = f2bf(v);
            }
        }
    }
    __syncthreads();

    // ---- phase 2: conv3 over 48 output rows -> i3 = conv3 + bc3 + s ----
    {
        f32x4 acc[3];
        const f32x4 z = {0.f,0.f,0.f,0.f};
#pragma unroll
        for (int m = 0; m < 3; ++m) acc[m] = z;
#pragma unroll
        for (int k = 0; k < 3; ++k) {
#pragma unroll
            for (int cb = 0; cb < 4; ++cb) {
                size_t off = ((((size_t)k*4 + cb)*8 + wid)*64 + lane)*8;
                bf16x8 bh = *(const bf16x8*)(W3h + off);
                bf16x8 bl = *(const bf16x8*)(W3l + off);
                bf16x8 ah[3];
#pragma unroll
                for (int m = 0; m < 3; ++m) {
                    int r = 4 + m*16 + l16 + k*4;      // in [4,59]
                    unsigned byte = ((unsigned)(r*128 + cb*32 + l4*8))*2u
                                  ^ ((unsigned)((r & 7) << 4));
                    ah[m] = *(const bf16x8*)((const char*)ss_ + byte);
                }
#pragma unroll
                for (int m = 0; m < 3; ++m) {
                    acc[m] = __builtin_amdgcn_mfma_f32_16x16x32_bf16(ah[m], bh, acc[m], 0, 0, 0);
                    acc[m] = __builtin_amdgcn_mfma_f32_16x16x32_bf16(ah[m], bl, acc[m], 0, 0, 0);
                }
            }
        }
        const int c = wid*16 + l16;
        const float bv = bc3[c];
#pragma unroll
        for (int m = 0; m < 3; ++m) {
#pragma unroll
            for (int rg = 0; rg < 4; ++rg) {
                int rl = 8 + m*16 + l4*4 + rg;         // s local row
                int t  = t0 - 8 + rl;
                if (t < T_) {
                    unsigned byte = ((unsigned)(rl*128 + c))*2u ^ ((unsigned)((rl & 7) << 4));
                    float cen = bf2f(*(const ushort_t*)((const char*)ss_ + byte));
                    float v = acc[m][rg] + bv + cen;
                    Ys[((size_t)b*T_ + t)*128 + c] = f2bf(v);
                }
            }
        }
    }
}

// ---------------------------------------------------------------------------
// Fused ASP (single-plane i3; weights split => 2-pass). LDS 32KB + reds.
__launch_bounds__(256)
__global__ void asp_fused(const ushort_t* __restrict__ As,
                          const ushort_t* __restrict__ Wa1h, const ushort_t* __restrict__ Wa1l,
                          const ushort_t* __restrict__ Wa2h, const ushort_t* __restrict__ Wa2l,
                          const float* __restrict__ ba1, const float* __restrict__ ba2,
                          float* __restrict__ pm, float* __restrict__ ps,
                          float* __restrict__ pcm, float* __restrict__ pcq) {
    __shared__ __align__(16) char smem[32768];
    ushort_t* as_ = (ushort_t*)smem;               // [128][64] stage-1 A
    ushort_t* vs_ = (ushort_t*)(smem + 16384);     // v [128][64]
    ushort_t* xs_ = (ushort_t*)smem;               // [128][128] i3 (after stage 2)
    __shared__ float redM[2][128];
    __shared__ float redS[2][128];
    __shared__ float redAM[2][128];
    __shared__ float redAQ[2][128];

    const int tid  = threadIdx.x;
    const int lane = tid & 63;
    const int wid  = tid >> 6;
    const int wy   = wid >> 1, wx = wid & 1;
    const int l16  = lane & 15, l4 = lane >> 4;
    const int ch   = blockIdx.x;
    const int b    = blockIdx.y;
    const int t0   = ch * CHL;
    const size_t xrow = ((size_t)b*T_ + t0) * 128;

    // ---- stage 1: v = tanh(i3 @ wa1^T + ba1), K=128 in 2 chunks ----
    f32x4 acc1[4][2];
    const f32x4 z = {0.f,0.f,0.f,0.f};
#pragma unroll
    for (int m = 0; m < 4; ++m) { acc1[m][0] = z; acc1[m][1] = z; }

    for (int k0 = 0; k0 < 128; k0 += 64) {
        __syncthreads();
        for (int c0 = wid*64; c0 < 1024; c0 += 256) {
            int ck = c0 + lane;
            int r  = ck >> 3, wc = ck & 7;
            int sc = wc ^ (r & 7);
            gload16(As + xrow + (size_t)r*128 + k0 + sc*8, (char*)as_ + (size_t)c0*16);
        }
        __syncthreads();
#pragma unroll
        for (int kk = 0; kk < 64; kk += 32) {
            bf16x8 bh[2], bl[2];
#pragma unroll
            for (int n = 0; n < 2; ++n) {
                size_t off = (((size_t)((k0 + kk) >> 5)*4 + wx*2 + n)*64 + lane)*8;
                bh[n] = *(const bf16x8*)(Wa1h + off);
                bl[n] = *(const bf16x8*)(Wa1l + off);
            }
            bf16x8 fh[4];
#pragma unroll
            for (int m = 0; m < 4; ++m) {
                int r = wy*64 + m*16 + l16;
                unsigned byte = ((unsigned)(r*64 + kk + l4*8))*2u ^ ((unsigned)((r & 7) << 4));
                fh[m] = *(const bf16x8*)((const char*)as_ + byte);
            }
#pragma unroll
            for (int m = 0; m < 4; ++m)
#pragma unroll
                for (int n = 0; n < 2; ++n) {
                    acc1[m][n] = __builtin_amdgcn_mfma_f32_16x16x32_bf16(fh[m], bh[n], acc1[m][n], 0, 0, 0);
                    acc1[m][n] = __builtin_amdgcn_mfma_f32_16x16x32_bf16(fh[m], bl[n], acc1[m][n], 0, 0, 0);
                }
        }
    }
    // epilogue 1: tanh, write v (single bf16) to LDS
#pragma unroll
    for (int m = 0; m < 4; ++m)
#pragma unroll
        for (int n = 0; n < 2; ++n) {
            int c = wx*32 + n*16 + l16;
            float bv = ba1[c];
            int rb = wy*64 + m*16 + l4*4;
#pragma unroll
            for (int rg = 0; rg < 4; ++rg) {
                float v = tanhf(acc1[m][n][rg] + bv);
                int r = rb + rg;
                unsigned byte = ((unsigned)(r*64 + c))*2u ^ ((unsigned)((r & 7) << 4));
                *(ushort_t*)((char*)vs_ + byte) = f2bf(v);
            }
        }
    __syncthreads();

    // ---- stage 2: D[n][t] = wa2 . v ----
    f32x4 acc2[4][4];
#pragma unroll
    for (int m = 0; m < 4; ++m)
#pragma unroll
        for (int j = 0; j < 4; ++j) acc2[m][j] = z;

#pragma unroll
    for (int kk = 0; kk < 64; kk += 32) {
        bf16x8 awh[4], awl[4];
#pragma unroll
        for (int m = 0; m < 4; ++m) {
            size_t off = (((size_t)(kk >> 5)*8 + wy*4 + m)*64 + lane)*8;
            awh[m] = *(const bf16x8*)(Wa2h + off);
            awl[m] = *(const bf16x8*)(Wa2l + off);
        }
        bf16x8 bv_[4];
#pragma unroll
        for (int j = 0; j < 4; ++j) {
            int r = wx*64 + j*16 + l16;
            unsigned byte = ((unsigned)(r*64 + kk + l4*8))*2u ^ ((unsigned)((r & 7) << 4));
            bv_[j] = *(const bf16x8*)((const char*)vs_ + byte);
        }
#pragma unroll
        for (int m = 0; m < 4; ++m)
#pragma unroll
            for (int j = 0; j < 4; ++j) {
                acc2[m][j] = __builtin_amdgcn_mfma_f32_16x16x32_bf16(awh[m], bv_[j], acc2[m][j], 0, 0, 0);
                acc2[m][j] = __builtin_amdgcn_mfma_f32_16x16x32_bf16(awl[m], bv_[j], acc2[m][j], 0, 0, 0);
            }
    }

    // epilogue 2: bias; chunk max; DMA restage i3 (single); weighted sums
#pragma unroll
    for (int m = 0; m < 4; ++m) {
        const float4 bv = *(const float4*)&ba2[wy*64 + m*16 + l4*4];
#pragma unroll
        for (int j = 0; j < 4; ++j) {
            acc2[m][j][0] += bv.x; acc2[m][j][1] += bv.y;
            acc2[m][j][2] += bv.z; acc2[m][j][3] += bv.w;
        }
    }
#pragma unroll
    for (int m = 0; m < 4; ++m)
#pragma unroll
        for (int rg = 0; rg < 4; ++rg) {
            int n = wy*64 + m*16 + l4*4 + rg;
            float mx = -INFINITY;
#pragma unroll
            for (int j = 0; j < 4; ++j) {
                int tg = t0 + wx*64 + j*16 + l16;
                if (tg < T_) mx = fmaxf(mx, acc2[m][j][rg]);
            }
            mx = fmaxf(mx, __shfl_xor(mx, 1));
            mx = fmaxf(mx, __shfl_xor(mx, 2));
            mx = fmaxf(mx, __shfl_xor(mx, 4));
            mx = fmaxf(mx, __shfl_xor(mx, 8));
            if (l16 == 0) redM[wx][n] = mx;
        }
    __syncthreads();                               // stage-2 smem reads done
    for (int c0 = wid*64; c0 < 2048; c0 += 256) {  // restage 128x128 single plane
        int ck = c0 + lane;
        int r  = ck >> 4, wc = ck & 15;
        int sc = wc ^ (r & 7);
        gload16(As + xrow + (size_t)r*128 + sc*8, (char*)xs_ + (size_t)c0*16);
    }
    __syncthreads();
#pragma unroll
    for (int m = 0; m < 4; ++m)
#pragma unroll
        for (int rg = 0; rg < 4; ++rg) {
            int n = wy*64 + m*16 + l4*4 + rg;
            const float mch = fmaxf(redM[0][n], redM[1][n]);
            float se = 0.0f, am = 0.0f, aq = 0.0f;
#pragma unroll
            for (int j = 0; j < 4; ++j) {
                int tl = wx*64 + j*16 + l16;
                int tg = t0 + tl;
                if (tg < T_) {
                    float p = expf(acc2[m][j][rg] - mch);
                    unsigned byte = ((unsigned)(tl*128 + n))*2u ^ ((unsigned)((tl & 7) << 4));
                    float x = bf2f(*(const ushort_t*)((const char*)xs_ + byte));
                    se += p; am += p*x; aq += p*x*x;
                }
            }
#pragma unroll
            for (int d = 1; d <= 8; d <<= 1) {
                se += __shfl_xor(se, d);
                am += __shfl_xor(am, d);
                aq += __shfl_xor(aq, d);
            }
            if (l16 == 0) { redS[wx][n] = se; redAM[wx][n] = am; redAQ[wx][n] = aq; }
        }
    __syncthreads();
    if (tid < 128) {
        float m0 = redM[0][tid], m1 = redM[1][tid];
        float M  = fmaxf(m0, m1);
        size_t o = ((size_t)b*NCH + ch)*128 + tid;
        pm[o]  = M;
        ps[o]  = redS[0][tid]  + redS[1][tid];
        pcm[o] = redAM[0][tid] + redAM[1][tid];
        pcq[o] = redAQ[0][tid] + redAQ[1][tid];
    }
}

// ---------------------------------------------------------------------------
__global__ void sm_pass_b(const float* __restrict__ pm, const float* __restrict__ ps,
                          float* __restrict__ Ms, float* __restrict__ Ss) {
    const int c = threadIdx.x, b = blockIdx.x;
    float M = -INFINITY;
    for (int ch = 0; ch < NCH; ++ch) M = fmaxf(M, pm[((size_t)b*NCH + ch)*128 + c]);
    float S = 0.0f;
    for (int ch = 0; ch < NCH; ++ch) {
        float m = pm[((size_t)b*NCH + ch)*128 + c];
        if (m > -INFINITY) S += ps[((size_t)b*NCH + ch)*128 + c] * expf(m - M);
    }
    Ms[b*128 + c] = M;
    Ss[b*128 + c] = S;
}

// stats (rescaled chunk partials) -> layernorm(256) -> linear 256->512
__global__ void final_kernel(const float* __restrict__ pcm, const float* __restrict__ pcq,
                             const float* __restrict__ pm,
                             const float* __restrict__ Ms, const float* __restrict__ Ss,
                             const float* __restrict__ gamma, const float* __restrict__ beta,
                             const float* __restrict__ w2, const float* __restrict__ b2,
                             float* __restrict__ out) {
    __shared__ float row[256];
    __shared__ float nrm[256];
    __shared__ float red[8];
    const int tid = threadIdx.x, b = blockIdx.x;
    if (tid < 128) {
        const float M = Ms[b*128 + tid];
        float sm = 0.0f, sq = 0.0f;
        for (int ch = 0; ch < NCH; ++ch) {
            size_t o = ((size_t)b*NCH + ch)*128 + tid;
            float m = pm[o];
            if (m > -INFINITY) {
                float e = expf(m - M);
                sm += pcm[o]*e;
                sq += pcq[o]*e;
            }
        }
        float S = Ss[b*128 + tid];
        float mean = sm / S;
        float q    = sq / S;
        float resid = q - mean*mean;
        float stdv  = sqrtf(fmaxf(resid, 1e-9f));
        row[tid]       = mean;
        row[128 + tid] = stdv;
    }
    __syncthreads();
    float v  = row[tid];
    float s1 = v, s2 = v*v;
    for (int off = 32; off >= 1; off >>= 1) {
        s1 += __shfl_down(s1, off, 64);
        s2 += __shfl_down(s2, off, 64);
    }
    if ((tid & 63) == 0) { red[tid >> 6] = s1; red[4 + (tid >> 6)] = s2; }
    __syncthreads();
    float S1 = red[0] + red[1] + red[2] + red[3];
    float S2 = red[4] + red[5] + red[6] + red[7];
    float mu  = S1 / 256.0f;
    float var = S2 / 256.0f - mu*mu;
    float inv = 1.0f / sqrtf(var + 1e-5f);
    nrm[tid] = (v - mu)*inv*gamma[tid] + beta[tid];
    __syncthreads();
#pragma unroll
    for (int oo = 0; oo < 2; ++oo) {
        int o = tid + oo*256;
        float acc = b2[o];
        const float4* wr = (const float4*)&w2[(size_t)o*256];
        for (int j = 0; j < 64; ++j) {
            float4 w = wr[j];
            acc += w.x*nrm[j*4] + w.y*nrm[j*4+1] + w.z*nrm[j*4+2] + w.w*nrm[j*4+3];
        }
        out[(size_t)b*512 + o] = acc;
    }
}

// ---------------------------------------------------------------------------
extern "C" void kernel_launch(void* const* d_in, const int* in_sizes, int n_in,
                              void* d_out, int out_size, void* d_ws, size_t ws_size,
                              hipStream_t stream) {
    const float* x      = (const float*)d_in[0];
    const float* bp     = (const float*)d_in[1];
    const float* w_lin1 = (const float*)d_in[2];
    const float* b_lin1 = (const float*)d_in[3];
    const float* wc1    = (const float*)d_in[4];
    const float* bc1    = (const float*)d_in[5];
    const float* wc2    = (const float*)d_in[6];
    const float* bc2    = (const float*)d_in[7];
    const float* wc3    = (const float*)d_in[8];
    const float* bc3    = (const float*)d_in[9];
    const float* wa1    = (const float*)d_in[10];
    const float* ba1    = (const float*)d_in[11];
    const float* wa2    = (const float*)d_in[12];
    const float* ba2    = (const float*)d_in[13];
    const float* gamma  = (const float*)d_in[14];
    const float* beta   = (const float*)d_in[15];
    const float* wl2    = (const float*)d_in[16];
    const float* bl2    = (const float*)d_in[17];

    float* ws   = (float*)d_ws;
    float* bs   = ws + OFF_BS;
    ushort_t* weh  = (ushort_t*)(ws + OFF_WEFF);
    ushort_t* wel  = weh + 64*320;
    float* wtail   = ws + OFF_WTAIL;
    ushort_t* w1h  = (ushort_t*)(ws + OFF_W1);
    ushort_t* w1l  = w1h + 3*128*64;
    ushort_t* w2h  = (ushort_t*)(ws + OFF_W2);
    ushort_t* w2l  = w2h + 3*128*128;
    ushort_t* w3h  = (ushort_t*)(ws + OFF_W3);
    ushort_t* w3l  = w3h + 3*128*128;
    ushort_t* wa1h = (ushort_t*)(ws + OFF_WA1);
    ushort_t* wa1l = wa1h + 64*128;
    ushort_t* wa2h = (ushort_t*)(ws + OFF_WA2);
    ushort_t* wa2l = wa2h + 128*64;
    float* pm   = ws + OFF_PM;
    float* ps   = ws + OFF_PS;
    float* Ms   = ws + OFF_MS;
    float* Ss   = ws + OFF_SS;
    float* pcm  = ws + OFF_PCM;
    float* pcq  = ws + OFF_PCQ;
    ushort_t* Hs = (ushort_t*)(ws + OFF_HS);
    ushort_t* As = (ushort_t*)(ws + OFF_AS);
    ushort_t* Bs = (ushort_t*)(ws + OFF_BSP);

    sort_kernel<<<dim3(1), dim3(64), 0, stream>>>(bp, bs);
    prep_kernel<<<dim3(624), dim3(256), 0, stream>>>(bs, w_lin1, wc1, wc2, wc3, wa1, wa2,
                                                     weh, wel, wtail, w1h, w1l, w2h, w2l,
                                                     w3h, w3l, wa1h, wa1l, wa2h, wa2l);
    // h = relu(x @ Weff^T + b_lin1) -> single bf16 plane
    lin1_mfma<<<dim3(R_/128), dim3(256), 0, stream>>>(x, weh, wel, wtail, b_lin1, Hs);
    // i1 = conv1(h) + b
    dconv1_mfma<<<dim3(47, B_), dim3(256), 0, stream>>>(Hs, w1h, w1l, bc1, As);
    // i3 = conv3(conv2(i1)+b2+2*i1) + b3 + s  (s in LDS only)
    dconv23_fused<<<dim3(63, B_), dim3(512), 0, stream>>>(As, w2h, w2l, w3h, w3l,
                                                          bc2, bc3, Bs);
    // fused asp1+asp2+softmax partials+weighted stats
    asp_fused<<<dim3(NCH, B_), dim3(256), 0, stream>>>(Bs, wa1h, wa1l, wa2h, wa2l,
                                                       ba1, ba2, pm, ps, pcm, pcq);
    sm_pass_b<<<dim3(B_), dim3(128), 0, stream>>>(pm, ps, Ms, Ss);
    final_kernel<<<dim3(B_), dim3(256), 0, stream>>>(pcm, pcq, pm, Ms, Ss, gamma, beta,
                                                     wl2, bl2, (float*)d_out);
}

// Round 14
// 368.555 us; speedup vs baseline: 1.3541x; 1.0922x over previous
//
#include <hip/hip_runtime.h>
#include <math.h>

// ---------------------------------------------------------------------------
// ResCNN_ASP_SpeakerEncoder — v13: column-tiled wave decomposition in convs
// (each weight chunk feeds 4 row-fragments => 4x L2 arithmetic intensity,
// no cross-wave duplicate weight loads). Single-bf16 activations (v12),
// split weights (2-pass MFMA), conv2+conv3 fused, ASP fused.
// ---------------------------------------------------------------------------

constexpr int B_  = 64;
constexpr int T_  = 3000;
constexpr int NB_ = 257;   // NBINS
constexpr int R_  = B_ * T_;           // 192000 rows
constexpr int NCH = 24;                // softmax T-chunks (24 x 128)
constexpr int CHL = 128;

// workspace layout (float offsets)
constexpr size_t OFF_BS    = 0;
constexpr size_t OFF_WEFF  = 128;                          // ushort hi[64*320]+lo
constexpr size_t OFF_WTAIL = OFF_WEFF + 20480;
constexpr size_t OFF_W1    = OFF_WTAIL + 128;              // ushort hi+lo 3*128*64
constexpr size_t OFF_W2    = OFF_W1  + 3*64*128;
constexpr size_t OFF_W3    = OFF_W2  + 3*128*128;
constexpr size_t OFF_WA1   = OFF_W3  + 3*128*128;
constexpr size_t OFF_WA2   = OFF_WA1 + 8192;
constexpr size_t SZ_P      = (size_t)B_*NCH*128;
constexpr size_t OFF_PM    = OFF_WA2 + 8192;
constexpr size_t OFF_PS    = OFF_PM  + SZ_P;
constexpr size_t OFF_MS    = OFF_PS  + SZ_P;
constexpr size_t OFF_SS    = OFF_MS  + (size_t)B_*128;
constexpr size_t OFF_PCM   = OFF_SS  + (size_t)B_*128;
constexpr size_t OFF_PCQ   = OFF_PCM + SZ_P;
// single bf16 planes (ushort counts -> float counts /2)
constexpr size_t OFF_HS    = OFF_PCQ + SZ_P;               // h  [R*64]u
constexpr size_t OFF_AS    = OFF_HS  + (size_t)R_*32;      // i1 [R*128]u
constexpr size_t OFF_BSP   = OFF_AS  + (size_t)R_*64;      // i3 [R*128]u

typedef __attribute__((ext_vector_type(8))) short  bf16x8;
typedef __attribute__((ext_vector_type(4))) float  f32x4;
typedef __attribute__((ext_vector_type(4), aligned(4))) float float4a;
typedef unsigned short ushort_t;

typedef __attribute__((address_space(3))) unsigned int        as3_u32;
typedef const __attribute__((address_space(1))) unsigned int  as1_u32c;
__device__ __forceinline__ void gload16(const void* g, void* l) {
    __builtin_amdgcn_global_load_lds((as1_u32c*)g, (as3_u32*)l, 16, 0, 0);
}

__device__ inline ushort_t f2bf(float f) {                // RNE f32->bf16
    unsigned u = __float_as_uint(f);
    unsigned r = u + 0x7FFFu + ((u >> 16) & 1u);
    return (ushort_t)(r >> 16);
}
__device__ inline float bf2f(ushort_t h) {
    return __uint_as_float(((unsigned)h) << 16);
}
__device__ inline void split2(float v, ushort_t &h, ushort_t &l) {
    h = f2bf(v);
    l = f2bf(v - bf2f(h));
}

// pack 4 f32 -> 4 bf16 (RNE, 2 u32)
__device__ inline void pack_hi4(float x, float y, float z, float w, uint2 &ph) {
    unsigned hx, hy;
    asm("v_cvt_pk_bf16_f32 %0, %1, %2" : "=v"(hx) : "v"(x), "v"(y));
    asm("v_cvt_pk_bf16_f32 %0, %1, %2" : "=v"(hy) : "v"(z), "v"(w));
    ph.x = hx; ph.y = hy;
}

// ---------------------------------------------------------------------------
__global__ void sort_kernel(const float* __restrict__ bp, float* __restrict__ bs) {
    if (threadIdx.x == 0) {
        float tmp[82];
        for (int i = 0; i < 82; ++i) tmp[i] = bp[i];
        for (int i = 1; i < 82; ++i) {
            float key = tmp[i];
            int j = i - 1;
            while (j >= 0 && tmp[j] > key) { tmp[j+1] = tmp[j]; --j; }
            tmp[j+1] = key;
        }
        for (int i = 0; i < 82; ++i) bs[i] = tmp[i];
    }
}

// Fragment-order packing (B: lane&15=col, lane>>4=k-octet; A: lane&15=row).
__global__ void prep_kernel(const float* __restrict__ bs, const float* __restrict__ wl1,
                            const float* __restrict__ wc1, const float* __restrict__ wc2,
                            const float* __restrict__ wc3, const float* __restrict__ wa1,
                            const float* __restrict__ wa2,
                            ushort_t* __restrict__ weh, ushort_t* __restrict__ wel,
                            float* __restrict__ wtail,
                            ushort_t* __restrict__ w1h, ushort_t* __restrict__ w1l,
                            ushort_t* __restrict__ w2h, ushort_t* __restrict__ w2l,
                            ushort_t* __restrict__ w3h, ushort_t* __restrict__ w3l,
                            ushort_t* __restrict__ wa1h, ushort_t* __restrict__ wa1l,
                            ushort_t* __restrict__ wa2h, ushort_t* __restrict__ wa2l) {
    int gid = blockIdx.x * 256 + threadIdx.x;
    if (gid < 64*320) {                            // Weff[o][f]
        int o = gid / 320, f = gid % 320;
        if (f > 256) return;
        float acc = 0.0f;
        if (f == 0) acc = wl1[o*80];               // filt[:,:,0] = x[:,:,0]
        else {
            for (int n = 1; n < 79; ++n) {
                float bn = bs[n], bn1 = bs[n+1], bn2 = bs[n+2];
                int ibn  = (int)floorf(bn);
                int ibn1 = (int)floorf(bn1);
                int ibn2 = (int)floorf(bn2);
                float fbv = 0.0f;
                if (f >= ibn && f < ibn1) {
                    float d = (bn1-bn)*(bn1-bn);
                    fbv = ((float)f - bn) / (d > 0.0f ? d : 1.0f);
                } else if (f >= ibn1 && f < ibn2) {
                    float d = (bn2-bn1)*(bn2-bn1);
                    fbv = (bn2 - (float)f) / (d > 0.0f ? d : 1.0f);
                }
                acc += wl1[o*80 + n] * fbv;
            }
        }
        if (f == 256) { wtail[o] = acc; return; }
        int kc = f >> 5, lane = ((f & 31) >> 3)*16 + (o & 15), e = f & 7;
        size_t dst = (((size_t)kc*4 + (o >> 4))*64 + lane)*8 + e;
        split2(acc, weh[dst], wel[dst]);
        return;
    }
    gid -= 64*320;
    if (gid < 3*128*64) {                          // conv1: [k][c][ci=64]
        int k = gid / (128*64), rem = gid % (128*64);
        int c = rem >> 6, ci = rem & 63;
        float v = wc1[(c*64 + ci)*3 + k];
        int lane = ((ci & 31) >> 3)*16 + (c & 15), e = ci & 7;
        size_t dst = ((((size_t)k*2 + (ci >> 5))*8 + (c >> 4))*64 + lane)*8 + e;
        split2(v, w1h[dst], w1l[dst]);
        return;
    }
    gid -= 3*128*64;
    if (gid < 3*128*128) {                         // conv2
        int k = gid / (128*128), rem = gid % (128*128);
        int c = rem >> 7, ci = rem & 127;
        float v = wc2[(c*128 + ci)*3 + k];
        int lane = ((ci & 31) >> 3)*16 + (c & 15), e = ci & 7;
        size_t dst = ((((size_t)k*4 + (ci >> 5))*8 + (c >> 4))*64 + lane)*8 + e;
        split2(v, w2h[dst], w2l[dst]);
        return;
    }
    gid -= 3*128*128;
    if (gid < 3*128*128) {                         // conv3
        int k = gid / (128*128), rem = gid % (128*128);
        int c = rem >> 7, ci = rem & 127;
        float v = wc3[(c*128 + ci)*3 + k];
        int lane = ((ci & 31) >> 3)*16 + (c & 15), e = ci & 7;
        size_t dst = ((((size_t)k*4 + (ci >> 5))*8 + (c >> 4))*64 + lane)*8 + e;
        split2(v, w3h[dst], w3l[dst]);
        return;
    }
    gid -= 3*128*128;
    if (gid < 64*128) {                            // wa1 [c=64][ci=128]
        int c = gid >> 7, ci = gid & 127;
        float v = wa1[gid];
        int lane = ((ci & 31) >> 3)*16 + (c & 15), e = ci & 7;
        size_t dst = (((size_t)(ci >> 5)*4 + (c >> 4))*64 + lane)*8 + e;
        split2(v, wa1h[dst], wa1l[dst]);
        return;
    }
    gid -= 64*128;
    if (gid < 128*64) {                            // wa2 [n=128][ci=64] (A op)
        int n = gid >> 6, ci = gid & 63;
        float v = wa2[gid];
        int lane = ((ci & 31) >> 3)*16 + (n & 15), e = ci & 7;
        size_t dst = (((size_t)(ci >> 5)*8 + (n >> 4))*64 + lane)*8 + e;
        split2(v, wa2h[dst], wa2l[dst]);
        return;
    }
}

// ---------------------------------------------------------------------------
// lin1: h = relu(x @ Weff^T + b); x staged as single bf16; 2-pass MFMA.
__launch_bounds__(256)
__global__ void lin1_mfma(const float* __restrict__ X,
                          const ushort_t* __restrict__ Wh, const ushort_t* __restrict__ Wl,
                          const float* __restrict__ wtail,
                          const float* __restrict__ bias,
                          ushort_t* __restrict__ Hs) {
    __shared__ __align__(16) ushort_t ash[128*64];
    __shared__ float xs[128];
    __shared__ float wts[64];
    const int tid  = threadIdx.x;
    const int lane = tid & 63;
    const int wid  = tid >> 6;
    const int wy   = wid >> 1, wx = wid & 1;
    const int l16  = lane & 15, l4 = lane >> 4;
    const int r0   = blockIdx.x * 128;

    if (tid < 128)       xs[tid] = X[(size_t)(r0 + tid)*NB_ + 256];
    else if (tid < 192)  wts[tid - 128] = wtail[tid - 128];

#define LIN1_LOAD(dst, k0)                                            \
    _Pragma("unroll")                                                 \
    for (int i = 0; i < 8; ++i) {                                     \
        int q = tid + i*256; int r = q >> 4, cc = (q & 15) << 2;      \
        dst[i] = *(const float4a*)(X + (size_t)(r0 + r)*NB_ + (k0) + cc); \
    }
#define LIN1_CW(src)                                                  \
    _Pragma("unroll")                                                 \
    for (int i = 0; i < 8; ++i) {                                     \
        int q = tid + i*256; int r = q >> 4, cc = (q & 15) << 2;      \
        uint2 ph;                                                     \
        pack_hi4(src[i].x, src[i].y, src[i].z, src[i].w, ph);         \
        unsigned byte = ((unsigned)(r*64 + cc))*2u ^ ((unsigned)((r & 7) << 4)); \
        *(uint2*)((char*)ash + byte) = ph;                            \
    }

    float4a bufA[8], bufB[8];
    LIN1_LOAD(bufA, 0);

    f32x4 acc[4][2];
    const f32x4 z = {0.f,0.f,0.f,0.f};
#pragma unroll
    for (int m = 0; m < 4; ++m) { acc[m][0] = z; acc[m][1] = z; }

#pragma unroll
    for (int ck = 0; ck < 4; ++ck) {
        const float4a* cur = (ck & 1) ? bufB : bufA;
        float4a*       nxt = (ck & 1) ? bufA : bufB;
        if (ck < 3) LIN1_LOAD(nxt, (ck + 1)*64);
        LIN1_CW(cur);
        __syncthreads();
#pragma unroll
        for (int kk = 0; kk < 64; kk += 32) {
            bf16x8 bh[2], bl[2];
#pragma unroll
            for (int n = 0; n < 2; ++n) {
                size_t off = (((size_t)(ck*2 + (kk >> 5))*4 + wx*2 + n)*64 + lane)*8;
                bh[n] = *(const bf16x8*)(Wh + off);
                bl[n] = *(const bf16x8*)(Wl + off);
            }
            bf16x8 fh[4];
#pragma unroll
            for (int m = 0; m < 4; ++m) {
                int r = wy*64 + m*16 + l16;
                unsigned byte = ((unsigned)(r*64 + kk + l4*8))*2u ^ ((unsigned)((r & 7) << 4));
                fh[m] = *(const bf16x8*)((const char*)ash + byte);
            }
#pragma unroll
            for (int m = 0; m < 4; ++m)
#pragma unroll
                for (int n = 0; n < 2; ++n) {
                    acc[m][n] = __builtin_amdgcn_mfma_f32_16x16x32_bf16(fh[m], bh[n], acc[m][n], 0, 0, 0);
                    acc[m][n] = __builtin_amdgcn_mfma_f32_16x16x32_bf16(fh[m], bl[n], acc[m][n], 0, 0, 0);
                }
        }
        __syncthreads();
    }
#undef LIN1_LOAD
#undef LIN1_CW

#pragma unroll
    for (int m = 0; m < 4; ++m)
#pragma unroll
        for (int n = 0; n < 2; ++n) {
            int c = wx*32 + n*16 + l16;
            float bv = bias[c];
            float wc = wts[c];
            int rbl = wy*64 + m*16 + l4*4;
#pragma unroll
            for (int rg = 0; rg < 4; ++rg) {
                int rl = rbl + rg;
                float v = fmaxf(acc[m][n][rg] + bv + xs[rl]*wc, 0.0f);
                Hs[(size_t)(r0 + rl)*64 + c] = f2bf(v);
            }
        }
}

// ---------------------------------------------------------------------------
// conv1 (CIN=64, DIL=2): column-tiled waves — wave owns 32 cols, loops 4
// row-fragments per weight chunk (4 MFMA/KB; W1 read once per block).
__launch_bounds__(256, 4)
__global__ void dconv1_mfma(const ushort_t* __restrict__ Xs,
                            const ushort_t* __restrict__ Wh, const ushort_t* __restrict__ Wl,
                            const float* __restrict__ bias,
                            ushort_t* __restrict__ Ys) {
    constexpr int CIN = 64, DIL = 2;
    constexpr int TT  = 64;
    constexpr int HS  = TT + 2*DIL;        // 68
    constexpr int NCK = HS*8;              // 16B chunks (8 per row)
    constexpr int NCKP = ((NCK + 255)/256)*256;
    __shared__ __align__(16) ushort_t hs_[NCKP*8];

    const int tid  = threadIdx.x;
    const int lane = tid & 63;
    const int wid  = tid >> 6;            // 0..3: cols wid*32 + n*16
    const int l16  = lane & 15;
    const int l4   = lane >> 4;
    const int t0   = blockIdx.x * TT;
    const int b    = blockIdx.y;

    const long long rowbase = ((long long)b*T_ + (t0 - DIL)) * CIN;
    for (int c0 = wid*64; c0 < NCKP; c0 += 256) {
        int ck = c0 + lane;
        int r  = ck >> 3;
        int sc = ck ^ (r & 7);
        gload16(Xs + rowbase + (long long)sc*8, (char*)hs_ + (size_t)c0*16);
    }
    __syncthreads();
    if (t0 < DIL || t0 + TT + DIL > T_) {
        for (int idx = tid; idx < HS*CIN/4; idx += 256) {
            int e = idx << 2;
            int r = e / CIN, ci = e % CIN;
            int t = t0 - DIL + r;
            if (t < 0 || t >= T_) {
                unsigned byte = ((unsigned)(r*CIN + ci))*2u ^ ((unsigned)((r & 7) << 4));
                *(uint2*)((char*)hs_ + byte) = make_uint2(0u, 0u);
            }
        }
        __syncthreads();
    }

    f32x4 acc[4][2];
    const f32x4 z = {0.f, 0.f, 0.f, 0.f};
#pragma unroll
    for (int m = 0; m < 4; ++m)
#pragma unroll
        for (int n = 0; n < 2; ++n) acc[m][n] = z;

#pragma unroll
    for (int k = 0; k < 3; ++k) {
#pragma unroll
        for (int cb = 0; cb < 2; ++cb) {
            bf16x8 bh[2], bl[2];
#pragma unroll
            for (int n = 0; n < 2; ++n) {
                size_t off = ((((size_t)k*2 + cb)*8 + wid*2 + n)*64 + lane)*8;
                bh[n] = *(const bf16x8*)(Wh + off);
                bl[n] = *(const bf16x8*)(Wl + off);
            }
            bf16x8 ah[4];
#pragma unroll
            for (int m = 0; m < 4; ++m) {
                int r = m*16 + l16 + k*DIL;
                unsigned byte = ((unsigned)(r*CIN + cb*32 + l4*8))*2u
                              ^ ((unsigned)((r & 7) << 4));
                ah[m] = *(const bf16x8*)((const char*)hs_ + byte);
            }
#pragma unroll
            for (int m = 0; m < 4; ++m)
#pragma unroll
                for (int n = 0; n < 2; ++n) {
                    acc[m][n] = __builtin_amdgcn_mfma_f32_16x16x32_bf16(ah[m], bh[n], acc[m][n], 0, 0, 0);
                    acc[m][n] = __builtin_amdgcn_mfma_f32_16x16x32_bf16(ah[m], bl[n], acc[m][n], 0, 0, 0);
                }
        }
    }

#pragma unroll
    for (int m = 0; m < 4; ++m) {
        int tl_base = m*16 + l4*4;
#pragma unroll
        for (int n = 0; n < 2; ++n) {
            int c = wid*32 + n*16 + l16;
            float bv = bias[c];
#pragma unroll
            for (int rg = 0; rg < 4; ++rg) {
                int tl = tl_base + rg;
                int t  = t0 + tl;
                if (t < T_) {
                    float v = acc[m][n][rg] + bv;
                    Ys[((size_t)b*T_ + t)*128 + c] = f2bf(v);
                }
            }
        }
    }
}

// ---------------------------------------------------------------------------
// Fused conv2+conv3, column-tiled waves in BOTH phases: wave owns 16 cols,
// loops 4 (phase1) / 3 (phase2) row-fragments per weight chunk.
__launch_bounds__(512, 8)
__global__ void dconv23_fused(const ushort_t* __restrict__ Xs,
                              const ushort_t* __restrict__ W2h, const ushort_t* __restrict__ W2l,
                              const ushort_t* __restrict__ W3h, const ushort_t* __restrict__ W3l,
                              const float* __restrict__ bc2, const float* __restrict__ bc3,
                              ushort_t* __restrict__ Ys) {
    constexpr int TT = 48;
    __shared__ __align__(16) ushort_t i1s[64*128];   // rows t0-8 .. t0+55
    __shared__ __align__(16) ushort_t ss_[64*128];

    const int tid  = threadIdx.x;
    const int lane = tid & 63;
    const int wid  = tid >> 6;            // 0..7: cols wid*16 + l16
    const int l16  = lane & 15, l4 = lane >> 4;
    const int t0   = blockIdx.x * TT;
    const int b    = blockIdx.y;

    const long long rowbase = ((long long)b*T_ + (t0 - 8)) * 128;
    for (int c0 = wid*64; c0 < 1024; c0 += 512) {
        int ck = c0 + lane;
        int r  = ck >> 4;
        int sc = ck ^ (r & 7);
        gload16(Xs + rowbase + (long long)sc*8, (char*)i1s + (size_t)c0*16);
    }
    __syncthreads();
    if (t0 < 8 || t0 + 56 > T_) {
        for (int idx = tid; idx < 64*128/4; idx += 512) {
            int e = idx << 2;
            int r = e >> 7, ci = e & 127;
            int t = t0 - 8 + r;
            if (t < 0 || t >= T_) {
                unsigned byte = ((unsigned)(r*128 + ci))*2u ^ ((unsigned)((r & 7) << 4));
                *(uint2*)((char*)i1s + byte) = make_uint2(0u, 0u);
            }
        }
        __syncthreads();
    }

    // ---- phase 1: conv2, all 64 local rows, wave = 16 cols ----
    {
        f32x4 acc[4];
        const f32x4 z = {0.f,0.f,0.f,0.f};
#pragma unroll
        for (int m = 0; m < 4; ++m) acc[m] = z;
#pragma unroll
        for (int k = 0; k < 3; ++k) {
#pragma unroll
            for (int cb = 0; cb < 4; ++cb) {
                size_t off = ((((size_t)k*4 + cb)*8 + wid)*64 + lane)*8;
                bf16x8 bh = *(const bf16x8*)(W2h + off);
                bf16x8 bl = *(const bf16x8*)(W2l + off);
                bf16x8 ah[4];
#pragma unroll
                for (int m = 0; m < 4; ++m) {
                    int r = m*16 + l16 + k*3 - 3;
                    r = min(max(r, 0), 63);   // garbage edge rows; never consumed
                    unsigned byte = ((unsigned)(r*128 + cb*32 + l4*8))*2u
                                  ^ ((unsigned)((r & 7) << 4));
                    ah[m] = *(const bf16x8*)((const char*)i1s + byte);
                }
#pragma unroll
                for (int m = 0; m < 4; ++m) {
                    acc[m] = __builtin_amdgcn_mfma_f32_16x16x32_bf16(ah[m], bh, acc[m], 0, 0, 0);
                    acc[m] = __builtin_amdgcn_mfma_f32_16x16x32_bf16(ah[m], bl, acc[m], 0, 0, 0);
                }
            }
        }
        const int c = wid*16 + l16;
        const float bv = bc2[c];
#pragma unroll
        for (int m = 0; m < 4; ++m) {
#pragma unroll
            for (int rg = 0; rg < 4; ++rg) {
                int rl = m*16 + l4*4 + rg;
                int t  = t0 - 8 + rl;
                float v = 0.0f;
                unsigned byte = ((unsigned)(rl*128 + c))*2u ^ ((unsigned)((rl & 7) << 4));
                if (t >= 0 && t < T_) {
                    float cen = bf2f(*(const ushort_t*)((const char*)i1s + byte));
                    v = acc[m][rg] + bv + 2.0f*cen;
                }
                *(ushort_t*)((char*)ss_ + byte) = f2bf(v);
            }
        }
    }
    __syncthreads();

    // ---- phase 2: conv3 over 48 output rows, wave = 16 cols ----
    {
        f32x4 acc[3];
        const f32x4 z = {0.f,0.f,0.f,0.f};
#pragma unroll
        for (int m = 0; m < 3; ++m) acc[m] = z;
#pragma unroll
        for (int k = 0; k < 3; ++k) {
#pragma unroll
            for (int cb = 0; cb < 4; ++cb) {
                size_t off = ((((size_t)k*4 + cb)*8 + wid)*64 + lane)*8;
                bf16x8 bh = *(const bf16x8*)(W3h + off);
                bf16x8 bl = *(const bf16x8*)(W3l + off);
                bf16x8 ah[3];
#pragma unroll
                for (int m = 0; m < 3; ++m) {
                    int r = 4 + m*16 + l16 + k*4;      // in [4,59]
                    unsigned byte = ((unsigned)(r*128 + cb*32 + l4*8))*2u
                                  ^ ((unsigned)((r & 7) << 4));
                    ah[m] = *(const bf16x8*)((const char*)ss_ + byte);
                }
#pragma unroll
                for (int m = 0; m < 3; ++m) {
                    acc[m] = __builtin_amdgcn_mfma_f32_16x16x32_bf16(ah[m], bh, acc[m], 0, 0, 0);
                    acc[m] = __builtin_amdgcn_mfma_f32_16x16x32_bf16(ah[m], bl, acc[m], 0, 0, 0);
                }
            }
        }
        const int c = wid*16 + l16;
        const float bv = bc3[c];
#pragma unroll
        for (int m = 0; m < 3; ++m) {
#pragma unroll
            for (int rg = 0; rg < 4; ++rg) {
                int rl = 8 + m*16 + l4*4 + rg;         // s local row
                int t  = t0 - 8 + rl;
                if (t < T_) {
                    unsigned byte = ((unsigned)(rl*128 + c))*2u ^ ((unsigned)((rl & 7) << 4));
                    float cen = bf2f(*(const ushort_t*)((const char*)ss_ + byte));
                    float v = acc[m][rg] + bv + cen;
                    Ys[((size_t)b*T_ + t)*128 + c] = f2bf(v);
                }
            }
        }
    }
}

// ---------------------------------------------------------------------------
// Fused ASP (single-plane i3; weights split => 2-pass). LDS 32KB + reds.
__launch_bounds__(256)
__global__ void asp_fused(const ushort_t* __restrict__ As,
                          const ushort_t* __restrict__ Wa1h, const ushort_t* __restrict__ Wa1l,
                          const ushort_t* __restrict__ Wa2h, const ushort_t* __restrict__ Wa2l,
                          const float* __restrict__ ba1, const float* __restrict__ ba2,
                          float* __restrict__ pm, float* __restrict__ ps,
                          float* __restrict__ pcm, float* __restrict__ pcq) {
    __shared__ __align__(16) char smem[32768];
    ushort_t* as_ = (ushort_t*)smem;               // [128][64] stage-1 A
    ushort_t* vs_ = (ushort_t*)(smem + 16384);     // v [128][64]
    ushort_t* xs_ = (ushort_t*)smem;               // [128][128] i3 (after stage 2)
    __shared__ float redM[2][128];
    __shared__ float redS[2][128];
    __shared__ float redAM[2][128];
    __shared__ float redAQ[2][128];

    const int tid  = threadIdx.x;
    const int lane = tid & 63;
    const int wid  = tid >> 6;
    const int wy   = wid >> 1, wx = wid & 1;
    const int l16  = lane & 15, l4 = lane >> 4;
    const int ch   = blockIdx.x;
    const int b    = blockIdx.y;
    const int t0   = ch * CHL;
    const size_t xrow = ((size_t)b*T_ + t0) * 128;

    // ---- stage 1: v = tanh(i3 @ wa1^T + ba1), K=128 in 2 chunks ----
    f32x4 acc1[4][2];
    const f32x4 z = {0.f,0.f,0.f,0.f};
#pragma unroll
    for (int m = 0; m < 4; ++m) { acc1[m][0] = z; acc1[m][1] = z; }

    for (int k0 = 0; k0 < 128; k0 += 64) {
        __syncthreads();
        for (int c0 = wid*64; c0 < 1024; c0 += 256) {
            int ck = c0 + lane;
            int r  = ck >> 3, wc = ck & 7;
            int sc = wc ^ (r & 7);
            gload16(As + xrow + (size_t)r*128 + k0 + sc*8, (char*)as_ + (size_t)c0*16);
        }
        __syncthreads();
#pragma unroll
        for (int kk = 0; kk < 64; kk += 32) {
            bf16x8 bh[2], bl[2];
#pragma unroll
            for (int n = 0; n < 2; ++n) {
                size_t off = (((size_t)((k0 + kk) >> 5)*4 + wx*2 + n)*64 + lane)*8;
                bh[n] = *(const bf16x8*)(Wa1h + off);
                bl[n] = *(const bf16x8*)(Wa1l + off);
            }
            bf16x8 fh[4];
#pragma unroll
            for (int m = 0; m < 4; ++m) {
                int r = wy*64 + m*16 + l16;
                unsigned byte = ((unsigned)(r*64 + kk + l4*8))*2u ^ ((unsigned)((r & 7) << 4));
                fh[m] = *(const bf16x8*)((const char*)as_ + byte);
            }
#pragma unroll
            for (int m = 0; m < 4; ++m)
#pragma unroll
                for (int n = 0; n < 2; ++n) {
                    acc1[m][n] = __builtin_amdgcn_mfma_f32_16x16x32_bf16(fh[m], bh[n], acc1[m][n], 0, 0, 0);
                    acc1[m][n] = __builtin_amdgcn_mfma_f32_16x16x32_bf16(fh[m], bl[n], acc1[m][n], 0, 0, 0);
                }
        }
    }
    // epilogue 1: tanh, write v (single bf16) to LDS
#pragma unroll
    for (int m = 0; m < 4; ++m)
#pragma unroll
        for (int n = 0; n < 2; ++n) {
            int c = wx*32 + n*16 + l16;
            float bv = ba1[c];
            int rb = wy*64 + m*16 + l4*4;
#pragma unroll
            for (int rg = 0; rg < 4; ++rg) {
                float v = tanhf(acc1[m][n][rg] + bv);
                int r = rb + rg;
                unsigned byte = ((unsigned)(r*64 + c))*2u ^ ((unsigned)((r & 7) << 4));
                *(ushort_t*)((char*)vs_ + byte) = f2bf(v);
            }
        }
    __syncthreads();

    // ---- stage 2: D[n][t] = wa2 . v ----
    f32x4 acc2[4][4];
#pragma unroll
    for (int m = 0; m < 4; ++m)
#pragma unroll
        for (int j = 0; j < 4; ++j) acc2[m][j] = z;

#pragma unroll
    for (int kk = 0; kk < 64; kk += 32) {
        bf16x8 awh[4], awl[4];
#pragma unroll
        for (int m = 0; m < 4; ++m) {
            size_t off = (((size_t)(kk >> 5)*8 + wy*4 + m)*64 + lane)*8;
            awh[m] = *(const bf16x8*)(Wa2h + off);
            awl[m] = *(const bf16x8*)(Wa2l + off);
        }
        bf16x8 bv_[4];
#pragma unroll
        for (int j = 0; j < 4; ++j) {
            int r = wx*64 + j*16 + l16;
            unsigned byte = ((unsigned)(r*64 + kk + l4*8))*2u ^ ((unsigned)((r & 7) << 4));
            bv_[j] = *(const bf16x8*)((const char*)vs_ + byte);
        }
#pragma unroll
        for (int m = 0; m < 4; ++m)
#pragma unroll
            for (int j = 0; j < 4; ++j) {
                acc2[m][j] = __builtin_amdgcn_mfma_f32_16x16x32_bf16(awh[m], bv_[j], acc2[m][j], 0, 0, 0);
                acc2[m][j] = __builtin_amdgcn_mfma_f32_16x16x32_bf16(awl[m], bv_[j], acc2[m][j], 0, 0, 0);
            }
    }

    // epilogue 2: bias; chunk max; DMA restage i3 (single); weighted sums
#pragma unroll
    for (int m = 0; m < 4; ++m) {
        const float4 bv = *(const float4*)&ba2[wy*64 + m*16 + l4*4];
#pragma unroll
        for (int j = 0; j < 4; ++j) {
            acc2[m][j][0] += bv.x; acc2[m][j][1] += bv.y;
            acc2[m][j][2] += bv.z; acc2[m][j][3] += bv.w;
        }
    }
#pragma unroll
    for (int m = 0; m < 4; ++m)
#pragma unroll
        for (int rg = 0; rg < 4; ++rg) {
            int n = wy*64 + m*16 + l4*4 + rg;
            float mx = -INFINITY;
#pragma unroll
            for (int j = 0; j < 4; ++j) {
                int tg = t0 + wx*64 + j*16 + l16;
                if (tg < T_) mx = fmaxf(mx, acc2[m][j][rg]);
            }
            mx = fmaxf(mx, __shfl_xor(mx, 1));
            mx = fmaxf(mx, __shfl_xor(mx, 2));
            mx = fmaxf(mx, __shfl_xor(mx, 4));
            mx = fmaxf(mx, __shfl_xor(mx, 8));
            if (l16 == 0) redM[wx][n] = mx;
        }
    __syncthreads();                               // stage-2 smem reads done
    for (int c0 = wid*64; c0 < 2048; c0 += 256) {  // restage 128x128 single plane
        int ck = c0 + lane;
        int r  = ck >> 4, wc = ck & 15;
        int sc = wc ^ (r & 7);
        gload16(As + xrow + (size_t)r*128 + sc*8, (char*)xs_ + (size_t)c0*16);
    }
    __syncthreads();
#pragma unroll
    for (int m = 0; m < 4; ++m)
#pragma unroll
        for (int rg = 0; rg < 4; ++rg) {
            int n = wy*64 + m*16 + l4*4 + rg;
            const float mch = fmaxf(redM[0][n], redM[1][n]);
            float se = 0.0f, am = 0.0f, aq = 0.0f;
#pragma unroll
            for (int j = 0; j < 4; ++j) {
                int tl = wx*64 + j*16 + l16;
                int tg = t0 + tl;
                if (tg < T_) {
                    float p = expf(acc2[m][j][rg] - mch);
                    unsigned byte = ((unsigned)(tl*128 + n))*2u ^ ((unsigned)((tl & 7) << 4));
                    float x = bf2f(*(const ushort_t*)((const char*)xs_ + byte));
                    se += p; am += p*x; aq += p*x*x;
                }
            }
#pragma unroll
            for (int d = 1; d <= 8; d <<= 1) {
                se += __shfl_xor(se, d);
                am += __shfl_xor(am, d);
                aq += __shfl_xor(aq, d);
            }
            if (l16 == 0) { redS[wx][n] = se; redAM[wx][n] = am; redAQ[wx][n] = aq; }
        }
    __syncthreads();
    if (tid < 128) {
        float m0 = redM[0][tid], m1 = redM[1][tid];
        float M  = fmaxf(m0, m1);
        size_t o = ((size_t)b*NCH + ch)*128 + tid;
        pm[o]  = M;
        ps[o]  = redS[0][tid]  + redS[1][tid];
        pcm[o] = redAM[0][tid] + redAM[1][tid];
        pcq[o] = redAQ[0][tid] + redAQ[1][tid];
    }
}

// ---------------------------------------------------------------------------
__global__ void sm_pass_b(const float* __restrict__ pm, const float* __restrict__ ps,
                          float* __restrict__ Ms, float* __restrict__ Ss) {
    const int c = threadIdx.x, b = blockIdx.x;
    float M = -INFINITY;
    for (int ch = 0; ch < NCH; ++ch) M = fmaxf(M, pm[((size_t)b*NCH + ch)*128 + c]);
    float S = 0.0f;
    for (int ch = 0; ch < NCH; ++ch) {
        float m = pm[((size_t)b*NCH + ch)*128 + c];
        if (m > -INFINITY) S += ps[((size_t)b*NCH + ch)*128 + c] * expf(m - M);
    }
    Ms[b*128 + c] = M;
    Ss[b*128 + c] = S;
}

// stats (rescaled chunk partials) -> layernorm(256) -> linear 256->512
__global__ void final_kernel(const float* __restrict__ pcm, const float* __restrict__ pcq,
                             const float* __restrict__ pm,
                             const float* __restrict__ Ms, const float* __restrict__ Ss,
                             const float* __restrict__ gamma, const float* __restrict__ beta,
                             const float* __restrict__ w2, const float* __restrict__ b2,
                             float* __restrict__ out) {
    __shared__ float row[256];
    __shared__ float nrm[256];
    __shared__ float red[8];
    const int tid = threadIdx.x, b = blockIdx.x;
    if (tid < 128) {
        const float M = Ms[b*128 + tid];
        float sm = 0.0f, sq = 0.0f;
        for (int ch = 0; ch < NCH; ++ch) {
            size_t o = ((size_t)b*NCH + ch)*128 + tid;
            float m = pm[o];
            if (m > -INFINITY) {
                float e = expf(m - M);
                sm += pcm[o]*e;
                sq += pcq[o]*e;
            }
        }
        float S = Ss[b*128 + tid];
        float mean = sm / S;
        float q    = sq / S;
        float resid = q - mean*mean;
        float stdv  = sqrtf(fmaxf(resid, 1e-9f));
        row[tid]       = mean;
        row[128 + tid] = stdv;
    }
    __syncthreads();
    float v  = row[tid];
    float s1 = v, s2 = v*v;
    for (int off = 32; off >= 1; off >>= 1) {
        s1 += __shfl_down(s1, off, 64);
        s2 += __shfl_down(s2, off, 64);
    }
    if ((tid & 63) == 0) { red[tid >> 6] = s1; red[4 + (tid >> 6)] = s2; }
    __syncthreads();
    float S1 = red[0] + red[1] + red[2] + red[3];
    float S2 = red[4] + red[5] + red[6] + red[7];
    float mu  = S1 / 256.0f;
    float var = S2 / 256.0f - mu*mu;
    float inv = 1.0f / sqrtf(var + 1e-5f);
    nrm[tid] = (v - mu)*inv*gamma[tid] + beta[tid];
    __syncthreads();
#pragma unroll
    for (int oo = 0; oo < 2; ++oo) {
        int o = tid + oo*256;
        float acc = b2[o];
        const float4* wr = (const float4*)&w2[(size_t)o*256];
        for (int j = 0; j < 64; ++j) {
            float4 w = wr[j];
            acc += w.x*nrm[j*4] + w.y*nrm[j*4+1] + w.z*nrm[j*4+2] + w.w*nrm[j*4+3];
        }
        out[(size_t)b*512 + o] = acc;
    }
}

// ---------------------------------------------------------------------------
extern "C" void kernel_launch(void* const* d_in, const int* in_sizes, int n_in,
                              void* d_out, int out_size, void* d_ws, size_t ws_size,
                              hipStream_t stream) {
    const float* x      = (const float*)d_in[0];
    const float* bp     = (const float*)d_in[1];
    const float* w_lin1 = (const float*)d_in[2];
    const float* b_lin1 = (const float*)d_in[3];
    const float* wc1    = (const float*)d_in[4];
    const float* bc1    = (const float*)d_in[5];
    const float* wc2    = (const float*)d_in[6];
    const float* bc2    = (const float*)d_in[7];
    const float* wc3    = (const float*)d_in[8];
    const float* bc3    = (const float*)d_in[9];
    const float* wa1    = (const float*)d_in[10];
    const float* ba1    = (const float*)d_in[11];
    const float* wa2    = (const float*)d_in[12];
    const float* ba2    = (const float*)d_in[13];
    const float* gamma  = (const float*)d_in[14];
    const float* beta   = (const float*)d_in[15];
    const float* wl2    = (const float*)d_in[16];
    const float* bl2    = (const float*)d_in[17];

    float* ws   = (float*)d_ws;
    float* bs   = ws + OFF_BS;
    ushort_t* weh  = (ushort_t*)(ws + OFF_WEFF);
    ushort_t* wel  = weh + 64*320;
    float* wtail   = ws + OFF_WTAIL;
    ushort_t* w1h  = (ushort_t*)(ws + OFF_W1);
    ushort_t* w1l  = w1h + 3*128*64;
    ushort_t* w2h  = (ushort_t*)(ws + OFF_W2);
    ushort_t* w2l  = w2h + 3*128*128;
    ushort_t* w3h  = (ushort_t*)(ws + OFF_W3);
    ushort_t* w3l  = w3h + 3*128*128;
    ushort_t* wa1h = (ushort_t*)(ws + OFF_WA1);
    ushort_t* wa1l = wa1h + 64*128;
    ushort_t* wa2h = (ushort_t*)(ws + OFF_WA2);
    ushort_t* wa2l = wa2h + 128*64;
    float* pm   = ws + OFF_PM;
    float* ps   = ws + OFF_PS;
    float* Ms   = ws + OFF_MS;
    float* Ss   = ws + OFF_SS;
    float* pcm  = ws + OFF_PCM;
    float* pcq  = ws + OFF_PCQ;
    ushort_t* Hs = (ushort_t*)(ws + OFF_HS);
    ushort_t* As = (ushort_t*)(ws + OFF_AS);
    ushort_t* Bs = (ushort_t*)(ws + OFF_BSP);

    sort_kernel<<<dim3(1), dim3(64), 0, stream>>>(bp, bs);
    prep_kernel<<<dim3(624), dim3(256), 0, stream>>>(bs, w_lin1, wc1, wc2, wc3, wa1, wa2,
                                                     weh, wel, wtail, w1h, w1l, w2h, w2l,
                                                     w3h, w3l, wa1h, wa1l, wa2h, wa2l);
    // h = relu(x @ Weff^T + b_lin1) -> single bf16 plane
    lin1_mfma<<<dim3(R_/128), dim3(256), 0, stream>>>(x, weh, wel, wtail, b_lin1, Hs);
    // i1 = conv1(h) + b
    dconv1_mfma<<<dim3(47, B_), dim3(256), 0, stream>>>(Hs, w1h, w1l, bc1, As);
    // i3 = conv3(conv2(i1)+b2+2*i1) + b3 + s  (s in LDS only)
    dconv23_fused<<<dim3(63, B_), dim3(512), 0, stream>>>(As, w2h, w2l, w3h, w3l,
                                                          bc2, bc3, Bs);
    // fused asp1+asp2+softmax partials+weighted stats
    asp_fused<<<dim3(NCH, B_), dim3(256), 0, stream>>>(Bs, wa1h, wa1l, wa2h, wa2l,
                                                       ba1, ba2, pm, ps, pcm, pcq);
    sm_pass_b<<<dim3(B_), dim3(128), 0, stream>>>(pm, ps, Ms, Ss);
    final_kernel<<<dim3(B_), dim3(256), 0, stream>>>(pcm, pcq, pm, Ms, Ss, gamma, beta,
                                                     wl2, bl2, (float*)d_out);
}

// Round 15
// 359.133 us; speedup vs baseline: 1.3897x; 1.0262x over previous
//
#include <hip/hip_runtime.h>
#include <math.h>

// ---------------------------------------------------------------------------
// ResCNN_ASP_SpeakerEncoder — v14: final_kernel coalesced via wl2 transpose
// (lane-consecutive reads; was 64-line gather) + sm_pass_b folded in.
// v13 base: column-tiled convs, single-bf16 activations, split weights,
// conv2+conv3 fused, ASP fused.
// ---------------------------------------------------------------------------

constexpr int B_  = 64;
constexpr int T_  = 3000;
constexpr int NB_ = 257;   // NBINS
constexpr int R_  = B_ * T_;           // 192000 rows
constexpr int NCH = 24;                // softmax T-chunks (24 x 128)
constexpr int CHL = 128;

// workspace layout (float offsets)
constexpr size_t OFF_BS    = 0;
constexpr size_t OFF_WEFF  = 128;                          // ushort hi[64*320]+lo
constexpr size_t OFF_WTAIL = OFF_WEFF + 20480;
constexpr size_t OFF_W1    = OFF_WTAIL + 128;              // ushort hi+lo 3*128*64
constexpr size_t OFF_W2    = OFF_W1  + 3*64*128;
constexpr size_t OFF_W3    = OFF_W2  + 3*128*128;
constexpr size_t OFF_WA1   = OFF_W3  + 3*128*128;
constexpr size_t OFF_WA2   = OFF_WA1 + 8192;
constexpr size_t SZ_P      = (size_t)B_*NCH*128;
constexpr size_t OFF_PM    = OFF_WA2 + 8192;
constexpr size_t OFF_PS    = OFF_PM  + SZ_P;
constexpr size_t OFF_PCM   = OFF_PS  + SZ_P;
constexpr size_t OFF_PCQ   = OFF_PCM + SZ_P;
// single bf16 planes (ushort counts -> float counts /2)
constexpr size_t OFF_HS    = OFF_PCQ + SZ_P;               // h  [R*64]u
constexpr size_t OFF_AS    = OFF_HS  + (size_t)R_*32;      // i1 [R*128]u
constexpr size_t OFF_BSP   = OFF_AS  + (size_t)R_*64;      // i3 [R*128]u
constexpr size_t OFF_WL2T  = OFF_BSP + (size_t)R_*64;      // fp32 [256][512]

typedef __attribute__((ext_vector_type(8))) short  bf16x8;
typedef __attribute__((ext_vector_type(4))) float  f32x4;
typedef __attribute__((ext_vector_type(4), aligned(4))) float float4a;
typedef unsigned short ushort_t;

typedef __attribute__((address_space(3))) unsigned int        as3_u32;
typedef const __attribute__((address_space(1))) unsigned int  as1_u32c;
__device__ __forceinline__ void gload16(const void* g, void* l) {
    __builtin_amdgcn_global_load_lds((as1_u32c*)g, (as3_u32*)l, 16, 0, 0);
}

__device__ inline ushort_t f2bf(float f) {                // RNE f32->bf16
    unsigned u = __float_as_uint(f);
    unsigned r = u + 0x7FFFu + ((u >> 16) & 1u);
    return (ushort_t)(r >> 16);
}
__device__ inline float bf2f(ushort_t h) {
    return __uint_as_float(((unsigned)h) << 16);
}
__device__ inline void split2(float v, ushort_t &h, ushort_t &l) {
    h = f2bf(v);
    l = f2bf(v - bf2f(h));
}

// pack 4 f32 -> 4 bf16 (RNE, 2 u32)
__device__ inline void pack_hi4(float x, float y, float z, float w, uint2 &ph) {
    unsigned hx, hy;
    asm("v_cvt_pk_bf16_f32 %0, %1, %2" : "=v"(hx) : "v"(x), "v"(y));
    asm("v_cvt_pk_bf16_f32 %0, %1, %2" : "=v"(hy) : "v"(z), "v"(w));
    ph.x = hx; ph.y = hy;
}

// ---------------------------------------------------------------------------
__global__ void sort_kernel(const float* __restrict__ bp, float* __restrict__ bs) {
    if (threadIdx.x == 0) {
        float tmp[82];
        for (int i = 0; i < 82; ++i) tmp[i] = bp[i];
        for (int i = 1; i < 82; ++i) {
            float key = tmp[i];
            int j = i - 1;
            while (j >= 0 && tmp[j] > key) { tmp[j+1] = tmp[j]; --j; }
            tmp[j+1] = key;
        }
        for (int i = 0; i < 82; ++i) bs[i] = tmp[i];
    }
}

// Fragment-order packing (B: lane&15=col, lane>>4=k-octet; A: lane&15=row),
// plus fp32 wl2 transpose [256 j][512 o] for the coalesced final GEMM.
__global__ void prep_kernel(const float* __restrict__ bs, const float* __restrict__ wl1,
                            const float* __restrict__ wc1, const float* __restrict__ wc2,
                            const float* __restrict__ wc3, const float* __restrict__ wa1,
                            const float* __restrict__ wa2, const float* __restrict__ wl2,
                            ushort_t* __restrict__ weh, ushort_t* __restrict__ wel,
                            float* __restrict__ wtail,
                            ushort_t* __restrict__ w1h, ushort_t* __restrict__ w1l,
                            ushort_t* __restrict__ w2h, ushort_t* __restrict__ w2l,
                            ushort_t* __restrict__ w3h, ushort_t* __restrict__ w3l,
                            ushort_t* __restrict__ wa1h, ushort_t* __restrict__ wa1l,
                            ushort_t* __restrict__ wa2h, ushort_t* __restrict__ wa2l,
                            float* __restrict__ wl2t) {
    int gid = blockIdx.x * 256 + threadIdx.x;
    if (gid < 64*320) {                            // Weff[o][f]
        int o = gid / 320, f = gid % 320;
        if (f > 256) return;
        float acc = 0.0f;
        if (f == 0) acc = wl1[o*80];               // filt[:,:,0] = x[:,:,0]
        else {
            for (int n = 1; n < 79; ++n) {
                float bn = bs[n], bn1 = bs[n+1], bn2 = bs[n+2];
                int ibn  = (int)floorf(bn);
                int ibn1 = (int)floorf(bn1);
                int ibn2 = (int)floorf(bn2);
                float fbv = 0.0f;
                if (f >= ibn && f < ibn1) {
                    float d = (bn1-bn)*(bn1-bn);
                    fbv = ((float)f - bn) / (d > 0.0f ? d : 1.0f);
                } else if (f >= ibn1 && f < ibn2) {
                    float d = (bn2-bn1)*(bn2-bn1);
                    fbv = (bn2 - (float)f) / (d > 0.0f ? d : 1.0f);
                }
                acc += wl1[o*80 + n] * fbv;
            }
        }
        if (f == 256) { wtail[o] = acc; return; }
        int kc = f >> 5, lane = ((f & 31) >> 3)*16 + (o & 15), e = f & 7;
        size_t dst = (((size_t)kc*4 + (o >> 4))*64 + lane)*8 + e;
        split2(acc, weh[dst], wel[dst]);
        return;
    }
    gid -= 64*320;
    if (gid < 3*128*64) {                          // conv1: [k][c][ci=64]
        int k = gid / (128*64), rem = gid % (128*64);
        int c = rem >> 6, ci = rem & 63;
        float v = wc1[(c*64 + ci)*3 + k];
        int lane = ((ci & 31) >> 3)*16 + (c & 15), e = ci & 7;
        size_t dst = ((((size_t)k*2 + (ci >> 5))*8 + (c >> 4))*64 + lane)*8 + e;
        split2(v, w1h[dst], w1l[dst]);
        return;
    }
    gid -= 3*128*64;
    if (gid < 3*128*128) {                         // conv2
        int k = gid / (128*128), rem = gid % (128*128);
        int c = rem >> 7, ci = rem & 127;
        float v = wc2[(c*128 + ci)*3 + k];
        int lane = ((ci & 31) >> 3)*16 + (c & 15), e = ci & 7;
        size_t dst = ((((size_t)k*4 + (ci >> 5))*8 + (c >> 4))*64 + lane)*8 + e;
        split2(v, w2h[dst], w2l[dst]);
        return;
    }
    gid -= 3*128*128;
    if (gid < 3*128*128) {                         // conv3
        int k = gid / (128*128), rem = gid % (128*128);
        int c = rem >> 7, ci = rem & 127;
        float v = wc3[(c*128 + ci)*3 + k];
        int lane = ((ci & 31) >> 3)*16 + (c & 15), e = ci & 7;
        size_t dst = ((((size_t)k*4 + (ci >> 5))*8 + (c >> 4))*64 + lane)*8 + e;
        split2(v, w3h[dst], w3l[dst]);
        return;
    }
    gid -= 3*128*128;
    if (gid < 64*128) {                            // wa1 [c=64][ci=128]
        int c = gid >> 7, ci = gid & 127;
        float v = wa1[gid];
        int lane = ((ci & 31) >> 3)*16 + (c & 15), e = ci & 7;
        size_t dst = (((size_t)(ci >> 5)*4 + (c >> 4))*64 + lane)*8 + e;
        split2(v, wa1h[dst], wa1l[dst]);
        return;
    }
    gid -= 64*128;
    if (gid < 128*64) {                            // wa2 [n=128][ci=64] (A op)
        int n = gid >> 6, ci = gid & 63;
        float v = wa2[gid];
        int lane = ((ci & 31) >> 3)*16 + (n & 15), e = ci & 7;
        size_t dst = (((size_t)(ci >> 5)*8 + (n >> 4))*64 + lane)*8 + e;
        split2(v, wa2h[dst], wa2l[dst]);
        return;
    }
    gid -= 128*64;
    if (gid < 256*512) {                           // wl2T[j][o] <- wl2[o][j]
        int j = gid >> 9, o = gid & 511;
        wl2t[gid] = wl2[(size_t)o*256 + j];
        return;
    }
}

// ---------------------------------------------------------------------------
// lin1: h = relu(x @ Weff^T + b); x staged as single bf16; 2-pass MFMA.
__launch_bounds__(256)
__global__ void lin1_mfma(const float* __restrict__ X,
                          const ushort_t* __restrict__ Wh, const ushort_t* __restrict__ Wl,
                          const float* __restrict__ wtail,
                          const float* __restrict__ bias,
                          ushort_t* __restrict__ Hs) {
    __shared__ __align__(16) ushort_t ash[128*64];
    __shared__ float xs[128];
    __shared__ float wts[64];
    const int tid  = threadIdx.x;
    const int lane = tid & 63;
    const int wid  = tid >> 6;
    const int wy   = wid >> 1, wx = wid & 1;
    const int l16  = lane & 15, l4 = lane >> 4;
    const int r0   = blockIdx.x * 128;

    if (tid < 128)       xs[tid] = X[(size_t)(r0 + tid)*NB_ + 256];
    else if (tid < 192)  wts[tid - 128] = wtail[tid - 128];

#define LIN1_LOAD(dst, k0)                                            \
    _Pragma("unroll")                                                 \
    for (int i = 0; i < 8; ++i) {                                     \
        int q = tid + i*256; int r = q >> 4, cc = (q & 15) << 2;      \
        dst[i] = *(const float4a*)(X + (size_t)(r0 + r)*NB_ + (k0) + cc); \
    }
#define LIN1_CW(src)                                                  \
    _Pragma("unroll")                                                 \
    for (int i = 0; i < 8; ++i) {                                     \
        int q = tid + i*256; int r = q >> 4, cc = (q & 15) << 2;      \
        uint2 ph;                                                     \
        pack_hi4(src[i].x, src[i].y, src[i].z, src[i].w, ph);         \
        unsigned byte = ((unsigned)(r*64 + cc))*2u ^ ((unsigned)((r & 7) << 4)); \
        *(uint2*)((char*)ash + byte) = ph;                            \
    }

    float4a bufA[8], bufB[8];
    LIN1_LOAD(bufA, 0);

    f32x4 acc[4][2];
    const f32x4 z = {0.f,0.f,0.f,0.f};
#pragma unroll
    for (int m = 0; m < 4; ++m) { acc[m][0] = z; acc[m][1] = z; }

#pragma unroll
    for (int ck = 0; ck < 4; ++ck) {
        const float4a* cur = (ck & 1) ? bufB : bufA;
        float4a*       nxt = (ck & 1) ? bufA : bufB;
        if (ck < 3) LIN1_LOAD(nxt, (ck + 1)*64);
        LIN1_CW(cur);
        __syncthreads();
#pragma unroll
        for (int kk = 0; kk < 64; kk += 32) {
            bf16x8 bh[2], bl[2];
#pragma unroll
            for (int n = 0; n < 2; ++n) {
                size_t off = (((size_t)(ck*2 + (kk >> 5))*4 + wx*2 + n)*64 + lane)*8;
                bh[n] = *(const bf16x8*)(Wh + off);
                bl[n] = *(const bf16x8*)(Wl + off);
            }
            bf16x8 fh[4];
#pragma unroll
            for (int m = 0; m < 4; ++m) {
                int r = wy*64 + m*16 + l16;
                unsigned byte = ((unsigned)(r*64 + kk + l4*8))*2u ^ ((unsigned)((r & 7) << 4));
                fh[m] = *(const bf16x8*)((const char*)ash + byte);
            }
#pragma unroll
            for (int m = 0; m < 4; ++m)
#pragma unroll
                for (int n = 0; n < 2; ++n) {
                    acc[m][n] = __builtin_amdgcn_mfma_f32_16x16x32_bf16(fh[m], bh[n], acc[m][n], 0, 0, 0);
                    acc[m][n] = __builtin_amdgcn_mfma_f32_16x16x32_bf16(fh[m], bl[n], acc[m][n], 0, 0, 0);
                }
        }
        __syncthreads();
    }
#undef LIN1_LOAD
#undef LIN1_CW

#pragma unroll
    for (int m = 0; m < 4; ++m)
#pragma unroll
        for (int n = 0; n < 2; ++n) {
            int c = wx*32 + n*16 + l16;
            float bv = bias[c];
            float wc = wts[c];
            int rbl = wy*64 + m*16 + l4*4;
#pragma unroll
            for (int rg = 0; rg < 4; ++rg) {
                int rl = rbl + rg;
                float v = fmaxf(acc[m][n][rg] + bv + xs[rl]*wc, 0.0f);
                Hs[(size_t)(r0 + rl)*64 + c] = f2bf(v);
            }
        }
}

// ---------------------------------------------------------------------------
// conv1 (CIN=64, DIL=2): column-tiled waves.
__launch_bounds__(256, 4)
__global__ void dconv1_mfma(const ushort_t* __restrict__ Xs,
                            const ushort_t* __restrict__ Wh, const ushort_t* __restrict__ Wl,
                            const float* __restrict__ bias,
                            ushort_t* __restrict__ Ys) {
    constexpr int CIN = 64, DIL = 2;
    constexpr int TT  = 64;
    constexpr int HS  = TT + 2*DIL;        // 68
    constexpr int NCK = HS*8;
    constexpr int NCKP = ((NCK + 255)/256)*256;
    __shared__ __align__(16) ushort_t hs_[NCKP*8];

    const int tid  = threadIdx.x;
    const int lane = tid & 63;
    const int wid  = tid >> 6;            // 0..3: cols wid*32 + n*16
    const int l16  = lane & 15;
    const int l4   = lane >> 4;
    const int t0   = blockIdx.x * TT;
    const int b    = blockIdx.y;

    const long long rowbase = ((long long)b*T_ + (t0 - DIL)) * CIN;
    for (int c0 = wid*64; c0 < NCKP; c0 += 256) {
        int ck = c0 + lane;
        int r  = ck >> 3;
        int sc = ck ^ (r & 7);
        gload16(Xs + rowbase + (long long)sc*8, (char*)hs_ + (size_t)c0*16);
    }
    __syncthreads();
    if (t0 < DIL || t0 + TT + DIL > T_) {
        for (int idx = tid; idx < HS*CIN/4; idx += 256) {
            int e = idx << 2;
            int r = e / CIN, ci = e % CIN;
            int t = t0 - DIL + r;
            if (t < 0 || t >= T_) {
                unsigned byte = ((unsigned)(r*CIN + ci))*2u ^ ((unsigned)((r & 7) << 4));
                *(uint2*)((char*)hs_ + byte) = make_uint2(0u, 0u);
            }
        }
        __syncthreads();
    }

    f32x4 acc[4][2];
    const f32x4 z = {0.f, 0.f, 0.f, 0.f};
#pragma unroll
    for (int m = 0; m < 4; ++m)
#pragma unroll
        for (int n = 0; n < 2; ++n) acc[m][n] = z;

#pragma unroll
    for (int k = 0; k < 3; ++k) {
#pragma unroll
        for (int cb = 0; cb < 2; ++cb) {
            bf16x8 bh[2], bl[2];
#pragma unroll
            for (int n = 0; n < 2; ++n) {
                size_t off = ((((size_t)k*2 + cb)*8 + wid*2 + n)*64 + lane)*8;
                bh[n] = *(const bf16x8*)(Wh + off);
                bl[n] = *(const bf16x8*)(Wl + off);
            }
            bf16x8 ah[4];
#pragma unroll
            for (int m = 0; m < 4; ++m) {
                int r = m*16 + l16 + k*DIL;
                unsigned byte = ((unsigned)(r*CIN + cb*32 + l4*8))*2u
                              ^ ((unsigned)((r & 7) << 4));
                ah[m] = *(const bf16x8*)((const char*)hs_ + byte);
            }
#pragma unroll
            for (int m = 0; m < 4; ++m)
#pragma unroll
                for (int n = 0; n < 2; ++n) {
                    acc[m][n] = __builtin_amdgcn_mfma_f32_16x16x32_bf16(ah[m], bh[n], acc[m][n], 0, 0, 0);
                    acc[m][n] = __builtin_amdgcn_mfma_f32_16x16x32_bf16(ah[m], bl[n], acc[m][n], 0, 0, 0);
                }
        }
    }

#pragma unroll
    for (int m = 0; m < 4; ++m) {
        int tl_base = m*16 + l4*4;
#pragma unroll
        for (int n = 0; n < 2; ++n) {
            int c = wid*32 + n*16 + l16;
            float bv = bias[c];
#pragma unroll
            for (int rg = 0; rg < 4; ++rg) {
                int tl = tl_base + rg;
                int t  = t0 + tl;
                if (t < T_) {
                    float v = acc[m][n][rg] + bv;
                    Ys[((size_t)b*T_ + t)*128 + c] = f2bf(v);
                }
            }
        }
    }
}

// ---------------------------------------------------------------------------
// Fused conv2+conv3, column-tiled waves in both phases.
__launch_bounds__(512, 8)
__global__ void dconv23_fused(const ushort_t* __restrict__ Xs,
                              const ushort_t* __restrict__ W2h, const ushort_t* __restrict__ W2l,
                              const ushort_t* __restrict__ W3h, const ushort_t* __restrict__ W3l,
                              const float* __restrict__ bc2, const float* __restrict__ bc3,
                              ushort_t* __restrict__ Ys) {
    constexpr int TT = 48;
    __shared__ __align__(16) ushort_t i1s[64*128];   // rows t0-8 .. t0+55
    __shared__ __align__(16) ushort_t ss_[64*128];

    const int tid  = threadIdx.x;
    const int lane = tid & 63;
    const int wid  = tid >> 6;            // 0..7: cols wid*16 + l16
    const int l16  = lane & 15, l4 = lane >> 4;
    const int t0   = blockIdx.x * TT;
    const int b    = blockIdx.y;

    const long long rowbase = ((long long)b*T_ + (t0 - 8)) * 128;
    for (int c0 = wid*64; c0 < 1024; c0 += 512) {
        int ck = c0 + lane;
        int r  = ck >> 4;
        int sc = ck ^ (r & 7);
        gload16(Xs + rowbase + (long long)sc*8, (char*)i1s + (size_t)c0*16);
    }
    __syncthreads();
    if (t0 < 8 || t0 + 56 > T_) {
        for (int idx = tid; idx < 64*128/4; idx += 512) {
            int e = idx << 2;
            int r = e >> 7, ci = e & 127;
            int t = t0 - 8 + r;
            if (t < 0 || t >= T_) {
                unsigned byte = ((unsigned)(r*128 + ci))*2u ^ ((unsigned)((r & 7) << 4));
                *(uint2*)((char*)i1s + byte) = make_uint2(0u, 0u);
            }
        }
        __syncthreads();
    }

    // ---- phase 1: conv2, all 64 local rows, wave = 16 cols ----
    {
        f32x4 acc[4];
        const f32x4 z = {0.f,0.f,0.f,0.f};
#pragma unroll
        for (int m = 0; m < 4; ++m) acc[m] = z;
#pragma unroll
        for (int k = 0; k < 3; ++k) {
#pragma unroll
            for (int cb = 0; cb < 4; ++cb) {
                size_t off = ((((size_t)k*4 + cb)*8 + wid)*64 + lane)*8;
                bf16x8 bh = *(const bf16x8*)(W2h + off);
                bf16x8 bl = *(const bf16x8*)(W2l + off);
                bf16x8 ah[4];
#pragma unroll
                for (int m = 0; m < 4; ++m) {
                    int r = m*16 + l16 + k*3 - 3;
                    r = min(max(r, 0), 63);   // garbage edge rows; never consumed
                    unsigned byte = ((unsigned)(r*128 + cb*32 + l4*8))*2u
                                  ^ ((unsigned)((r & 7) << 4));
                    ah[m] = *(const bf16x8*)((const char*)i1s + byte);
                }
#pragma unroll
                for (int m = 0; m < 4; ++m) {
                    acc[m] = __builtin_amdgcn_mfma_f32_16x16x32_bf16(ah[m], bh, acc[m], 0, 0, 0);
                    acc[m] = __builtin_amdgcn_mfma_f32_16x16x32_bf16(ah[m], bl, acc[m], 0, 0, 0);
                }
            }
        }
        const int c = wid*16 + l16;
        const float bv = bc2[c];
#pragma unroll
        for (int m = 0; m < 4; ++m) {
#pragma unroll
            for (int rg = 0; rg < 4; ++rg) {
                int rl = m*16 + l4*4 + rg;
                int t  = t0 - 8 + rl;
                float v = 0.0f;
                unsigned byte = ((unsigned)(rl*128 + c))*2u ^ ((unsigned)((rl & 7) << 4));
                if (t >= 0 && t < T_) {
                    float cen = bf2f(*(const ushort_t*)((const char*)i1s + byte));
                    v = acc[m][rg] + bv + 2.0f*cen;
                }
                *(ushort_t*)((char*)ss_ + byte) = f2bf(v);
            }
        }
    }
    __syncthreads();

    // ---- phase 2: conv3 over 48 output rows, wave = 16 cols ----
    {
        f32x4 acc[3];
        const f32x4 z = {0.f,0.f,0.f,0.f};
#pragma unroll
        for (int m = 0; m < 3; ++m) acc[m] = z;
#pragma unroll
        for (int k = 0; k < 3; ++k) {
#pragma unroll
            for (int cb = 0; cb < 4; ++cb) {
                size_t off = ((((size_t)k*4 + cb)*8 + wid)*64 + lane)*8;
                bf16x8 bh = *(const bf16x8*)(W3h + off);
                bf16x8 bl = *(const bf16x8*)(W3l + off);
                bf16x8 ah[3];
#pragma unroll
                for (int m = 0; m < 3; ++m) {
                    int r = 4 + m*16 + l16 + k*4;      // in [4,59]
                    unsigned byte = ((unsigned)(r*128 + cb*32 + l4*8))*2u
                                  ^ ((unsigned)((r & 7) << 4));
                    ah[m] = *(const bf16x8*)((const char*)ss_ + byte);
                }
#pragma unroll
                for (int m = 0; m < 3; ++m) {
                    acc[m] = __builtin_amdgcn_mfma_f32_16x16x32_bf16(ah[m], bh, acc[m], 0, 0, 0);
                    acc[m] = __builtin_amdgcn_mfma_f32_16x16x32_bf16(ah[m], bl, acc[m], 0, 0, 0);
                }
            }
        }
        const int c = wid*16 + l16;
        const float bv = bc3[c];
#pragma unroll
        for (int m = 0; m < 3; ++m) {
#pragma unroll
            for (int rg = 0; rg < 4; ++rg) {
                int rl = 8 + m*16 + l4*4 + rg;         // s local row
                int t  = t0 - 8 + rl;
                if (t < T_) {
                    unsigned byte = ((unsigned)(rl*128 + c))*2u ^ ((unsigned)((rl & 7) << 4));
                    float cen = bf2f(*(const ushort_t*)((const char*)ss_ + byte));
                    float v = acc[m][rg] + bv + cen;
                    Ys[((size_t)b*T_ + t)*128 + c] = f2bf(v);
                }
            }
        }
    }
}

// ---------------------------------------------------------------------------
// Fused ASP (single-plane i3; weights split => 2-pass). LDS 32KB + reds.
__launch_bounds__(256)
__global__ void asp_fused(const ushort_t* __restrict__ As,
                          const ushort_t* __restrict__ Wa1h, const ushort_t* __restrict__ Wa1l,
                          const ushort_t* __restrict__ Wa2h, const ushort_t* __restrict__ Wa2l,
                          const float* __restrict__ ba1, const float* __restrict__ ba2,
                          float* __restrict__ pm, float* __restrict__ ps,
                          float* __restrict__ pcm, float* __restrict__ pcq) {
    __shared__ __align__(16) char smem[32768];
    ushort_t* as_ = (ushort_t*)smem;               // [128][64] stage-1 A
    ushort_t* vs_ = (ushort_t*)(smem + 16384);     // v [128][64]
    ushort_t* xs_ = (ushort_t*)smem;               // [128][128] i3 (after stage 2)
    __shared__ float redM[2][128];
    __shared__ float redS[2][128];
    __shared__ float redAM[2][128];
    __shared__ float redAQ[2][128];

    const int tid  = threadIdx.x;
    const int lane = tid & 63;
    const int wid  = tid >> 6;
    const int wy   = wid >> 1, wx = wid & 1;
    const int l16  = lane & 15, l4 = lane >> 4;
    const int ch   = blockIdx.x;
    const int b    = blockIdx.y;
    const int t0   = ch * CHL;
    const size_t xrow = ((size_t)b*T_ + t0) * 128;

    // ---- stage 1: v = tanh(i3 @ wa1^T + ba1), K=128 in 2 chunks ----
    f32x4 acc1[4][2];
    const f32x4 z = {0.f,0.f,0.f,0.f};
#pragma unroll
    for (int m = 0; m < 4; ++m) { acc1[m][0] = z; acc1[m][1] = z; }

    for (int k0 = 0; k0 < 128; k0 += 64) {
        __syncthreads();
        for (int c0 = wid*64; c0 < 1024; c0 += 256) {
            int ck = c0 + lane;
            int r  = ck >> 3, wc = ck & 7;
            int sc = wc ^ (r & 7);
            gload16(As + xrow + (size_t)r*128 + k0 + sc*8, (char*)as_ + (size_t)c0*16);
        }
        __syncthreads();
#pragma unroll
        for (int kk = 0; kk < 64; kk += 32) {
            bf16x8 bh[2], bl[2];
#pragma unroll
            for (int n = 0; n < 2; ++n) {
                size_t off = (((size_t)((k0 + kk) >> 5)*4 + wx*2 + n)*64 + lane)*8;
                bh[n] = *(const bf16x8*)(Wa1h + off);
                bl[n] = *(const bf16x8*)(Wa1l + off);
            }
            bf16x8 fh[4];
#pragma unroll
            for (int m = 0; m < 4; ++m) {
                int r = wy*64 + m*16 + l16;
                unsigned byte = ((unsigned)(r*64 + kk + l4*8))*2u ^ ((unsigned)((r & 7) << 4));
                fh[m] = *(const bf16x8*)((const char*)as_ + byte);
            }
#pragma unroll
            for (int m = 0; m < 4; ++m)
#pragma unroll
                for (int n = 0; n < 2; ++n) {
                    acc1[m][n] = __builtin_amdgcn_mfma_f32_16x16x32_bf16(fh[m], bh[n], acc1[m][n], 0, 0, 0);
                    acc1[m][n] = __builtin_amdgcn_mfma_f32_16x16x32_bf16(fh[m], bl[n], acc1[m][n], 0, 0, 0);
                }
        }
    }
    // epilogue 1: tanh, write v (single bf16) to LDS
#pragma unroll
    for (int m = 0; m < 4; ++m)
#pragma unroll
        for (int n = 0; n < 2; ++n) {
            int c = wx*32 + n*16 + l16;
            float bv = ba1[c];
            int rb = wy*64 + m*16 + l4*4;
#pragma unroll
            for (int rg = 0; rg < 4; ++rg) {
                float v = tanhf(acc1[m][n][rg] + bv);
                int r = rb + rg;
                unsigned byte = ((unsigned)(r*64 + c))*2u ^ ((unsigned)((r & 7) << 4));
                *(ushort_t*)((char*)vs_ + byte) = f2bf(v);
            }
        }
    __syncthreads();

    // ---- stage 2: D[n][t] = wa2 . v ----
    f32x4 acc2[4][4];
#pragma unroll
    for (int m = 0; m < 4; ++m)
#pragma unroll
        for (int j = 0; j < 4; ++j) acc2[m][j] = z;

#pragma unroll
    for (int kk = 0; kk < 64; kk += 32) {
        bf16x8 awh[4], awl[4];
#pragma unroll
        for (int m = 0; m < 4; ++m) {
            size_t off = (((size_t)(kk >> 5)*8 + wy*4 + m)*64 + lane)*8;
            awh[m] = *(const bf16x8*)(Wa2h + off);
            awl[m] = *(const bf16x8*)(Wa2l + off);
        }
        bf16x8 bv_[4];
#pragma unroll
        for (int j = 0; j < 4; ++j) {
            int r = wx*64 + j*16 + l16;
            unsigned byte = ((unsigned)(r*64 + kk + l4*8))*2u ^ ((unsigned)((r & 7) << 4));
            bv_[j] = *(const bf16x8*)((const char*)vs_ + byte);
        }
#pragma unroll
        for (int m = 0; m < 4; ++m)
#pragma unroll
            for (int j = 0; j < 4; ++j) {
                acc2[m][j] = __builtin_amdgcn_mfma_f32_16x16x32_bf16(awh[m], bv_[j], acc2[m][j], 0, 0, 0);
                acc2[m][j] = __builtin_amdgcn_mfma_f32_16x16x32_bf16(awl[m], bv_[j], acc2[m][j], 0, 0, 0);
            }
    }

    // epilogue 2: bias; chunk max; DMA restage i3 (single); weighted sums
#pragma unroll
    for (int m = 0; m < 4; ++m) {
        const float4 bv = *(const float4*)&ba2[wy*64 + m*16 + l4*4];
#pragma unroll
        for (int j = 0; j < 4; ++j) {
            acc2[m][j][0] += bv.x; acc2[m][j][1] += bv.y;
            acc2[m][j][2] += bv.z; acc2[m][j][3] += bv.w;
        }
    }
#pragma unroll
    for (int m = 0; m < 4; ++m)
#pragma unroll
        for (int rg = 0; rg < 4; ++rg) {
            int n = wy*64 + m*16 + l4*4 + rg;
            float mx = -INFINITY;
#pragma unroll
            for (int j = 0; j < 4; ++j) {
                int tg = t0 + wx*64 + j*16 + l16;
                if (tg < T_) mx = fmaxf(mx, acc2[m][j][rg]);
            }
            mx = fmaxf(mx, __shfl_xor(mx, 1));
            mx = fmaxf(mx, __shfl_xor(mx, 2));
            mx = fmaxf(mx, __shfl_xor(mx, 4));
            mx = fmaxf(mx, __shfl_xor(mx, 8));
            if (l16 == 0) redM[wx][n] = mx;
        }
    __syncthreads();                               // stage-2 smem reads done
    for (int c0 = wid*64; c0 < 2048; c0 += 256) {  // restage 128x128 single plane
        int ck = c0 + lane;
        int r  = ck >> 4, wc = ck & 15;
        int sc = wc ^ (r & 7);
        gload16(As + xrow + (size_t)r*128 + sc*8, (char*)xs_ + (size_t)c0*16);
    }
    __syncthreads();
#pragma unroll
    for (int m = 0; m < 4; ++m)
#pragma unroll
        for (int rg = 0; rg < 4; ++rg) {
            int n = wy*64 + m*16 + l4*4 + rg;
            const float mch = fmaxf(redM[0][n], redM[1][n]);
            float se = 0.0f, am = 0.0f, aq = 0.0f;
#pragma unroll
            for (int j = 0; j < 4; ++j) {
                int tl = wx*64 + j*16 + l16;
                int tg = t0 + tl;
                if (tg < T_) {
                    float p = expf(acc2[m][j][rg] - mch);
                    unsigned byte = ((unsigned)(tl*128 + n))*2u ^ ((unsigned)((tl & 7) << 4));
                    float x = bf2f(*(const ushort_t*)((const char*)xs_ + byte));
                    se += p; am += p*x; aq += p*x*x;
                }
            }
#pragma unroll
            for (int d = 1; d <= 8; d <<= 1) {
                se += __shfl_xor(se, d);
                am += __shfl_xor(am, d);
                aq += __shfl_xor(aq, d);
            }
            if (l16 == 0) { redS[wx][n] = se; redAM[wx][n] = am; redAQ[wx][n] = aq; }
        }
    __syncthreads();
    if (tid < 128) {
        float m0 = redM[0][tid], m1 = redM[1][tid];
        float M  = fmaxf(m0, m1);
        size_t o = ((size_t)b*NCH + ch)*128 + tid;
        pm[o]  = M;
        ps[o]  = redS[0][tid]  + redS[1][tid];
        pcm[o] = redAM[0][tid] + redAM[1][tid];
        pcq[o] = redAQ[0][tid] + redAQ[1][tid];
    }
}

// ---------------------------------------------------------------------------
// final: global softmax combine (was sm_pass_b) + stats + layernorm(256) +
// linear 256->512 with TRANSPOSED weights (lane-coalesced reads).
__launch_bounds__(256)
__global__ void final_kernel(const float* __restrict__ pcm, const float* __restrict__ pcq,
                             const float* __restrict__ pm, const float* __restrict__ ps,
                             const float* __restrict__ gamma, const float* __restrict__ beta,
                             const float* __restrict__ w2t, const float* __restrict__ b2,
                             float* __restrict__ out) {
    __shared__ float row[256];
    __shared__ float nrm[256];
    __shared__ float red[8];
    const int tid = threadIdx.x, b = blockIdx.x;
    if (tid < 128) {
        // combine chunk-local softmax partials (was sm_pass_b)
        float M = -INFINITY;
        for (int ch = 0; ch < NCH; ++ch)
            M = fmaxf(M, pm[((size_t)b*NCH + ch)*128 + tid]);
        float S = 0.0f, sm = 0.0f, sq = 0.0f;
        for (int ch = 0; ch < NCH; ++ch) {
            size_t o = ((size_t)b*NCH + ch)*128 + tid;
            float m = pm[o];
            if (m > -INFINITY) {
                float e = expf(m - M);
                S  += ps[o]*e;
                sm += pcm[o]*e;
                sq += pcq[o]*e;
            }
        }
        float mean = sm / S;
        float q    = sq / S;
        float resid = q - mean*mean;
        float stdv  = sqrtf(fmaxf(resid, 1e-9f));
        row[tid]       = mean;
        row[128 + tid] = stdv;
    }
    __syncthreads();
    float v  = row[tid];
    float s1 = v, s2 = v*v;
    for (int off = 32; off >= 1; off >>= 1) {
        s1 += __shfl_down(s1, off, 64);
        s2 += __shfl_down(s2, off, 64);
    }
    if ((tid & 63) == 0) { red[tid >> 6] = s1; red[4 + (tid >> 6)] = s2; }
    __syncthreads();
    float S1 = red[0] + red[1] + red[2] + red[3];
    float S2 = red[4] + red[5] + red[6] + red[7];
    float mu  = S1 / 256.0f;
    float var = S2 / 256.0f - mu*mu;
    float inv = 1.0f / sqrtf(var + 1e-5f);
    nrm[tid] = (v - mu)*inv*gamma[tid] + beta[tid];
    __syncthreads();
    // linear 256->512: o = tid and tid+256; w2t[j][o] lane-coalesced
    float acc0 = b2[tid], acc1 = b2[tid + 256];
#pragma unroll 4
    for (int j = 0; j < 256; ++j) {
        float nv = nrm[j];
        const float* wr = w2t + (size_t)j*512;
        acc0 += wr[tid]       * nv;
        acc1 += wr[tid + 256] * nv;
    }
    out[(size_t)b*512 + tid]       = acc0;
    out[(size_t)b*512 + tid + 256] = acc1;
}

// ---------------------------------------------------------------------------
extern "C" void kernel_launch(void* const* d_in, const int* in_sizes, int n_in,
                              void* d_out, int out_size, void* d_ws, size_t ws_size,
                              hipStream_t stream) {
    const float* x      = (const float*)d_in[0];
    const float* bp     = (const float*)d_in[1];
    const float* w_lin1 = (const float*)d_in[2];
    const float* b_lin1 = (const float*)d_in[3];
    const float* wc1    = (const float*)d_in[4];
    const float* bc1    = (const float*)d_in[5];
    const float* wc2    = (const float*)d_in[6];
    const float* bc2    = (const float*)d_in[7];
    const float* wc3    = (const float*)d_in[8];
    const float* bc3    = (const float*)d_in[9];
    const float* wa1    = (const float*)d_in[10];
    const float* ba1    = (const float*)d_in[11];
    const float* wa2    = (const float*)d_in[12];
    const float* ba2    = (const float*)d_in[13];
    const float* gamma  = (const float*)d_in[14];
    const float* beta   = (const float*)d_in[15];
    const float* wl2    = (const float*)d_in[16];
    const float* bl2    = (const float*)d_in[17];

    float* ws   = (float*)d_ws;
    float* bs   = ws + OFF_BS;
    ushort_t* weh  = (ushort_t*)(ws + OFF_WEFF);
    ushort_t* wel  = weh + 64*320;
    float* wtail   = ws + OFF_WTAIL;
    ushort_t* w1h  = (ushort_t*)(ws + OFF_W1);
    ushort_t* w1l  = w1h + 3*128*64;
    ushort_t* w2h  = (ushort_t*)(ws + OFF_W2);
    ushort_t* w2l  = w2h + 3*128*128;
    ushort_t* w3h  = (ushort_t*)(ws + OFF_W3);
    ushort_t* w3l  = w3h + 3*128*128;
    ushort_t* wa1h = (ushort_t*)(ws + OFF_WA1);
    ushort_t* wa1l = wa1h + 64*128;
    ushort_t* wa2h = (ushort_t*)(ws + OFF_WA2);
    ushort_t* wa2l = wa2h + 128*64;
    float* pm   = ws + OFF_PM;
    float* ps   = ws + OFF_PS;
    float* pcm  = ws + OFF_PCM;
    float* pcq  = ws + OFF_PCQ;
    ushort_t* Hs = (ushort_t*)(ws + OFF_HS);
    ushort_t* As = (ushort_t*)(ws + OFF_AS);
    ushort_t* Bs = (ushort_t*)(ws + OFF_BSP);
    float* wl2t  = ws + OFF_WL2T;

    sort_kernel<<<dim3(1), dim3(64), 0, stream>>>(bp, bs);
    prep_kernel<<<dim3(1136), dim3(256), 0, stream>>>(bs, w_lin1, wc1, wc2, wc3, wa1, wa2,
                                                      wl2, weh, wel, wtail, w1h, w1l,
                                                      w2h, w2l, w3h, w3l, wa1h, wa1l,
                                                      wa2h, wa2l, wl2t);
    // h = relu(x @ Weff^T + b_lin1) -> single bf16 plane
    lin1_mfma<<<dim3(R_/128), dim3(256), 0, stream>>>(x, weh, wel, wtail, b_lin1, Hs);
    // i1 = conv1(h) + b
    dconv1_mfma<<<dim3(47, B_), dim3(256), 0, stream>>>(Hs, w1h, w1l, bc1, As);
    // i3 = conv3(conv2(i1)+b2+2*i1) + b3 + s  (s in LDS only)
    dconv23_fused<<<dim3(63, B_), dim3(512), 0, stream>>>(As, w2h, w2l, w3h, w3l,
                                                          bc2, bc3, Bs);
    // fused asp1+asp2+softmax partials+weighted stats
    asp_fused<<<dim3(NCH, B_), dim3(256), 0, stream>>>(Bs, wa1h, wa1l, wa2h, wa2l,
                                                       ba1, ba2, pm, ps, pcm, pcq);
    // global combine + stats + LN + coalesced 256->512 linear
    final_kernel<<<dim3(B_), dim3(256), 0, stream>>>(pcm, pcq, pm, ps, gamma, beta,
                                                     wl2t, bl2, (float*)d_out);
}

// Round 16
// 350.997 us; speedup vs baseline: 1.4219x; 1.0232x over previous
//
#include <hip/hip_runtime.h>
#include <math.h>

// ---------------------------------------------------------------------------
// ResCNN_ASP_SpeakerEncoder — v15: dconv23 row-doubled (128-row tile, 8 frags
// per weight chunk => half the L2 weight traffic); asp stages i3 once (full
// 128x128 tile reused by stage1 + stats). v14 base otherwise.
// ---------------------------------------------------------------------------

constexpr int B_  = 64;
constexpr int T_  = 3000;
constexpr int NB_ = 257;   // NBINS
constexpr int R_  = B_ * T_;           // 192000 rows
constexpr int NCH = 24;                // softmax T-chunks (24 x 128)
constexpr int CHL = 128;

// workspace layout (float offsets)
constexpr size_t OFF_BS    = 0;
constexpr size_t OFF_WEFF  = 128;                          // ushort hi[64*320]+lo
constexpr size_t OFF_WTAIL = OFF_WEFF + 20480;
constexpr size_t OFF_W1    = OFF_WTAIL + 128;              // ushort hi+lo 3*128*64
constexpr size_t OFF_W2    = OFF_W1  + 3*64*128;
constexpr size_t OFF_W3    = OFF_W2  + 3*128*128;
constexpr size_t OFF_WA1   = OFF_W3  + 3*128*128;
constexpr size_t OFF_WA2   = OFF_WA1 + 8192;
constexpr size_t SZ_P      = (size_t)B_*NCH*128;
constexpr size_t OFF_PM    = OFF_WA2 + 8192;
constexpr size_t OFF_PS    = OFF_PM  + SZ_P;
constexpr size_t OFF_PCM   = OFF_PS  + SZ_P;
constexpr size_t OFF_PCQ   = OFF_PCM + SZ_P;
// single bf16 planes (ushort counts -> float counts /2)
constexpr size_t OFF_HS    = OFF_PCQ + SZ_P;               // h  [R*64]u
constexpr size_t OFF_AS    = OFF_HS  + (size_t)R_*32;      // i1 [R*128]u
constexpr size_t OFF_BSP   = OFF_AS  + (size_t)R_*64;      // i3 [R*128]u
constexpr size_t OFF_WL2T  = OFF_BSP + (size_t)R_*64;      // fp32 [256][512]

typedef __attribute__((ext_vector_type(8))) short  bf16x8;
typedef __attribute__((ext_vector_type(4))) float  f32x4;
typedef __attribute__((ext_vector_type(4), aligned(4))) float float4a;
typedef unsigned short ushort_t;

typedef __attribute__((address_space(3))) unsigned int        as3_u32;
typedef const __attribute__((address_space(1))) unsigned int  as1_u32c;
__device__ __forceinline__ void gload16(const void* g, void* l) {
    __builtin_amdgcn_global_load_lds((as1_u32c*)g, (as3_u32*)l, 16, 0, 0);
}

__device__ inline ushort_t f2bf(float f) {                // RNE f32->bf16
    unsigned u = __float_as_uint(f);
    unsigned r = u + 0x7FFFu + ((u >> 16) & 1u);
    return (ushort_t)(r >> 16);
}
__device__ inline float bf2f(ushort_t h) {
    return __uint_as_float(((unsigned)h) << 16);
}
__device__ inline void split2(float v, ushort_t &h, ushort_t &l) {
    h = f2bf(v);
    l = f2bf(v - bf2f(h));
}

// pack 4 f32 -> 4 bf16 (RNE, 2 u32)
__device__ inline void pack_hi4(float x, float y, float z, float w, uint2 &ph) {
    unsigned hx, hy;
    asm("v_cvt_pk_bf16_f32 %0, %1, %2" : "=v"(hx) : "v"(x), "v"(y));
    asm("v_cvt_pk_bf16_f32 %0, %1, %2" : "=v"(hy) : "v"(z), "v"(w));
    ph.x = hx; ph.y = hy;
}

// ---------------------------------------------------------------------------
__global__ void sort_kernel(const float* __restrict__ bp, float* __restrict__ bs) {
    if (threadIdx.x == 0) {
        float tmp[82];
        for (int i = 0; i < 82; ++i) tmp[i] = bp[i];
        for (int i = 1; i < 82; ++i) {
            float key = tmp[i];
            int j = i - 1;
            while (j >= 0 && tmp[j] > key) { tmp[j+1] = tmp[j]; --j; }
            tmp[j+1] = key;
        }
        for (int i = 0; i < 82; ++i) bs[i] = tmp[i];
    }
}

// Fragment-order packing (B: lane&15=col, lane>>4=k-octet; A: lane&15=row),
// plus fp32 wl2 transpose [256 j][512 o] for the coalesced final GEMM.
__global__ void prep_kernel(const float* __restrict__ bs, const float* __restrict__ wl1,
                            const float* __restrict__ wc1, const float* __restrict__ wc2,
                            const float* __restrict__ wc3, const float* __restrict__ wa1,
                            const float* __restrict__ wa2, const float* __restrict__ wl2,
                            ushort_t* __restrict__ weh, ushort_t* __restrict__ wel,
                            float* __restrict__ wtail,
                            ushort_t* __restrict__ w1h, ushort_t* __restrict__ w1l,
                            ushort_t* __restrict__ w2h, ushort_t* __restrict__ w2l,
                            ushort_t* __restrict__ w3h, ushort_t* __restrict__ w3l,
                            ushort_t* __restrict__ wa1h, ushort_t* __restrict__ wa1l,
                            ushort_t* __restrict__ wa2h, ushort_t* __restrict__ wa2l,
                            float* __restrict__ wl2t) {
    int gid = blockIdx.x * 256 + threadIdx.x;
    if (gid < 64*320) {                            // Weff[o][f]
        int o = gid / 320, f = gid % 320;
        if (f > 256) return;
        float acc = 0.0f;
        if (f == 0) acc = wl1[o*80];               // filt[:,:,0] = x[:,:,0]
        else {
            for (int n = 1; n < 79; ++n) {
                float bn = bs[n], bn1 = bs[n+1], bn2 = bs[n+2];
                int ibn  = (int)floorf(bn);
                int ibn1 = (int)floorf(bn1);
                int ibn2 = (int)floorf(bn2);
                float fbv = 0.0f;
                if (f >= ibn && f < ibn1) {
                    float d = (bn1-bn)*(bn1-bn);
                    fbv = ((float)f - bn) / (d > 0.0f ? d : 1.0f);
                } else if (f >= ibn1 && f < ibn2) {
                    float d = (bn2-bn1)*(bn2-bn1);
                    fbv = (bn2 - (float)f) / (d > 0.0f ? d : 1.0f);
                }
                acc += wl1[o*80 + n] * fbv;
            }
        }
        if (f == 256) { wtail[o] = acc; return; }
        int kc = f >> 5, lane = ((f & 31) >> 3)*16 + (o & 15), e = f & 7;
        size_t dst = (((size_t)kc*4 + (o >> 4))*64 + lane)*8 + e;
        split2(acc, weh[dst], wel[dst]);
        return;
    }
    gid -= 64*320;
    if (gid < 3*128*64) {                          // conv1: [k][c][ci=64]
        int k = gid / (128*64), rem = gid % (128*64);
        int c = rem >> 6, ci = rem & 63;
        float v = wc1[(c*64 + ci)*3 + k];
        int lane = ((ci & 31) >> 3)*16 + (c & 15), e = ci & 7;
        size_t dst = ((((size_t)k*2 + (ci >> 5))*8 + (c >> 4))*64 + lane)*8 + e;
        split2(v, w1h[dst], w1l[dst]);
        return;
    }
    gid -= 3*128*64;
    if (gid < 3*128*128) {                         // conv2
        int k = gid / (128*128), rem = gid % (128*128);
        int c = rem >> 7, ci = rem & 127;
        float v = wc2[(c*128 + ci)*3 + k];
        int lane = ((ci & 31) >> 3)*16 + (c & 15), e = ci & 7;
        size_t dst = ((((size_t)k*4 + (ci >> 5))*8 + (c >> 4))*64 + lane)*8 + e;
        split2(v, w2h[dst], w2l[dst]);
        return;
    }
    gid -= 3*128*128;
    if (gid < 3*128*128) {                         // conv3
        int k = gid / (128*128), rem = gid % (128*128);
        int c = rem >> 7, ci = rem & 127;
        float v = wc3[(c*128 + ci)*3 + k];
        int lane = ((ci & 31) >> 3)*16 + (c & 15), e = ci & 7;
        size_t dst = ((((size_t)k*4 + (ci >> 5))*8 + (c >> 4))*64 + lane)*8 + e;
        split2(v, w3h[dst], w3l[dst]);
        return;
    }
    gid -= 3*128*128;
    if (gid < 64*128) {                            // wa1 [c=64][ci=128]
        int c = gid >> 7, ci = gid & 127;
        float v = wa1[gid];
        int lane = ((ci & 31) >> 3)*16 + (c & 15), e = ci & 7;
        size_t dst = (((size_t)(ci >> 5)*4 + (c >> 4))*64 + lane)*8 + e;
        split2(v, wa1h[dst], wa1l[dst]);
        return;
    }
    gid -= 64*128;
    if (gid < 128*64) {                            // wa2 [n=128][ci=64] (A op)
        int n = gid >> 6, ci = gid & 63;
        float v = wa2[gid];
        int lane = ((ci & 31) >> 3)*16 + (n & 15), e = ci & 7;
        size_t dst = (((size_t)(ci >> 5)*8 + (n >> 4))*64 + lane)*8 + e;
        split2(v, wa2h[dst], wa2l[dst]);
        return;
    }
    gid -= 128*64;
    if (gid < 256*512) {                           // wl2T[j][o] <- wl2[o][j]
        int j = gid >> 9, o = gid & 511;
        wl2t[gid] = wl2[(size_t)o*256 + j];
        return;
    }
}

// ---------------------------------------------------------------------------
// lin1: h = relu(x @ Weff^T + b); x staged as single bf16; 2-pass MFMA.
__launch_bounds__(256)
__global__ void lin1_mfma(const float* __restrict__ X,
                          const ushort_t* __restrict__ Wh, const ushort_t* __restrict__ Wl,
                          const float* __restrict__ wtail,
                          const float* __restrict__ bias,
                          ushort_t* __restrict__ Hs) {
    __shared__ __align__(16) ushort_t ash[128*64];
    __shared__ float xs[128];
    __shared__ float wts[64];
    const int tid  = threadIdx.x;
    const int lane = tid & 63;
    const int wid  = tid >> 6;
    const int wy   = wid >> 1, wx = wid & 1;
    const int l16  = lane & 15, l4 = lane >> 4;
    const int r0   = blockIdx.x * 128;

    if (tid < 128)       xs[tid] = X[(size_t)(r0 + tid)*NB_ + 256];
    else if (tid < 192)  wts[tid - 128] = wtail[tid - 128];

#define LIN1_LOAD(dst, k0)                                            \
    _Pragma("unroll")                                                 \
    for (int i = 0; i < 8; ++i) {                                     \
        int q = tid + i*256; int r = q >> 4, cc = (q & 15) << 2;      \
        dst[i] = *(const float4a*)(X + (size_t)(r0 + r)*NB_ + (k0) + cc); \
    }
#define LIN1_CW(src)                                                  \
    _Pragma("unroll")                                                 \
    for (int i = 0; i < 8; ++i) {                                     \
        int q = tid + i*256; int r = q >> 4, cc = (q & 15) << 2;      \
        uint2 ph;                                                     \
        pack_hi4(src[i].x, src[i].y, src[i].z, src[i].w, ph);         \
        unsigned byte = ((unsigned)(r*64 + cc))*2u ^ ((unsigned)((r & 7) << 4)); \
        *(uint2*)((char*)ash + byte) = ph;                            \
    }

    float4a bufA[8], bufB[8];
    LIN1_LOAD(bufA, 0);

    f32x4 acc[4][2];
    const f32x4 z = {0.f,0.f,0.f,0.f};
#pragma unroll
    for (int m = 0; m < 4; ++m) { acc[m][0] = z; acc[m][1] = z; }

#pragma unroll
    for (int ck = 0; ck < 4; ++ck) {
        const float4a* cur = (ck & 1) ? bufB : bufA;
        float4a*       nxt = (ck & 1) ? bufA : bufB;
        if (ck < 3) LIN1_LOAD(nxt, (ck + 1)*64);
        LIN1_CW(cur);
        __syncthreads();
#pragma unroll
        for (int kk = 0; kk < 64; kk += 32) {
            bf16x8 bh[2], bl[2];
#pragma unroll
            for (int n = 0; n < 2; ++n) {
                size_t off = (((size_t)(ck*2 + (kk >> 5))*4 + wx*2 + n)*64 + lane)*8;
                bh[n] = *(const bf16x8*)(Wh + off);
                bl[n] = *(const bf16x8*)(Wl + off);
            }
            bf16x8 fh[4];
#pragma unroll
            for (int m = 0; m < 4; ++m) {
                int r = wy*64 + m*16 + l16;
                unsigned byte = ((unsigned)(r*64 + kk + l4*8))*2u ^ ((unsigned)((r & 7) << 4));
                fh[m] = *(const bf16x8*)((const char*)ash + byte);
            }
#pragma unroll
            for (int m = 0; m < 4; ++m)
#pragma unroll
                for (int n = 0; n < 2; ++n) {
                    acc[m][n] = __builtin_amdgcn_mfma_f32_16x16x32_bf16(fh[m], bh[n], acc[m][n], 0, 0, 0);
                    acc[m][n] = __builtin_amdgcn_mfma_f32_16x16x32_bf16(fh[m], bl[n], acc[m][n], 0, 0, 0);
                }
        }
        __syncthreads();
    }
#undef LIN1_LOAD
#undef LIN1_CW

#pragma unroll
    for (int m = 0; m < 4; ++m)
#pragma unroll
        for (int n = 0; n < 2; ++n) {
            int c = wx*32 + n*16 + l16;
            float bv = bias[c];
            float wc = wts[c];
            int rbl = wy*64 + m*16 + l4*4;
#pragma unroll
            for (int rg = 0; rg < 4; ++rg) {
                int rl = rbl + rg;
                float v = fmaxf(acc[m][n][rg] + bv + xs[rl]*wc, 0.0f);
                Hs[(size_t)(r0 + rl)*64 + c] = f2bf(v);
            }
        }
}

// ---------------------------------------------------------------------------
// conv1 (CIN=64, DIL=2): column-tiled waves.
__launch_bounds__(256, 4)
__global__ void dconv1_mfma(const ushort_t* __restrict__ Xs,
                            const ushort_t* __restrict__ Wh, const ushort_t* __restrict__ Wl,
                            const float* __restrict__ bias,
                            ushort_t* __restrict__ Ys) {
    constexpr int CIN = 64, DIL = 2;
    constexpr int TT  = 64;
    constexpr int HS  = TT + 2*DIL;        // 68
    constexpr int NCK = HS*8;
    constexpr int NCKP = ((NCK + 255)/256)*256;
    __shared__ __align__(16) ushort_t hs_[NCKP*8];

    const int tid  = threadIdx.x;
    const int lane = tid & 63;
    const int wid  = tid >> 6;            // 0..3: cols wid*32 + n*16
    const int l16  = lane & 15;
    const int l4   = lane >> 4;
    const int t0   = blockIdx.x * TT;
    const int b    = blockIdx.y;

    const long long rowbase = ((long long)b*T_ + (t0 - DIL)) * CIN;
    for (int c0 = wid*64; c0 < NCKP; c0 += 256) {
        int ck = c0 + lane;
        int r  = ck >> 3;
        int sc = ck ^ (r & 7);
        gload16(Xs + rowbase + (long long)sc*8, (char*)hs_ + (size_t)c0*16);
    }
    __syncthreads();
    if (t0 < DIL || t0 + TT + DIL > T_) {
        for (int idx = tid; idx < HS*CIN/4; idx += 256) {
            int e = idx << 2;
            int r = e / CIN, ci = e % CIN;
            int t = t0 - DIL + r;
            if (t < 0 || t >= T_) {
                unsigned byte = ((unsigned)(r*CIN + ci))*2u ^ ((unsigned)((r & 7) << 4));
                *(uint2*)((char*)hs_ + byte) = make_uint2(0u, 0u);
            }
        }
        __syncthreads();
    }

    f32x4 acc[4][2];
    const f32x4 z = {0.f, 0.f, 0.f, 0.f};
#pragma unroll
    for (int m = 0; m < 4; ++m)
#pragma unroll
        for (int n = 0; n < 2; ++n) acc[m][n] = z;

#pragma unroll
    for (int k = 0; k < 3; ++k) {
#pragma unroll
        for (int cb = 0; cb < 2; ++cb) {
            bf16x8 bh[2], bl[2];
#pragma unroll
            for (int n = 0; n < 2; ++n) {
                size_t off = ((((size_t)k*2 + cb)*8 + wid*2 + n)*64 + lane)*8;
                bh[n] = *(const bf16x8*)(Wh + off);
                bl[n] = *(const bf16x8*)(Wl + off);
            }
            bf16x8 ah[4];
#pragma unroll
            for (int m = 0; m < 4; ++m) {
                int r = m*16 + l16 + k*DIL;
                unsigned byte = ((unsigned)(r*CIN + cb*32 + l4*8))*2u
                              ^ ((unsigned)((r & 7) << 4));
                ah[m] = *(const bf16x8*)((const char*)hs_ + byte);
            }
#pragma unroll
            for (int m = 0; m < 4; ++m)
#pragma unroll
                for (int n = 0; n < 2; ++n) {
                    acc[m][n] = __builtin_amdgcn_mfma_f32_16x16x32_bf16(ah[m], bh[n], acc[m][n], 0, 0, 0);
                    acc[m][n] = __builtin_amdgcn_mfma_f32_16x16x32_bf16(ah[m], bl[n], acc[m][n], 0, 0, 0);
                }
        }
    }

#pragma unroll
    for (int m = 0; m < 4; ++m) {
        int tl_base = m*16 + l4*4;
#pragma unroll
        for (int n = 0; n < 2; ++n) {
            int c = wid*32 + n*16 + l16;
            float bv = bias[c];
#pragma unroll
            for (int rg = 0; rg < 4; ++rg) {
                int tl = tl_base + rg;
                int t  = t0 + tl;
                if (t < T_) {
                    float v = acc[m][n][rg] + bv;
                    Ys[((size_t)b*T_ + t)*128 + c] = f2bf(v);
                }
            }
        }
    }
}

// ---------------------------------------------------------------------------
// Fused conv2+conv3, 128-row tile (8 row-frags per weight chunk), TT=112.
__launch_bounds__(512, 4)
__global__ void dconv23_fused(const ushort_t* __restrict__ Xs,
                              const ushort_t* __restrict__ W2h, const ushort_t* __restrict__ W2l,
                              const ushort_t* __restrict__ W3h, const ushort_t* __restrict__ W3l,
                              const float* __restrict__ bc2, const float* __restrict__ bc3,
                              ushort_t* __restrict__ Ys) {
    constexpr int TT = 112;
    __shared__ __align__(16) ushort_t i1s[128*128];  // rows t0-8 .. t0+119
    __shared__ __align__(16) ushort_t ss_[128*128];

    const int tid  = threadIdx.x;
    const int lane = tid & 63;
    const int wid  = tid >> 6;            // 0..7: cols wid*16 + l16
    const int l16  = lane & 15, l4 = lane >> 4;
    const int t0   = blockIdx.x * TT;
    const int b    = blockIdx.y;

    const long long rowbase = ((long long)b*T_ + (t0 - 8)) * 128;
    for (int c0 = wid*64; c0 < 2048; c0 += 512) {
        int ck = c0 + lane;
        int r  = ck >> 4;
        int sc = ck ^ (r & 7);
        gload16(Xs + rowbase + (long long)sc*8, (char*)i1s + (size_t)c0*16);
    }
    __syncthreads();
    if (t0 < 8 || t0 + 120 > T_) {
        for (int idx = tid; idx < 128*128/4; idx += 512) {
            int e = idx << 2;
            int r = e >> 7, ci = e & 127;
            int t = t0 - 8 + r;
            if (t < 0 || t >= T_) {
                unsigned byte = ((unsigned)(r*128 + ci))*2u ^ ((unsigned)((r & 7) << 4));
                *(uint2*)((char*)i1s + byte) = make_uint2(0u, 0u);
            }
        }
        __syncthreads();
    }

    // ---- phase 1: conv2, all 128 local rows, wave = 16 cols ----
    {
        f32x4 acc[8];
        const f32x4 z = {0.f,0.f,0.f,0.f};
#pragma unroll
        for (int m = 0; m < 8; ++m) acc[m] = z;
#pragma unroll
        for (int k = 0; k < 3; ++k) {
#pragma unroll
            for (int cb = 0; cb < 4; ++cb) {
                size_t off = ((((size_t)k*4 + cb)*8 + wid)*64 + lane)*8;
                bf16x8 bh = *(const bf16x8*)(W2h + off);
                bf16x8 bl = *(const bf16x8*)(W2l + off);
#pragma unroll
                for (int m = 0; m < 8; ++m) {
                    int r = m*16 + l16 + k*3 - 3;
                    r = min(max(r, 0), 127);  // garbage edge rows; never consumed
                    unsigned byte = ((unsigned)(r*128 + cb*32 + l4*8))*2u
                                  ^ ((unsigned)((r & 7) << 4));
                    bf16x8 ah = *(const bf16x8*)((const char*)i1s + byte);
                    acc[m] = __builtin_amdgcn_mfma_f32_16x16x32_bf16(ah, bh, acc[m], 0, 0, 0);
                    acc[m] = __builtin_amdgcn_mfma_f32_16x16x32_bf16(ah, bl, acc[m], 0, 0, 0);
                }
            }
        }
        const int c = wid*16 + l16;
        const float bv = bc2[c];
#pragma unroll
        for (int m = 0; m < 8; ++m) {
#pragma unroll
            for (int rg = 0; rg < 4; ++rg) {
                int rl = m*16 + l4*4 + rg;
                int t  = t0 - 8 + rl;
                float v = 0.0f;
                unsigned byte = ((unsigned)(rl*128 + c))*2u ^ ((unsigned)((rl & 7) << 4));
                if (t >= 0 && t < T_) {
                    float cen = bf2f(*(const ushort_t*)((const char*)i1s + byte));
                    v = acc[m][rg] + bv + 2.0f*cen;
                }
                *(ushort_t*)((char*)ss_ + byte) = f2bf(v);
            }
        }
    }
    __syncthreads();

    // ---- phase 2: conv3 over 112 output rows, wave = 16 cols ----
    {
        f32x4 acc[7];
        const f32x4 z = {0.f,0.f,0.f,0.f};
#pragma unroll
        for (int m = 0; m < 7; ++m) acc[m] = z;
#pragma unroll
        for (int k = 0; k < 3; ++k) {
#pragma unroll
            for (int cb = 0; cb < 4; ++cb) {
                size_t off = ((((size_t)k*4 + cb)*8 + wid)*64 + lane)*8;
                bf16x8 bh = *(const bf16x8*)(W3h + off);
                bf16x8 bl = *(const bf16x8*)(W3l + off);
#pragma unroll
                for (int m = 0; m < 7; ++m) {
                    int r = 8 + m*16 + l16 + k*4 - 4;  // in [4,123]
                    unsigned byte = ((unsigned)(r*128 + cb*32 + l4*8))*2u
                                  ^ ((unsigned)((r & 7) << 4));
                    bf16x8 ah = *(const bf16x8*)((const char*)ss_ + byte);
                    acc[m] = __builtin_amdgcn_mfma_f32_16x16x32_bf16(ah, bh, acc[m], 0, 0, 0);
                    acc[m] = __builtin_amdgcn_mfma_f32_16x16x32_bf16(ah, bl, acc[m], 0, 0, 0);
                }
            }
        }
        const int c = wid*16 + l16;
        const float bv = bc3[c];
#pragma unroll
        for (int m = 0; m < 7; ++m) {
#pragma unroll
            for (int rg = 0; rg < 4; ++rg) {
                int rl = 8 + m*16 + l4*4 + rg;         // s local row in [8,119]
                int t  = t0 - 8 + rl;
                if (t < T_) {
                    unsigned byte = ((unsigned)(rl*128 + c))*2u ^ ((unsigned)((rl & 7) << 4));
                    float cen = bf2f(*(const ushort_t*)((const char*)ss_ + byte));
                    float v = acc[m][rg] + bv + cen;
                    Ys[((size_t)b*T_ + t)*128 + c] = f2bf(v);
                }
            }
        }
    }
}

// ---------------------------------------------------------------------------
// Fused ASP: full 128x128 i3 tile staged ONCE (feeds stage1 + stats).
__launch_bounds__(256)
__global__ void asp_fused(const ushort_t* __restrict__ As,
                          const ushort_t* __restrict__ Wa1h, const ushort_t* __restrict__ Wa1l,
                          const ushort_t* __restrict__ Wa2h, const ushort_t* __restrict__ Wa2l,
                          const float* __restrict__ ba1, const float* __restrict__ ba2,
                          float* __restrict__ pm, float* __restrict__ ps,
                          float* __restrict__ pcm, float* __restrict__ pcq) {
    __shared__ __align__(16) char smem[49152];
    ushort_t* xs_ = (ushort_t*)smem;               // [128][128] i3 (whole kernel)
    ushort_t* vs_ = (ushort_t*)(smem + 32768);     // v [128][64]
    __shared__ float redM[2][128];
    __shared__ float redS[2][128];
    __shared__ float redAM[2][128];
    __shared__ float redAQ[2][128];

    const int tid  = threadIdx.x;
    const int lane = tid & 63;
    const int wid  = tid >> 6;
    const int wy   = wid >> 1, wx = wid & 1;
    const int l16  = lane & 15, l4 = lane >> 4;
    const int ch   = blockIdx.x;
    const int b    = blockIdx.y;
    const int t0   = ch * CHL;
    const size_t xrow = ((size_t)b*T_ + t0) * 128;

    // ---- stage full i3 tile once ----
    for (int c0 = wid*64; c0 < 2048; c0 += 256) {
        int ck = c0 + lane;
        int r  = ck >> 4, wc = ck & 15;
        int sc = wc ^ (r & 7);
        gload16(As + xrow + (size_t)r*128 + sc*8, (char*)xs_ + (size_t)c0*16);
    }
    __syncthreads();

    // ---- stage 1: v = tanh(i3 @ wa1^T + ba1), K=128 in 2 chunks ----
    f32x4 acc1[4][2];
    const f32x4 z = {0.f,0.f,0.f,0.f};
#pragma unroll
    for (int m = 0; m < 4; ++m) { acc1[m][0] = z; acc1[m][1] = z; }

#pragma unroll
    for (int k0 = 0; k0 < 128; k0 += 64) {
#pragma unroll
        for (int kk = 0; kk < 64; kk += 32) {
            bf16x8 bh[2], bl[2];
#pragma unroll
            for (int n = 0; n < 2; ++n) {
                size_t off = (((size_t)((k0 + kk) >> 5)*4 + wx*2 + n)*64 + lane)*8;
                bh[n] = *(const bf16x8*)(Wa1h + off);
                bl[n] = *(const bf16x8*)(Wa1l + off);
            }
            bf16x8 fh[4];
#pragma unroll
            for (int m = 0; m < 4; ++m) {
                int r = wy*64 + m*16 + l16;
                unsigned byte = ((unsigned)(r*128 + k0 + kk + l4*8))*2u
                              ^ ((unsigned)((r & 7) << 4));
                fh[m] = *(const bf16x8*)((const char*)xs_ + byte);
            }
#pragma unroll
            for (int m = 0; m < 4; ++m)
#pragma unroll
                for (int n = 0; n < 2; ++n) {
                    acc1[m][n] = __builtin_amdgcn_mfma_f32_16x16x32_bf16(fh[m], bh[n], acc1[m][n], 0, 0, 0);
                    acc1[m][n] = __builtin_amdgcn_mfma_f32_16x16x32_bf16(fh[m], bl[n], acc1[m][n], 0, 0, 0);
                }
        }
    }
    // epilogue 1: tanh, write v (single bf16) to LDS
#pragma unroll
    for (int m = 0; m < 4; ++m)
#pragma unroll
        for (int n = 0; n < 2; ++n) {
            int c = wx*32 + n*16 + l16;
            float bv = ba1[c];
            int rb = wy*64 + m*16 + l4*4;
#pragma unroll
            for (int rg = 0; rg < 4; ++rg) {
                float v = tanhf(acc1[m][n][rg] + bv);
                int r = rb + rg;
                unsigned byte = ((unsigned)(r*64 + c))*2u ^ ((unsigned)((r & 7) << 4));
                *(ushort_t*)((char*)vs_ + byte) = f2bf(v);
            }
        }
    __syncthreads();

    // ---- stage 2: D[n][t] = wa2 . v ----
    f32x4 acc2[4][4];
#pragma unroll
    for (int m = 0; m < 4; ++m)
#pragma unroll
        for (int j = 0; j < 4; ++j) acc2[m][j] = z;

#pragma unroll
    for (int kk = 0; kk < 64; kk += 32) {
        bf16x8 awh[4], awl[4];
#pragma unroll
        for (int m = 0; m < 4; ++m) {
            size_t off = (((size_t)(kk >> 5)*8 + wy*4 + m)*64 + lane)*8;
            awh[m] = *(const bf16x8*)(Wa2h + off);
            awl[m] = *(const bf16x8*)(Wa2l + off);
        }
        bf16x8 bv_[4];
#pragma unroll
        for (int j = 0; j < 4; ++j) {
            int r = wx*64 + j*16 + l16;
            unsigned byte = ((unsigned)(r*64 + kk + l4*8))*2u ^ ((unsigned)((r & 7) << 4));
            bv_[j] = *(const bf16x8*)((const char*)vs_ + byte);
        }
#pragma unroll
        for (int m = 0; m < 4; ++m)
#pragma unroll
            for (int j = 0; j < 4; ++j) {
                acc2[m][j] = __builtin_amdgcn_mfma_f32_16x16x32_bf16(awh[m], bv_[j], acc2[m][j], 0, 0, 0);
                acc2[m][j] = __builtin_amdgcn_mfma_f32_16x16x32_bf16(awl[m], bv_[j], acc2[m][j], 0, 0, 0);
            }
    }

    // epilogue 2: bias; chunk max; weighted sums from the SAME staged tile
#pragma unroll
    for (int m = 0; m < 4; ++m) {
        const float4 bv = *(const float4*)&ba2[wy*64 + m*16 + l4*4];
#pragma unroll
        for (int j = 0; j < 4; ++j) {
            acc2[m][j][0] += bv.x; acc2[m][j][1] += bv.y;
            acc2[m][j][2] += bv.z; acc2[m][j][3] += bv.w;
        }
    }
#pragma unroll
    for (int m = 0; m < 4; ++m)
#pragma unroll
        for (int rg = 0; rg < 4; ++rg) {
            int n = wy*64 + m*16 + l4*4 + rg;
            float mx = -INFINITY;
#pragma unroll
            for (int j = 0; j < 4; ++j) {
                int tg = t0 + wx*64 + j*16 + l16;
                if (tg < T_) mx = fmaxf(mx, acc2[m][j][rg]);
            }
            mx = fmaxf(mx, __shfl_xor(mx, 1));
            mx = fmaxf(mx, __shfl_xor(mx, 2));
            mx = fmaxf(mx, __shfl_xor(mx, 4));
            mx = fmaxf(mx, __shfl_xor(mx, 8));
            if (l16 == 0) redM[wx][n] = mx;
        }
    __syncthreads();
#pragma unroll
    for (int m = 0; m < 4; ++m)
#pragma unroll
        for (int rg = 0; rg < 4; ++rg) {
            int n = wy*64 + m*16 + l4*4 + rg;
            const float mch = fmaxf(redM[0][n], redM[1][n]);
            float se = 0.0f, am = 0.0f, aq = 0.0f;
#pragma unroll
            for (int j = 0; j < 4; ++j) {
                int tl = wx*64 + j*16 + l16;
                int tg = t0 + tl;
                if (tg < T_) {
                    float p = expf(acc2[m][j][rg] - mch);
                    unsigned byte = ((unsigned)(tl*128 + n))*2u ^ ((unsigned)((tl & 7) << 4));
                    float x = bf2f(*(const ushort_t*)((const char*)xs_ + byte));
                    se += p; am += p*x; aq += p*x*x;
                }
            }
#pragma unroll
            for (int d = 1; d <= 8; d <<= 1) {
                se += __shfl_xor(se, d);
                am += __shfl_xor(am, d);
                aq += __shfl_xor(aq, d);
            }
            if (l16 == 0) { redS[wx][n] = se; redAM[wx][n] = am; redAQ[wx][n] = aq; }
        }
    __syncthreads();
    if (tid < 128) {
        float m0 = redM[0][tid], m1 = redM[1][tid];
        float M  = fmaxf(m0, m1);
        size_t o = ((size_t)b*NCH + ch)*128 + tid;
        pm[o]  = M;
        ps[o]  = redS[0][tid]  + redS[1][tid];
        pcm[o] = redAM[0][tid] + redAM[1][tid];
        pcq[o] = redAQ[0][tid] + redAQ[1][tid];
    }
}

// ---------------------------------------------------------------------------
// final: global softmax combine + stats + layernorm(256) + coalesced linear.
__launch_bounds__(256)
__global__ void final_kernel(const float* __restrict__ pcm, const float* __restrict__ pcq,
                             const float* __restrict__ pm, const float* __restrict__ ps,
                             const float* __restrict__ gamma, const float* __restrict__ beta,
                             const float* __restrict__ w2t, const float* __restrict__ b2,
                             float* __restrict__ out) {
    __shared__ float row[256];
    __shared__ float nrm[256];
    __shared__ float red[8];
    const int tid = threadIdx.x, b = blockIdx.x;
    if (tid < 128) {
        float M = -INFINITY;
        for (int ch = 0; ch < NCH; ++ch)
            M = fmaxf(M, pm[((size_t)b*NCH + ch)*128 + tid]);
        float S = 0.0f, sm = 0.0f, sq = 0.0f;
        for (int ch = 0; ch < NCH; ++ch) {
            size_t o = ((size_t)b*NCH + ch)*128 + tid;
            float m = pm[o];
            if (m > -INFINITY) {
                float e = expf(m - M);
                S  += ps[o]*e;
                sm += pcm[o]*e;
                sq += pcq[o]*e;
            }
        }
        float mean = sm / S;
        float q    = sq / S;
        float resid = q - mean*mean;
        float stdv  = sqrtf(fmaxf(resid, 1e-9f));
        row[tid]       = mean;
        row[128 + tid] = stdv;
    }
    __syncthreads();
    float v  = row[tid];
    float s1 = v, s2 = v*v;
    for (int off = 32; off >= 1; off >>= 1) {
        s1 += __shfl_down(s1, off, 64);
        s2 += __shfl_down(s2, off, 64);
    }
    if ((tid & 63) == 0) { red[tid >> 6] = s1; red[4 + (tid >> 6)] = s2; }
    __syncthreads();
    float S1 = red[0] + red[1] + red[2] + red[3];
    float S2 = red[4] + red[5] + red[6] + red[7];
    float mu  = S1 / 256.0f;
    float var = S2 / 256.0f - mu*mu;
    float inv = 1.0f / sqrtf(var + 1e-5f);
    nrm[tid] = (v - mu)*inv*gamma[tid] + beta[tid];
    __syncthreads();
    float acc0 = b2[tid], acc1 = b2[tid + 256];
#pragma unroll 4
    for (int j = 0; j < 256; ++j) {
        float nv = nrm[j];
        const float* wr = w2t + (size_t)j*512;
        acc0 += wr[tid]       * nv;
        acc1 += wr[tid + 256] * nv;
    }
    out[(size_t)b*512 + tid]       = acc0;
    out[(size_t)b*512 + tid + 256] = acc1;
}

// ---------------------------------------------------------------------------
extern "C" void kernel_launch(void* const* d_in, const int* in_sizes, int n_in,
                              void* d_out, int out_size, void* d_ws, size_t ws_size,
                              hipStream_t stream) {
    const float* x      = (const float*)d_in[0];
    const float* bp     = (const float*)d_in[1];
    const float* w_lin1 = (const float*)d_in[2];
    const float* b_lin1 = (const float*)d_in[3];
    const float* wc1    = (const float*)d_in[4];
    const float* bc1    = (const float*)d_in[5];
    const float* wc2    = (const float*)d_in[6];
    const float* bc2    = (const float*)d_in[7];
    const float* wc3    = (const float*)d_in[8];
    const float* bc3    = (const float*)d_in[9];
    const float* wa1    = (const float*)d_in[10];
    const float* ba1    = (const float*)d_in[11];
    const float* wa2    = (const float*)d_in[12];
    const float* ba2    = (const float*)d_in[13];
    const float* gamma  = (const float*)d_in[14];
    const float* beta   = (const float*)d_in[15];
    const float* wl2    = (const float*)d_in[16];
    const float* bl2    = (const float*)d_in[17];

    float* ws   = (float*)d_ws;
    float* bs   = ws + OFF_BS;
    ushort_t* weh  = (ushort_t*)(ws + OFF_WEFF);
    ushort_t* wel  = weh + 64*320;
    float* wtail   = ws + OFF_WTAIL;
    ushort_t* w1h  = (ushort_t*)(ws + OFF_W1);
    ushort_t* w1l  = w1h + 3*128*64;
    ushort_t* w2h  = (ushort_t*)(ws + OFF_W2);
    ushort_t* w2l  = w2h + 3*128*128;
    ushort_t* w3h  = (ushort_t*)(ws + OFF_W3);
    ushort_t* w3l  = w3h + 3*128*128;
    ushort_t* wa1h = (ushort_t*)(ws + OFF_WA1);
    ushort_t* wa1l = wa1h + 64*128;
    ushort_t* wa2h = (ushort_t*)(ws + OFF_WA2);
    ushort_t* wa2l = wa2h + 128*64;
    float* pm   = ws + OFF_PM;
    float* ps   = ws + OFF_PS;
    float* pcm  = ws + OFF_PCM;
    float* pcq  = ws + OFF_PCQ;
    ushort_t* Hs = (ushort_t*)(ws + OFF_HS);
    ushort_t* As = (ushort_t*)(ws + OFF_AS);
    ushort_t* Bs = (ushort_t*)(ws + OFF_BSP);
    float* wl2t  = ws + OFF_WL2T;

    sort_kernel<<<dim3(1), dim3(64), 0, stream>>>(bp, bs);
    prep_kernel<<<dim3(1136), dim3(256), 0, stream>>>(bs, w_lin1, wc1, wc2, wc3, wa1, wa2,
                                                      wl2, weh, wel, wtail, w1h, w1l,
                                                      w2h, w2l, w3h, w3l, wa1h, wa1l,
                                                      wa2h, wa2l, wl2t);
    // h = relu(x @ Weff^T + b_lin1) -> single bf16 plane
    lin1_mfma<<<dim3(R_/128), dim3(256), 0, stream>>>(x, weh, wel, wtail, b_lin1, Hs);
    // i1 = conv1(h) + b
    dconv1_mfma<<<dim3(47, B_), dim3(256), 0, stream>>>(Hs, w1h, w1l, bc1, As);
    // i3 = conv3(conv2(i1)+b2+2*i1) + b3 + s  (s in LDS only), TT=112
    dconv23_fused<<<dim3(27, B_), dim3(512), 0, stream>>>(As, w2h, w2l, w3h, w3l,
                                                          bc2, bc3, Bs);
    // fused asp1+asp2+softmax partials+weighted stats (single i3 stage)
    asp_fused<<<dim3(NCH, B_), dim3(256), 0, stream>>>(Bs, wa1h, wa1l, wa2h, wa2l,
                                                       ba1, ba2, pm, ps, pcm, pcq);
    // global combine + stats + LN + coalesced 256->512 linear
    final_kernel<<<dim3(B_), dim3(256), 0, stream>>>(pcm, pcq, pm, ps, gamma, beta,
                                                     wl2t, bl2, (float*)d_out);
}

// Round 17
// 300.929 us; speedup vs baseline: 1.6585x; 1.1664x over previous
//
#include <hip/hip_runtime.h>
#include <math.h>

// ---------------------------------------------------------------------------
// ResCNN_ASP_SpeakerEncoder — v16: conv2+conv3+ASP fully fused, TT=128
// (i3 lives only in LDS: phase2 writes it in-place over dead s buffer via
// register staging + double barrier; ASP reads it from LDS). i3 HBM round
// trip (98 MB) and the asp dispatch eliminated. v15 base otherwise.
// ---------------------------------------------------------------------------

constexpr int B_  = 64;
constexpr int T_  = 3000;
constexpr int NB_ = 257;   // NBINS
constexpr int R_  = B_ * T_;           // 192000 rows
constexpr int NCH = 24;                // chunks (24 x 128)

// workspace layout (float offsets)
constexpr size_t OFF_BS    = 0;
constexpr size_t OFF_WEFF  = 128;                          // ushort hi[64*320]+lo
constexpr size_t OFF_WTAIL = OFF_WEFF + 20480;
constexpr size_t OFF_W1    = OFF_WTAIL + 128;              // ushort hi+lo 3*128*64
constexpr size_t OFF_W2    = OFF_W1  + 3*64*128;
constexpr size_t OFF_W3    = OFF_W2  + 3*128*128;
constexpr size_t OFF_WA1   = OFF_W3  + 3*128*128;
constexpr size_t OFF_WA2   = OFF_WA1 + 8192;
constexpr size_t SZ_P      = (size_t)B_*NCH*128;
constexpr size_t OFF_PM    = OFF_WA2 + 8192;
constexpr size_t OFF_PS    = OFF_PM  + SZ_P;
constexpr size_t OFF_PCM   = OFF_PS  + SZ_P;
constexpr size_t OFF_PCQ   = OFF_PCM + SZ_P;
// single bf16 planes
constexpr size_t OFF_HS    = OFF_PCQ + SZ_P;               // h  [R*64]u
constexpr size_t OFF_AS    = OFF_HS  + (size_t)R_*32;      // i1 [R*128]u
constexpr size_t OFF_SLACK = OFF_AS  + (size_t)R_*64;      // slack (DMA overrun)
constexpr size_t OFF_WL2T  = OFF_SLACK + 4096;             // fp32 [256][512]

typedef __attribute__((ext_vector_type(8))) short  bf16x8;
typedef __attribute__((ext_vector_type(4))) float  f32x4;
typedef __attribute__((ext_vector_type(4), aligned(4))) float float4a;
typedef unsigned short ushort_t;

typedef __attribute__((address_space(3))) unsigned int        as3_u32;
typedef const __attribute__((address_space(1))) unsigned int  as1_u32c;
__device__ __forceinline__ void gload16(const void* g, void* l) {
    __builtin_amdgcn_global_load_lds((as1_u32c*)g, (as3_u32*)l, 16, 0, 0);
}

__device__ inline ushort_t f2bf(float f) {                // RNE f32->bf16
    unsigned u = __float_as_uint(f);
    unsigned r = u + 0x7FFFu + ((u >> 16) & 1u);
    return (ushort_t)(r >> 16);
}
__device__ inline float bf2f(ushort_t h) {
    return __uint_as_float(((unsigned)h) << 16);
}
__device__ inline void split2(float v, ushort_t &h, ushort_t &l) {
    h = f2bf(v);
    l = f2bf(v - bf2f(h));
}

// pack 4 f32 -> 4 bf16 (RNE, 2 u32)
__device__ inline void pack_hi4(float x, float y, float z, float w, uint2 &ph) {
    unsigned hx, hy;
    asm("v_cvt_pk_bf16_f32 %0, %1, %2" : "=v"(hx) : "v"(x), "v"(y));
    asm("v_cvt_pk_bf16_f32 %0, %1, %2" : "=v"(hy) : "v"(z), "v"(w));
    ph.x = hx; ph.y = hy;
}

// ---------------------------------------------------------------------------
__global__ void sort_kernel(const float* __restrict__ bp, float* __restrict__ bs) {
    if (threadIdx.x == 0) {
        float tmp[82];
        for (int i = 0; i < 82; ++i) tmp[i] = bp[i];
        for (int i = 1; i < 82; ++i) {
            float key = tmp[i];
            int j = i - 1;
            while (j >= 0 && tmp[j] > key) { tmp[j+1] = tmp[j]; --j; }
            tmp[j+1] = key;
        }
        for (int i = 0; i < 82; ++i) bs[i] = tmp[i];
    }
}

// Fragment-order packing (B: lane&15=col, lane>>4=k-octet; A: lane&15=row),
// plus fp32 wl2 transpose [256 j][512 o].
__global__ void prep_kernel(const float* __restrict__ bs, const float* __restrict__ wl1,
                            const float* __restrict__ wc1, const float* __restrict__ wc2,
                            const float* __restrict__ wc3, const float* __restrict__ wa1,
                            const float* __restrict__ wa2, const float* __restrict__ wl2,
                            ushort_t* __restrict__ weh, ushort_t* __restrict__ wel,
                            float* __restrict__ wtail,
                            ushort_t* __restrict__ w1h, ushort_t* __restrict__ w1l,
                            ushort_t* __restrict__ w2h, ushort_t* __restrict__ w2l,
                            ushort_t* __restrict__ w3h, ushort_t* __restrict__ w3l,
                            ushort_t* __restrict__ wa1h, ushort_t* __restrict__ wa1l,
                            ushort_t* __restrict__ wa2h, ushort_t* __restrict__ wa2l,
                            float* __restrict__ wl2t) {
    int gid = blockIdx.x * 256 + threadIdx.x;
    if (gid < 64*320) {                            // Weff[o][f]
        int o = gid / 320, f = gid % 320;
        if (f > 256) return;
        float acc = 0.0f;
        if (f == 0) acc = wl1[o*80];               // filt[:,:,0] = x[:,:,0]
        else {
            for (int n = 1; n < 79; ++n) {
                float bn = bs[n], bn1 = bs[n+1], bn2 = bs[n+2];
                int ibn  = (int)floorf(bn);
                int ibn1 = (int)floorf(bn1);
                int ibn2 = (int)floorf(bn2);
                float fbv = 0.0f;
                if (f >= ibn && f < ibn1) {
                    float d = (bn1-bn)*(bn1-bn);
                    fbv = ((float)f - bn) / (d > 0.0f ? d : 1.0f);
                } else if (f >= ibn1 && f < ibn2) {
                    float d = (bn2-bn1)*(bn2-bn1);
                    fbv = (bn2 - (float)f) / (d > 0.0f ? d : 1.0f);
                }
                acc += wl1[o*80 + n] * fbv;
            }
        }
        if (f == 256) { wtail[o] = acc; return; }
        int kc = f >> 5, lane = ((f & 31) >> 3)*16 + (o & 15), e = f & 7;
        size_t dst = (((size_t)kc*4 + (o >> 4))*64 + lane)*8 + e;
        split2(acc, weh[dst], wel[dst]);
        return;
    }
    gid -= 64*320;
    if (gid < 3*128*64) {                          // conv1: [k][c][ci=64]
        int k = gid / (128*64), rem = gid % (128*64);
        int c = rem >> 6, ci = rem & 63;
        float v = wc1[(c*64 + ci)*3 + k];
        int lane = ((ci & 31) >> 3)*16 + (c & 15), e = ci & 7;
        size_t dst = ((((size_t)k*2 + (ci >> 5))*8 + (c >> 4))*64 + lane)*8 + e;
        split2(v, w1h[dst], w1l[dst]);
        return;
    }
    gid -= 3*128*64;
    if (gid < 3*128*128) {                         // conv2
        int k = gid / (128*128), rem = gid % (128*128);
        int c = rem >> 7, ci = rem & 127;
        float v = wc2[(c*128 + ci)*3 + k];
        int lane = ((ci & 31) >> 3)*16 + (c & 15), e = ci & 7;
        size_t dst = ((((size_t)k*4 + (ci >> 5))*8 + (c >> 4))*64 + lane)*8 + e;
        split2(v, w2h[dst], w2l[dst]);
        return;
    }
    gid -= 3*128*128;
    if (gid < 3*128*128) {                         // conv3
        int k = gid / (128*128), rem = gid % (128*128);
        int c = rem >> 7, ci = rem & 127;
        float v = wc3[(c*128 + ci)*3 + k];
        int lane = ((ci & 31) >> 3)*16 + (c & 15), e = ci & 7;
        size_t dst = ((((size_t)k*4 + (ci >> 5))*8 + (c >> 4))*64 + lane)*8 + e;
        split2(v, w3h[dst], w3l[dst]);
        return;
    }
    gid -= 3*128*128;
    if (gid < 64*128) {                            // wa1 [c=64][ci=128]
        int c = gid >> 7, ci = gid & 127;
        float v = wa1[gid];
        int lane = ((ci & 31) >> 3)*16 + (c & 15), e = ci & 7;
        size_t dst = (((size_t)(ci >> 5)*4 + (c >> 4))*64 + lane)*8 + e;
        split2(v, wa1h[dst], wa1l[dst]);
        return;
    }
    gid -= 64*128;
    if (gid < 128*64) {                            // wa2 [n=128][ci=64] (A op)
        int n = gid >> 6, ci = gid & 63;
        float v = wa2[gid];
        int lane = ((ci & 31) >> 3)*16 + (n & 15), e = ci & 7;
        size_t dst = (((size_t)(ci >> 5)*8 + (n >> 4))*64 + lane)*8 + e;
        split2(v, wa2h[dst], wa2l[dst]);
        return;
    }
    gid -= 128*64;
    if (gid < 256*512) {                           // wl2T[j][o] <- wl2[o][j]
        int j = gid >> 9, o = gid & 511;
        wl2t[gid] = wl2[(size_t)o*256 + j];
        return;
    }
}

// ---------------------------------------------------------------------------
// lin1: h = relu(x @ Weff^T + b); x staged as single bf16; 2-pass MFMA.
__launch_bounds__(256)
__global__ void lin1_mfma(const float* __restrict__ X,
                          const ushort_t* __restrict__ Wh, const ushort_t* __restrict__ Wl,
                          const float* __restrict__ wtail,
                          const float* __restrict__ bias,
                          ushort_t* __restrict__ Hs) {
    __shared__ __align__(16) ushort_t ash[128*64];
    __shared__ float xs[128];
    __shared__ float wts[64];
    const int tid  = threadIdx.x;
    const int lane = tid & 63;
    const int wid  = tid >> 6;
    const int wy   = wid >> 1, wx = wid & 1;
    const int l16  = lane & 15, l4 = lane >> 4;
    const int r0   = blockIdx.x * 128;

    if (tid < 128)       xs[tid] = X[(size_t)(r0 + tid)*NB_ + 256];
    else if (tid < 192)  wts[tid - 128] = wtail[tid - 128];

#define LIN1_LOAD(dst, k0)                                            \
    _Pragma("unroll")                                                 \
    for (int i = 0; i < 8; ++i) {                                     \
        int q = tid + i*256; int r = q >> 4, cc = (q & 15) << 2;      \
        dst[i] = *(const float4a*)(X + (size_t)(r0 + r)*NB_ + (k0) + cc); \
    }
#define LIN1_CW(src)                                                  \
    _Pragma("unroll")                                                 \
    for (int i = 0; i < 8; ++i) {                                     \
        int q = tid + i*256; int r = q >> 4, cc = (q & 15) << 2;      \
        uint2 ph;                                                     \
        pack_hi4(src[i].x, src[i].y, src[i].z, src[i].w, ph);         \
        unsigned byte = ((unsigned)(r*64 + cc))*2u ^ ((unsigned)((r & 7) << 4)); \
        *(uint2*)((char*)ash + byte) = ph;                            \
    }

    float4a bufA[8], bufB[8];
    LIN1_LOAD(bufA, 0);

    f32x4 acc[4][2];
    const f32x4 z = {0.f,0.f,0.f,0.f};
#pragma unroll
    for (int m = 0; m < 4; ++m) { acc[m][0] = z; acc[m][1] = z; }

#pragma unroll
    for (int ck = 0; ck < 4; ++ck) {
        const float4a* cur = (ck & 1) ? bufB : bufA;
        float4a*       nxt = (ck & 1) ? bufA : bufB;
        if (ck < 3) LIN1_LOAD(nxt, (ck + 1)*64);
        LIN1_CW(cur);
        __syncthreads();
#pragma unroll
        for (int kk = 0; kk < 64; kk += 32) {
            bf16x8 bh[2], bl[2];
#pragma unroll
            for (int n = 0; n < 2; ++n) {
                size_t off = (((size_t)(ck*2 + (kk >> 5))*4 + wx*2 + n)*64 + lane)*8;
                bh[n] = *(const bf16x8*)(Wh + off);
                bl[n] = *(const bf16x8*)(Wl + off);
            }
            bf16x8 fh[4];
#pragma unroll
            for (int m = 0; m < 4; ++m) {
                int r = wy*64 + m*16 + l16;
                unsigned byte = ((unsigned)(r*64 + kk + l4*8))*2u ^ ((unsigned)((r & 7) << 4));
                fh[m] = *(const bf16x8*)((const char*)ash + byte);
            }
#pragma unroll
            for (int m = 0; m < 4; ++m)
#pragma unroll
                for (int n = 0; n < 2; ++n) {
                    acc[m][n] = __builtin_amdgcn_mfma_f32_16x16x32_bf16(fh[m], bh[n], acc[m][n], 0, 0, 0);
                    acc[m][n] = __builtin_amdgcn_mfma_f32_16x16x32_bf16(fh[m], bl[n], acc[m][n], 0, 0, 0);
                }
        }
        __syncthreads();
    }
#undef LIN1_LOAD
#undef LIN1_CW

#pragma unroll
    for (int m = 0; m < 4; ++m)
#pragma unroll
        for (int n = 0; n < 2; ++n) {
            int c = wx*32 + n*16 + l16;
            float bv = bias[c];
            float wc = wts[c];
            int rbl = wy*64 + m*16 + l4*4;
#pragma unroll
            for (int rg = 0; rg < 4; ++rg) {
                int rl = rbl + rg;
                float v = fmaxf(acc[m][n][rg] + bv + xs[rl]*wc, 0.0f);
                Hs[(size_t)(r0 + rl)*64 + c] = f2bf(v);
            }
        }
}

// ---------------------------------------------------------------------------
// conv1 (CIN=64, DIL=2): column-tiled waves.
__launch_bounds__(256, 4)
__global__ void dconv1_mfma(const ushort_t* __restrict__ Xs,
                            const ushort_t* __restrict__ Wh, const ushort_t* __restrict__ Wl,
                            const float* __restrict__ bias,
                            ushort_t* __restrict__ Ys) {
    constexpr int CIN = 64, DIL = 2;
    constexpr int TT  = 64;
    constexpr int HS  = TT + 2*DIL;        // 68
    constexpr int NCK = HS*8;
    constexpr int NCKP = ((NCK + 255)/256)*256;
    __shared__ __align__(16) ushort_t hs_[NCKP*8];

    const int tid  = threadIdx.x;
    const int lane = tid & 63;
    const int wid  = tid >> 6;            // 0..3: cols wid*32 + n*16
    const int l16  = lane & 15;
    const int l4   = lane >> 4;
    const int t0   = blockIdx.x * TT;
    const int b    = blockIdx.y;

    const long long rowbase = ((long long)b*T_ + (t0 - DIL)) * CIN;
    for (int c0 = wid*64; c0 < NCKP; c0 += 256) {
        int ck = c0 + lane;
        int r  = ck >> 3;
        int sc = ck ^ (r & 7);
        gload16(Xs + rowbase + (long long)sc*8, (char*)hs_ + (size_t)c0*16);
    }
    __syncthreads();
    if (t0 < DIL || t0 + TT + DIL > T_) {
        for (int idx = tid; idx < HS*CIN/4; idx += 256) {
            int e = idx << 2;
            int r = e / CIN, ci = e % CIN;
            int t = t0 - DIL + r;
            if (t < 0 || t >= T_) {
                unsigned byte = ((unsigned)(r*CIN + ci))*2u ^ ((unsigned)((r & 7) << 4));
                *(uint2*)((char*)hs_ + byte) = make_uint2(0u, 0u);
            }
        }
        __syncthreads();
    }

    f32x4 acc[4][2];
    const f32x4 z = {0.f, 0.f, 0.f, 0.f};
#pragma unroll
    for (int m = 0; m < 4; ++m)
#pragma unroll
        for (int n = 0; n < 2; ++n) acc[m][n] = z;

#pragma unroll
    for (int k = 0; k < 3; ++k) {
#pragma unroll
        for (int cb = 0; cb < 2; ++cb) {
            bf16x8 bh[2], bl[2];
#pragma unroll
            for (int n = 0; n < 2; ++n) {
                size_t off = ((((size_t)k*2 + cb)*8 + wid*2 + n)*64 + lane)*8;
                bh[n] = *(const bf16x8*)(Wh + off);
                bl[n] = *(const bf16x8*)(Wl + off);
            }
            bf16x8 ah[4];
#pragma unroll
            for (int m = 0; m < 4; ++m) {
                int r = m*16 + l16 + k*DIL;
                unsigned byte = ((unsigned)(r*CIN + cb*32 + l4*8))*2u
                              ^ ((unsigned)((r & 7) << 4));
                ah[m] = *(const bf16x8*)((const char*)hs_ + byte);
            }
#pragma unroll
            for (int m = 0; m < 4; ++m)
#pragma unroll
                for (int n = 0; n < 2; ++n) {
                    acc[m][n] = __builtin_amdgcn_mfma_f32_16x16x32_bf16(ah[m], bh[n], acc[m][n], 0, 0, 0);
                    acc[m][n] = __builtin_amdgcn_mfma_f32_16x16x32_bf16(ah[m], bl[n], acc[m][n], 0, 0, 0);
                }
        }
    }

#pragma unroll
    for (int m = 0; m < 4; ++m) {
        int tl_base = m*16 + l4*4;
#pragma unroll
        for (int n = 0; n < 2; ++n) {
            int c = wid*32 + n*16 + l16;
            float bv = bias[c];
#pragma unroll
            for (int rg = 0; rg < 4; ++rg) {
                int tl = tl_base + rg;
                int t  = t0 + tl;
                if (t < T_) {
                    float v = acc[m][n][rg] + bv;
                    Ys[((size_t)b*T_ + t)*128 + c] = f2bf(v);
                }
            }
        }
    }
}

// ---------------------------------------------------------------------------
// Fused conv2+conv3+ASP, TT=128 per (chunk, b). i1 buffer 144 rows; s buffer
// 144 rows; i3 written in-place over s (register-staged, double barrier);
// ASP (stage1 v, stage2 logits, chunk softmax partials + weighted stats)
// reads i3 from LDS. v buffer aliases dead i1 space.
__launch_bounds__(512)
__global__ void dconv23_asp(const ushort_t* __restrict__ Xs,
                            const ushort_t* __restrict__ W2h, const ushort_t* __restrict__ W2l,
                            const ushort_t* __restrict__ W3h, const ushort_t* __restrict__ W3l,
                            const float* __restrict__ bc2, const float* __restrict__ bc3,
                            const ushort_t* __restrict__ Wa1h, const ushort_t* __restrict__ Wa1l,
                            const ushort_t* __restrict__ Wa2h, const ushort_t* __restrict__ Wa2l,
                            const float* __restrict__ ba1, const float* __restrict__ ba2,
                            float* __restrict__ pm, float* __restrict__ ps,
                            float* __restrict__ pcm, float* __restrict__ pcq) {
    __shared__ __align__(16) char smem[73728];
    ushort_t* i1s = (ushort_t*)smem;               // [144][128] rows t0-8..t0+135
    ushort_t* ss_ = (ushort_t*)(smem + 36864);     // s, then i3 (in-place)
    ushort_t* vs_ = (ushort_t*)smem;               // v [128][64] (i1 dead)

    const int tid  = threadIdx.x;
    const int lane = tid & 63;
    const int wid  = tid >> 6;            // 0..7
    const int l16  = lane & 15, l4 = lane >> 4;
    const int ch   = blockIdx.x;
    const int b    = blockIdx.y;
    const int t0   = ch * 128;

    // ---- stage i1 rows [t0-8, t0+136) ----
    const long long rowbase = ((long long)b*T_ + (t0 - 8)) * 128;
    for (int c0 = wid*64; c0 < 2304; c0 += 512) {
        int ck = c0 + lane;
        int r  = ck >> 4;
        int sc = ck ^ (r & 7);
        gload16(Xs + rowbase + (long long)sc*8, (char*)i1s + (size_t)c0*16);
    }
    __syncthreads();
    if (t0 < 8 || t0 + 136 > T_) {
        for (int idx = tid; idx < 144*128/4; idx += 512) {
            int e = idx << 2;
            int r = e >> 7, ci = e & 127;
            int t = t0 - 8 + r;
            if (t < 0 || t >= T_) {
                unsigned byte = ((unsigned)(r*128 + ci))*2u ^ ((unsigned)((r & 7) << 4));
                *(uint2*)((char*)i1s + byte) = make_uint2(0u, 0u);
            }
        }
        __syncthreads();
    }

    // ---- phase 1: conv2 over all 144 local rows -> s = conv2 + bc2 + 2*i1 ----
    {
        f32x4 acc[9];
        const f32x4 z = {0.f,0.f,0.f,0.f};
#pragma unroll
        for (int m = 0; m < 9; ++m) acc[m] = z;
#pragma unroll
        for (int k = 0; k < 3; ++k) {
#pragma unroll
            for (int cb = 0; cb < 4; ++cb) {
                size_t off = ((((size_t)k*4 + cb)*8 + wid)*64 + lane)*8;
                bf16x8 bh = *(const bf16x8*)(W2h + off);
                bf16x8 bl = *(const bf16x8*)(W2l + off);
#pragma unroll
                for (int m = 0; m < 9; ++m) {
                    int r = m*16 + l16 + k*3 - 3;
                    r = min(max(r, 0), 143);  // garbage edge rows; never consumed
                    unsigned byte = ((unsigned)(r*128 + cb*32 + l4*8))*2u
                                  ^ ((unsigned)((r & 7) << 4));
                    bf16x8 ah = *(const bf16x8*)((const char*)i1s + byte);
                    acc[m] = __builtin_amdgcn_mfma_f32_16x16x32_bf16(ah, bh, acc[m], 0, 0, 0);
                    acc[m] = __builtin_amdgcn_mfma_f32_16x16x32_bf16(ah, bl, acc[m], 0, 0, 0);
                }
            }
        }
        const int c = wid*16 + l16;
        const float bv = bc2[c];
#pragma unroll
        for (int m = 0; m < 9; ++m) {
#pragma unroll
            for (int rg = 0; rg < 4; ++rg) {
                int rl = m*16 + l4*4 + rg;
                int t  = t0 - 8 + rl;
                float v = 0.0f;
                unsigned byte = ((unsigned)(rl*128 + c))*2u ^ ((unsigned)((rl & 7) << 4));
                if (t >= 0 && t < T_) {
                    float cen = bf2f(*(const ushort_t*)((const char*)i1s + byte));
                    v = acc[m][rg] + bv + 2.0f*cen;
                }
                *(ushort_t*)((char*)ss_ + byte) = f2bf(v);
            }
        }
    }
    __syncthreads();

    // ---- phase 2: conv3 + residual into REGISTERS (reads s) ----
    float i3r[8][4];
    {
        f32x4 acc[8];
        const f32x4 z = {0.f,0.f,0.f,0.f};
#pragma unroll
        for (int m = 0; m < 8; ++m) acc[m] = z;
#pragma unroll
        for (int k = 0; k < 3; ++k) {
#pragma unroll
            for (int cb = 0; cb < 4; ++cb) {
                size_t off = ((((size_t)k*4 + cb)*8 + wid)*64 + lane)*8;
                bf16x8 bh = *(const bf16x8*)(W3h + off);
                bf16x8 bl = *(const bf16x8*)(W3l + off);
#pragma unroll
                for (int m = 0; m < 8; ++m) {
                    int r = 8 + m*16 + l16 + k*4 - 4;  // in [4,139]
                    unsigned byte = ((unsigned)(r*128 + cb*32 + l4*8))*2u
                                  ^ ((unsigned)((r & 7) << 4));
                    bf16x8 ah = *(const bf16x8*)((const char*)ss_ + byte);
                    acc[m] = __builtin_amdgcn_mfma_f32_16x16x32_bf16(ah, bh, acc[m], 0, 0, 0);
                    acc[m] = __builtin_amdgcn_mfma_f32_16x16x32_bf16(ah, bl, acc[m], 0, 0, 0);
                }
            }
        }
        const int c = wid*16 + l16;
        const float bv = bc3[c];
#pragma unroll
        for (int m = 0; m < 8; ++m)
#pragma unroll
            for (int rg = 0; rg < 4; ++rg) {
                int rl = 8 + m*16 + l4*4 + rg;         // in [8,136)
                unsigned byte = ((unsigned)(rl*128 + c))*2u ^ ((unsigned)((rl & 7) << 4));
                float cen = bf2f(*(const ushort_t*)((const char*)ss_ + byte));
                i3r[m][rg] = acc[m][rg] + bv + cen;
            }
    }
    __syncthreads();                       // all s reads complete
    // write i3 over s (rows [8,136) = t [t0, t0+128))
    {
        const int c = wid*16 + l16;
#pragma unroll
        for (int m = 0; m < 8; ++m)
#pragma unroll
            for (int rg = 0; rg < 4; ++rg) {
                int rl = 8 + m*16 + l4*4 + rg;
                unsigned byte = ((unsigned)(rl*128 + c))*2u ^ ((unsigned)((rl & 7) << 4));
                *(ushort_t*)((char*)ss_ + byte) = f2bf(i3r[m][rg]);
            }
    }
    __syncthreads();                       // i3 tile ready (and i1 dead)

    // ---- ASP stage 1: v = tanh(i3 @ wa1^T + ba1)  (wave: rowhalf x coltile) ----
    {
        const int wy = wid >> 2;          // 0..1: rows wy*64 + m*16
        const int wx = wid & 3;           // 0..3: cols wx*16
        f32x4 acc1[4];
        const f32x4 z = {0.f,0.f,0.f,0.f};
#pragma unroll
        for (int m = 0; m < 4; ++m) acc1[m] = z;
#pragma unroll
        for (int kc = 0; kc < 4; ++kc) {
            size_t off = (((size_t)kc*4 + wx)*64 + lane)*8;
            bf16x8 bh = *(const bf16x8*)(Wa1h + off);
            bf16x8 bl = *(const bf16x8*)(Wa1l + off);
#pragma unroll
            for (int m = 0; m < 4; ++m) {
                int rl = 8 + wy*64 + m*16 + l16;       // i3 row
                unsigned byte = ((unsigned)(rl*128 + kc*32 + l4*8))*2u
                              ^ ((unsigned)((rl & 7) << 4));
                bf16x8 ah = *(const bf16x8*)((const char*)ss_ + byte);
                acc1[m] = __builtin_amdgcn_mfma_f32_16x16x32_bf16(ah, bh, acc1[m], 0, 0, 0);
                acc1[m] = __builtin_amdgcn_mfma_f32_16x16x32_bf16(ah, bl, acc1[m], 0, 0, 0);
            }
        }
        const int c = wx*16 + l16;
        const float bv = ba1[c];
#pragma unroll
        for (int m = 0; m < 4; ++m)
#pragma unroll
            for (int rg = 0; rg < 4; ++rg) {
                float v = tanhf(acc1[m][rg] + bv);
                int r = wy*64 + m*16 + l4*4 + rg;      // t row in [0,128)
                unsigned byte = ((unsigned)(r*64 + c))*2u ^ ((unsigned)((r & 7) << 4));
                *(ushort_t*)((char*)vs_ + byte) = f2bf(v);
            }
    }
    __syncthreads();

    // ---- ASP stage 2 + softmax partials + weighted stats ----
    {
        f32x4 acc2[8];
        const f32x4 z = {0.f,0.f,0.f,0.f};
#pragma unroll
        for (int j = 0; j < 8; ++j) acc2[j] = z;
#pragma unroll
        for (int kc = 0; kc < 2; ++kc) {
            size_t off = (((size_t)kc*8 + wid)*64 + lane)*8;
            bf16x8 awh = *(const bf16x8*)(Wa2h + off);
            bf16x8 awl = *(const bf16x8*)(Wa2l + off);
#pragma unroll
            for (int j = 0; j < 8; ++j) {
                int t = j*16 + l16;
                unsigned byte = ((unsigned)(t*64 + kc*32 + l4*8))*2u
                              ^ ((unsigned)((t & 7) << 4));
                bf16x8 bv_ = *(const bf16x8*)((const char*)vs_ + byte);
                acc2[j] = __builtin_amdgcn_mfma_f32_16x16x32_bf16(awh, bv_, acc2[j], 0, 0, 0);
                acc2[j] = __builtin_amdgcn_mfma_f32_16x16x32_bf16(awl, bv_, acc2[j], 0, 0, 0);
            }
        }
        const float4 bvv = *(const float4*)&ba2[wid*16 + l4*4];
        const float bva[4] = {bvv.x, bvv.y, bvv.z, bvv.w};
#pragma unroll
        for (int rg = 0; rg < 4; ++rg) {
            const int n = wid*16 + l4*4 + rg;
            float mx = -INFINITY;
#pragma unroll
            for (int j = 0; j < 8; ++j) {
                int tg = t0 + j*16 + l16;
                if (tg < T_) mx = fmaxf(mx, acc2[j][rg] + bva[rg]);
            }
            mx = fmaxf(mx, __shfl_xor(mx, 1));
            mx = fmaxf(mx, __shfl_xor(mx, 2));
            mx = fmaxf(mx, __shfl_xor(mx, 4));
            mx = fmaxf(mx, __shfl_xor(mx, 8));
            float se = 0.0f, am = 0.0f, aq = 0.0f;
#pragma unroll
            for (int j = 0; j < 8; ++j) {
                int tl = j*16 + l16;
                int tg = t0 + tl;
                if (tg < T_) {
                    float p = expf(acc2[j][rg] + bva[rg] - mx);
                    int rl = tl + 8;
                    unsigned byte = ((unsigned)(rl*128 + n))*2u ^ ((unsigned)((tl & 7) << 4));
                    float x = bf2f(*(const ushort_t*)((const char*)ss_ + byte));
                    se += p; am += p*x; aq += p*x*x;
                }
            }
#pragma unroll
            for (int d = 1; d <= 8; d <<= 1) {
                se += __shfl_xor(se, d);
                am += __shfl_xor(am, d);
                aq += __shfl_xor(aq, d);
            }
            if (l16 == 0) {
                size_t o = ((size_t)b*NCH + ch)*128 + n;
                pm[o]  = mx;
                ps[o]  = se;
                pcm[o] = am;
                pcq[o] = aq;
            }
        }
    }
}

// ---------------------------------------------------------------------------
// final: global softmax combine + stats + layernorm(256) + coalesced linear.
__launch_bounds__(256)
__global__ void final_kernel(const float* __restrict__ pcm, const float* __restrict__ pcq,
                             const float* __restrict__ pm, const float* __restrict__ ps,
                             const float* __restrict__ gamma, const float* __restrict__ beta,
                             const float* __restrict__ w2t, const float* __restrict__ b2,
                             float* __restrict__ out) {
    __shared__ float row[256];
    __shared__ float nrm[256];
    __shared__ float red[8];
    const int tid = threadIdx.x, b = blockIdx.x;
    if (tid < 128) {
        float M = -INFINITY;
        for (int ch = 0; ch < NCH; ++ch)
            M = fmaxf(M, pm[((size_t)b*NCH + ch)*128 + tid]);
        float S = 0.0f, sm = 0.0f, sq = 0.0f;
        for (int ch = 0; ch < NCH; ++ch) {
            size_t o = ((size_t)b*NCH + ch)*128 + tid;
            float m = pm[o];
            if (m > -INFINITY) {
                float e = expf(m - M);
                S  += ps[o]*e;
                sm += pcm[o]*e;
                sq += pcq[o]*e;
            }
        }
        float mean = sm / S;
        float q    = sq / S;
        float resid = q - mean*mean;
        float stdv  = sqrtf(fmaxf(resid, 1e-9f));
        row[tid]       = mean;
        row[128 + tid] = stdv;
    }
    __syncthreads();
    float v  = row[tid];
    float s1 = v, s2 = v*v;
    for (int off = 32; off >= 1; off >>= 1) {
        s1 += __shfl_down(s1, off, 64);
        s2 += __shfl_down(s2, off, 64);
    }
    if ((tid & 63) == 0) { red[tid >> 6] = s1; red[4 + (tid >> 6)] = s2; }
    __syncthreads();
    float S1 = red[0] + red[1] + red[2] + red[3];
    float S2 = red[4] + red[5] + red[6] + red[7];
    float mu  = S1 / 256.0f;
    float var = S2 / 256.0f - mu*mu;
    float inv = 1.0f / sqrtf(var + 1e-5f);
    nrm[tid] = (v - mu)*inv*gamma[tid] + beta[tid];
    __syncthreads();
    float acc0 = b2[tid], acc1 = b2[tid + 256];
#pragma unroll 4
    for (int j = 0; j < 256; ++j) {
        float nv = nrm[j];
        const float* wr = w2t + (size_t)j*512;
        acc0 += wr[tid]       * nv;
        acc1 += wr[tid + 256] * nv;
    }
    out[(size_t)b*512 + tid]       = acc0;
    out[(size_t)b*512 + tid + 256] = acc1;
}

// ---------------------------------------------------------------------------
extern "C" void kernel_launch(void* const* d_in, const int* in_sizes, int n_in,
                              void* d_out, int out_size, void* d_ws, size_t ws_size,
                              hipStream_t stream) {
    const float* x      = (const float*)d_in[0];
    const float* bp     = (const float*)d_in[1];
    const float* w_lin1 = (const float*)d_in[2];
    const float* b_lin1 = (const float*)d_in[3];
    const float* wc1    = (const float*)d_in[4];
    const float* bc1    = (const float*)d_in[5];
    const float* wc2    = (const float*)d_in[6];
    const float* bc2    = (const float*)d_in[7];
    const float* wc3    = (const float*)d_in[8];
    const float* bc3    = (const float*)d_in[9];
    const float* wa1    = (const float*)d_in[10];
    const float* ba1    = (const float*)d_in[11];
    const float* wa2    = (const float*)d_in[12];
    const float* ba2    = (const float*)d_in[13];
    const float* gamma  = (const float*)d_in[14];
    const float* beta   = (const float*)d_in[15];
    const float* wl2    = (const float*)d_in[16];
    const float* bl2    = (const float*)d_in[17];

    float* ws   = (float*)d_ws;
    float* bs   = ws + OFF_BS;
    ushort_t* weh  = (ushort_t*)(ws + OFF_WEFF);
    ushort_t* wel  = weh + 64*320;
    float* wtail   = ws + OFF_WTAIL;
    ushort_t* w1h  = (ushort_t*)(ws + OFF_W1);
    ushort_t* w1l  = w1h + 3*128*64;
    ushort_t* w2h  = (ushort_t*)(ws + OFF_W2);
    ushort_t* w2l  = w2h + 3*128*128;
    ushort_t* w3h  = (ushort_t*)(ws + OFF_W3);
    ushort_t* w3l  = w3h + 3*128*128;
    ushort_t* wa1h = (ushort_t*)(ws + OFF_WA1);
    ushort_t* wa1l = wa1h + 64*128;
    ushort_t* wa2h = (ushort_t*)(ws + OFF_WA2);
    ushort_t* wa2l = wa2h + 128*64;
    float* pm   = ws + OFF_PM;
    float* ps   = ws + OFF_PS;
    float* pcm  = ws + OFF_PCM;
    float* pcq  = ws + OFF_PCQ;
    ushort_t* Hs = (ushort_t*)(ws + OFF_HS);
    ushort_t* As = (ushort_t*)(ws + OFF_AS);
    float* wl2t  = ws + OFF_WL2T;

    sort_kernel<<<dim3(1), dim3(64), 0, stream>>>(bp, bs);
    prep_kernel<<<dim3(1136), dim3(256), 0, stream>>>(bs, w_lin1, wc1, wc2, wc3, wa1, wa2,
                                                      wl2, weh, wel, wtail, w1h, w1l,
                                                      w2h, w2l, w3h, w3l, wa1h, wa1l,
                                                      wa2h, wa2l, wl2t);
    // h = relu(x @ Weff^T + b_lin1) -> single bf16 plane
    lin1_mfma<<<dim3(R_/128), dim3(256), 0, stream>>>(x, weh, wel, wtail, b_lin1, Hs);
    // i1 = conv1(h) + b
    dconv1_mfma<<<dim3(47, B_), dim3(256), 0, stream>>>(Hs, w1h, w1l, bc1, As);
    // conv2+conv3+ASP fused, per (128-chunk, b); i3 never leaves LDS
    dconv23_asp<<<dim3(NCH, B_), dim3(512), 0, stream>>>(As, w2h, w2l, w3h, w3l,
                                                         bc2, bc3, wa1h, wa1l,
                                                         wa2h, wa2l, ba1, ba2,
                                                         pm, ps, pcm, pcq);
    // global combine + stats + LN + coalesced 256->512 linear
    final_kernel<<<dim3(B_), dim3(256), 0, stream>>>(pcm, pcq, pm, ps, gamma, beta,
                                                     wl2t, bl2, (float*)d_out);
}

// Round 18
// 289.649 us; speedup vs baseline: 1.7230x; 1.0389x over previous
//
#include <hip/hip_runtime.h>
#include <math.h>

// ---------------------------------------------------------------------------
// ResCNN_ASP_SpeakerEncoder — v17: dconv23_asp VALU diet — fast tanh/exp
// (exp2-based) and 16-row-period LDS swizzle ((r&15)<<4) on 128-col tiles
// (kills the 4-way scalar and 8-bank column-read conflicts). v16 base.
// ---------------------------------------------------------------------------

constexpr int B_  = 64;
constexpr int T_  = 3000;
constexpr int NB_ = 257;   // NBINS
constexpr int R_  = B_ * T_;           // 192000 rows
constexpr int NCH = 24;                // chunks (24 x 128)

// workspace layout (float offsets)
constexpr size_t OFF_BS    = 0;
constexpr size_t OFF_WEFF  = 128;                          // ushort hi[64*320]+lo
constexpr size_t OFF_WTAIL = OFF_WEFF + 20480;
constexpr size_t OFF_W1    = OFF_WTAIL + 128;              // ushort hi+lo 3*128*64
constexpr size_t OFF_W2    = OFF_W1  + 3*64*128;
constexpr size_t OFF_W3    = OFF_W2  + 3*128*128;
constexpr size_t OFF_WA1   = OFF_W3  + 3*128*128;
constexpr size_t OFF_WA2   = OFF_WA1 + 8192;
constexpr size_t SZ_P      = (size_t)B_*NCH*128;
constexpr size_t OFF_PM    = OFF_WA2 + 8192;
constexpr size_t OFF_PS    = OFF_PM  + SZ_P;
constexpr size_t OFF_PCM   = OFF_PS  + SZ_P;
constexpr size_t OFF_PCQ   = OFF_PCM + SZ_P;
// single bf16 planes
constexpr size_t OFF_HS    = OFF_PCQ + SZ_P;               // h  [R*64]u
constexpr size_t OFF_AS    = OFF_HS  + (size_t)R_*32;      // i1 [R*128]u
constexpr size_t OFF_SLACK = OFF_AS  + (size_t)R_*64;      // slack (DMA overrun)
constexpr size_t OFF_WL2T  = OFF_SLACK + 4096;             // fp32 [256][512]

typedef __attribute__((ext_vector_type(8))) short  bf16x8;
typedef __attribute__((ext_vector_type(4))) float  f32x4;
typedef __attribute__((ext_vector_type(4), aligned(4))) float float4a;
typedef unsigned short ushort_t;

typedef __attribute__((address_space(3))) unsigned int        as3_u32;
typedef const __attribute__((address_space(1))) unsigned int  as1_u32c;
__device__ __forceinline__ void gload16(const void* g, void* l) {
    __builtin_amdgcn_global_load_lds((as1_u32c*)g, (as3_u32*)l, 16, 0, 0);
}

__device__ inline ushort_t f2bf(float f) {                // RNE f32->bf16
    unsigned u = __float_as_uint(f);
    unsigned r = u + 0x7FFFu + ((u >> 16) & 1u);
    return (ushort_t)(r >> 16);
}
__device__ inline float bf2f(ushort_t h) {
    return __uint_as_float(((unsigned)h) << 16);
}
__device__ inline void split2(float v, ushort_t &h, ushort_t &l) {
    h = f2bf(v);
    l = f2bf(v - bf2f(h));
}

// fast tanh: (e^{2x}-1)/(e^{2x}+1), clamp +-15 (tanh==+-1 in fp32 beyond)
__device__ inline float fast_tanh(float x) {
    float cx = fminf(fmaxf(x, -15.0f), 15.0f);
    float e  = __expf(2.0f * cx);
    return __fdividef(e - 1.0f, e + 1.0f);
}

// pack 4 f32 -> 4 bf16 (RNE, 2 u32)
__device__ inline void pack_hi4(float x, float y, float z, float w, uint2 &ph) {
    unsigned hx, hy;
    asm("v_cvt_pk_bf16_f32 %0, %1, %2" : "=v"(hx) : "v"(x), "v"(y));
    asm("v_cvt_pk_bf16_f32 %0, %1, %2" : "=v"(hy) : "v"(z), "v"(w));
    ph.x = hx; ph.y = hy;
}

// ---------------------------------------------------------------------------
__global__ void sort_kernel(const float* __restrict__ bp, float* __restrict__ bs) {
    if (threadIdx.x == 0) {
        float tmp[82];
        for (int i = 0; i < 82; ++i) tmp[i] = bp[i];
        for (int i = 1; i < 82; ++i) {
            float key = tmp[i];
            int j = i - 1;
            while (j >= 0 && tmp[j] > key) { tmp[j+1] = tmp[j]; --j; }
            tmp[j+1] = key;
        }
        for (int i = 0; i < 82; ++i) bs[i] = tmp[i];
    }
}

// Fragment-order packing (B: lane&15=col, lane>>4=k-octet; A: lane&15=row),
// plus fp32 wl2 transpose [256 j][512 o].
__global__ void prep_kernel(const float* __restrict__ bs, const float* __restrict__ wl1,
                            const float* __restrict__ wc1, const float* __restrict__ wc2,
                            const float* __restrict__ wc3, const float* __restrict__ wa1,
                            const float* __restrict__ wa2, const float* __restrict__ wl2,
                            ushort_t* __restrict__ weh, ushort_t* __restrict__ wel,
                            float* __restrict__ wtail,
                            ushort_t* __restrict__ w1h, ushort_t* __restrict__ w1l,
                            ushort_t* __restrict__ w2h, ushort_t* __restrict__ w2l,
                            ushort_t* __restrict__ w3h, ushort_t* __restrict__ w3l,
                            ushort_t* __restrict__ wa1h, ushort_t* __restrict__ wa1l,
                            ushort_t* __restrict__ wa2h, ushort_t* __restrict__ wa2l,
                            float* __restrict__ wl2t) {
    int gid = blockIdx.x * 256 + threadIdx.x;
    if (gid < 64*320) {                            // Weff[o][f]
        int o = gid / 320, f = gid % 320;
        if (f > 256) return;
        float acc = 0.0f;
        if (f == 0) acc = wl1[o*80];               // filt[:,:,0] = x[:,:,0]
        else {
            for (int n = 1; n < 79; ++n) {
                float bn = bs[n], bn1 = bs[n+1], bn2 = bs[n+2];
                int ibn  = (int)floorf(bn);
                int ibn1 = (int)floorf(bn1);
                int ibn2 = (int)floorf(bn2);
                float fbv = 0.0f;
                if (f >= ibn && f < ibn1) {
                    float d = (bn1-bn)*(bn1-bn);
                    fbv = ((float)f - bn) / (d > 0.0f ? d : 1.0f);
                } else if (f >= ibn1 && f < ibn2) {
                    float d = (bn2-bn1)*(bn2-bn1);
                    fbv = (bn2 - (float)f) / (d > 0.0f ? d : 1.0f);
                }
                acc += wl1[o*80 + n] * fbv;
            }
        }
        if (f == 256) { wtail[o] = acc; return; }
        int kc = f >> 5, lane = ((f & 31) >> 3)*16 + (o & 15), e = f & 7;
        size_t dst = (((size_t)kc*4 + (o >> 4))*64 + lane)*8 + e;
        split2(acc, weh[dst], wel[dst]);
        return;
    }
    gid -= 64*320;
    if (gid < 3*128*64) {                          // conv1: [k][c][ci=64]
        int k = gid / (128*64), rem = gid % (128*64);
        int c = rem >> 6, ci = rem & 63;
        float v = wc1[(c*64 + ci)*3 + k];
        int lane = ((ci & 31) >> 3)*16 + (c & 15), e = ci & 7;
        size_t dst = ((((size_t)k*2 + (ci >> 5))*8 + (c >> 4))*64 + lane)*8 + e;
        split2(v, w1h[dst], w1l[dst]);
        return;
    }
    gid -= 3*128*64;
    if (gid < 3*128*128) {                         // conv2
        int k = gid / (128*128), rem = gid % (128*128);
        int c = rem >> 7, ci = rem & 127;
        float v = wc2[(c*128 + ci)*3 + k];
        int lane = ((ci & 31) >> 3)*16 + (c & 15), e = ci & 7;
        size_t dst = ((((size_t)k*4 + (ci >> 5))*8 + (c >> 4))*64 + lane)*8 + e;
        split2(v, w2h[dst], w2l[dst]);
        return;
    }
    gid -= 3*128*128;
    if (gid < 3*128*128) {                         // conv3
        int k = gid / (128*128), rem = gid % (128*128);
        int c = rem >> 7, ci = rem & 127;
        float v = wc3[(c*128 + ci)*3 + k];
        int lane = ((ci & 31) >> 3)*16 + (c & 15), e = ci & 7;
        size_t dst = ((((size_t)k*4 + (ci >> 5))*8 + (c >> 4))*64 + lane)*8 + e;
        split2(v, w3h[dst], w3l[dst]);
        return;
    }
    gid -= 3*128*128;
    if (gid < 64*128) {                            // wa1 [c=64][ci=128]
        int c = gid >> 7, ci = gid & 127;
        float v = wa1[gid];
        int lane = ((ci & 31) >> 3)*16 + (c & 15), e = ci & 7;
        size_t dst = (((size_t)(ci >> 5)*4 + (c >> 4))*64 + lane)*8 + e;
        split2(v, wa1h[dst], wa1l[dst]);
        return;
    }
    gid -= 64*128;
    if (gid < 128*64) {                            // wa2 [n=128][ci=64] (A op)
        int n = gid >> 6, ci = gid & 63;
        float v = wa2[gid];
        int lane = ((ci & 31) >> 3)*16 + (n & 15), e = ci & 7;
        size_t dst = (((size_t)(ci >> 5)*8 + (n >> 4))*64 + lane)*8 + e;
        split2(v, wa2h[dst], wa2l[dst]);
        return;
    }
    gid -= 128*64;
    if (gid < 256*512) {                           // wl2T[j][o] <- wl2[o][j]
        int j = gid >> 9, o = gid & 511;
        wl2t[gid] = wl2[(size_t)o*256 + j];
        return;
    }
}

// ---------------------------------------------------------------------------
// lin1: h = relu(x @ Weff^T + b); x staged as single bf16; 2-pass MFMA.
__launch_bounds__(256)
__global__ void lin1_mfma(const float* __restrict__ X,
                          const ushort_t* __restrict__ Wh, const ushort_t* __restrict__ Wl,
                          const float* __restrict__ wtail,
                          const float* __restrict__ bias,
                          ushort_t* __restrict__ Hs) {
    __shared__ __align__(16) ushort_t ash[128*64];
    __shared__ float xs[128];
    __shared__ float wts[64];
    const int tid  = threadIdx.x;
    const int lane = tid & 63;
    const int wid  = tid >> 6;
    const int wy   = wid >> 1, wx = wid & 1;
    const int l16  = lane & 15, l4 = lane >> 4;
    const int r0   = blockIdx.x * 128;

    if (tid < 128)       xs[tid] = X[(size_t)(r0 + tid)*NB_ + 256];
    else if (tid < 192)  wts[tid - 128] = wtail[tid - 128];

#define LIN1_LOAD(dst, k0)                                            \
    _Pragma("unroll")                                                 \
    for (int i = 0; i < 8; ++i) {                                     \
        int q = tid + i*256; int r = q >> 4, cc = (q & 15) << 2;      \
        dst[i] = *(const float4a*)(X + (size_t)(r0 + r)*NB_ + (k0) + cc); \
    }
#define LIN1_CW(src)                                                  \
    _Pragma("unroll")                                                 \
    for (int i = 0; i < 8; ++i) {                                     \
        int q = tid + i*256; int r = q >> 4, cc = (q & 15) << 2;      \
        uint2 ph;                                                     \
        pack_hi4(src[i].x, src[i].y, src[i].z, src[i].w, ph);         \
        unsigned byte = ((unsigned)(r*64 + cc))*2u ^ ((unsigned)((r & 7) << 4)); \
        *(uint2*)((char*)ash + byte) = ph;                            \
    }

    float4a bufA[8], bufB[8];
    LIN1_LOAD(bufA, 0);

    f32x4 acc[4][2];
    const f32x4 z = {0.f,0.f,0.f,0.f};
#pragma unroll
    for (int m = 0; m < 4; ++m) { acc[m][0] = z; acc[m][1] = z; }

#pragma unroll
    for (int ck = 0; ck < 4; ++ck) {
        const float4a* cur = (ck & 1) ? bufB : bufA;
        float4a*       nxt = (ck & 1) ? bufA : bufB;
        if (ck < 3) LIN1_LOAD(nxt, (ck + 1)*64);
        LIN1_CW(cur);
        __syncthreads();
#pragma unroll
        for (int kk = 0; kk < 64; kk += 32) {
            bf16x8 bh[2], bl[2];
#pragma unroll
            for (int n = 0; n < 2; ++n) {
                size_t off = (((size_t)(ck*2 + (kk >> 5))*4 + wx*2 + n)*64 + lane)*8;
                bh[n] = *(const bf16x8*)(Wh + off);
                bl[n] = *(const bf16x8*)(Wl + off);
            }
            bf16x8 fh[4];
#pragma unroll
            for (int m = 0; m < 4; ++m) {
                int r = wy*64 + m*16 + l16;
                unsigned byte = ((unsigned)(r*64 + kk + l4*8))*2u ^ ((unsigned)((r & 7) << 4));
                fh[m] = *(const bf16x8*)((const char*)ash + byte);
            }
#pragma unroll
            for (int m = 0; m < 4; ++m)
#pragma unroll
                for (int n = 0; n < 2; ++n) {
                    acc[m][n] = __builtin_amdgcn_mfma_f32_16x16x32_bf16(fh[m], bh[n], acc[m][n], 0, 0, 0);
                    acc[m][n] = __builtin_amdgcn_mfma_f32_16x16x32_bf16(fh[m], bl[n], acc[m][n], 0, 0, 0);
                }
        }
        __syncthreads();
    }
#undef LIN1_LOAD
#undef LIN1_CW

#pragma unroll
    for (int m = 0; m < 4; ++m)
#pragma unroll
        for (int n = 0; n < 2; ++n) {
            int c = wx*32 + n*16 + l16;
            float bv = bias[c];
            float wc = wts[c];
            int rbl = wy*64 + m*16 + l4*4;
#pragma unroll
            for (int rg = 0; rg < 4; ++rg) {
                int rl = rbl + rg;
                float v = fmaxf(acc[m][n][rg] + bv + xs[rl]*wc, 0.0f);
                Hs[(size_t)(r0 + rl)*64 + c] = f2bf(v);
            }
        }
}

// ---------------------------------------------------------------------------
// conv1 (CIN=64, DIL=2): column-tiled waves.
__launch_bounds__(256, 4)
__global__ void dconv1_mfma(const ushort_t* __restrict__ Xs,
                            const ushort_t* __restrict__ Wh, const ushort_t* __restrict__ Wl,
                            const float* __restrict__ bias,
                            ushort_t* __restrict__ Ys) {
    constexpr int CIN = 64, DIL = 2;
    constexpr int TT  = 64;
    constexpr int HS  = TT + 2*DIL;        // 68
    constexpr int NCK = HS*8;
    constexpr int NCKP = ((NCK + 255)/256)*256;
    __shared__ __align__(16) ushort_t hs_[NCKP*8];

    const int tid  = threadIdx.x;
    const int lane = tid & 63;
    const int wid  = tid >> 6;            // 0..3: cols wid*32 + n*16
    const int l16  = lane & 15;
    const int l4   = lane >> 4;
    const int t0   = blockIdx.x * TT;
    const int b    = blockIdx.y;

    const long long rowbase = ((long long)b*T_ + (t0 - DIL)) * CIN;
    for (int c0 = wid*64; c0 < NCKP; c0 += 256) {
        int ck = c0 + lane;
        int r  = ck >> 3;
        int sc = ck ^ (r & 7);
        gload16(Xs + rowbase + (long long)sc*8, (char*)hs_ + (size_t)c0*16);
    }
    __syncthreads();
    if (t0 < DIL || t0 + TT + DIL > T_) {
        for (int idx = tid; idx < HS*CIN/4; idx += 256) {
            int e = idx << 2;
            int r = e / CIN, ci = e % CIN;
            int t = t0 - DIL + r;
            if (t < 0 || t >= T_) {
                unsigned byte = ((unsigned)(r*CIN + ci))*2u ^ ((unsigned)((r & 7) << 4));
                *(uint2*)((char*)hs_ + byte) = make_uint2(0u, 0u);
            }
        }
        __syncthreads();
    }

    f32x4 acc[4][2];
    const f32x4 z = {0.f, 0.f, 0.f, 0.f};
#pragma unroll
    for (int m = 0; m < 4; ++m)
#pragma unroll
        for (int n = 0; n < 2; ++n) acc[m][n] = z;

#pragma unroll
    for (int k = 0; k < 3; ++k) {
#pragma unroll
        for (int cb = 0; cb < 2; ++cb) {
            bf16x8 bh[2], bl[2];
#pragma unroll
            for (int n = 0; n < 2; ++n) {
                size_t off = ((((size_t)k*2 + cb)*8 + wid*2 + n)*64 + lane)*8;
                bh[n] = *(const bf16x8*)(Wh + off);
                bl[n] = *(const bf16x8*)(Wl + off);
            }
            bf16x8 ah[4];
#pragma unroll
            for (int m = 0; m < 4; ++m) {
                int r = m*16 + l16 + k*DIL;
                unsigned byte = ((unsigned)(r*CIN + cb*32 + l4*8))*2u
                              ^ ((unsigned)((r & 7) << 4));
                ah[m] = *(const bf16x8*)((const char*)hs_ + byte);
            }
#pragma unroll
            for (int m = 0; m < 4; ++m)
#pragma unroll
                for (int n = 0; n < 2; ++n) {
                    acc[m][n] = __builtin_amdgcn_mfma_f32_16x16x32_bf16(ah[m], bh[n], acc[m][n], 0, 0, 0);
                    acc[m][n] = __builtin_amdgcn_mfma_f32_16x16x32_bf16(ah[m], bl[n], acc[m][n], 0, 0, 0);
                }
        }
    }

#pragma unroll
    for (int m = 0; m < 4; ++m) {
        int tl_base = m*16 + l4*4;
#pragma unroll
        for (int n = 0; n < 2; ++n) {
            int c = wid*32 + n*16 + l16;
            float bv = bias[c];
#pragma unroll
            for (int rg = 0; rg < 4; ++rg) {
                int tl = tl_base + rg;
                int t  = t0 + tl;
                if (t < T_) {
                    float v = acc[m][n][rg] + bv;
                    Ys[((size_t)b*T_ + t)*128 + c] = f2bf(v);
                }
            }
        }
    }
}

// ---------------------------------------------------------------------------
// Fused conv2+conv3+ASP, TT=128 per (chunk, b). 16-row-period swizzle on the
// 128-col tiles; fast tanh/exp; i3 in-place over s; ASP from LDS.
__launch_bounds__(512)
__global__ void dconv23_asp(const ushort_t* __restrict__ Xs,
                            const ushort_t* __restrict__ W2h, const ushort_t* __restrict__ W2l,
                            const ushort_t* __restrict__ W3h, const ushort_t* __restrict__ W3l,
                            const float* __restrict__ bc2, const float* __restrict__ bc3,
                            const ushort_t* __restrict__ Wa1h, const ushort_t* __restrict__ Wa1l,
                            const ushort_t* __restrict__ Wa2h, const ushort_t* __restrict__ Wa2l,
                            const float* __restrict__ ba1, const float* __restrict__ ba2,
                            float* __restrict__ pm, float* __restrict__ ps,
                            float* __restrict__ pcm, float* __restrict__ pcq) {
    __shared__ __align__(16) char smem[73728];
    ushort_t* i1s = (ushort_t*)smem;               // [144][128] rows t0-8..t0+135
    ushort_t* ss_ = (ushort_t*)(smem + 36864);     // s, then i3 (in-place)
    ushort_t* vs_ = (ushort_t*)smem;               // v [128][64] (i1 dead)

    const int tid  = threadIdx.x;
    const int lane = tid & 63;
    const int wid  = tid >> 6;            // 0..7
    const int l16  = lane & 15, l4 = lane >> 4;
    const int ch   = blockIdx.x;
    const int b    = blockIdx.y;
    const int t0   = ch * 128;

    // ---- stage i1 rows [t0-8, t0+136), 16-row-period pre-swizzle ----
    const long long rowbase = ((long long)b*T_ + (t0 - 8)) * 128;
    for (int c0 = wid*64; c0 < 2304; c0 += 512) {
        int ck = c0 + lane;
        int r  = ck >> 4;
        int sc = ck ^ (r & 15);
        gload16(Xs + rowbase + (long long)sc*8, (char*)i1s + (size_t)c0*16);
    }
    __syncthreads();
    if (t0 < 8 || t0 + 136 > T_) {
        for (int idx = tid; idx < 144*128/4; idx += 512) {
            int e = idx << 2;
            int r = e >> 7, ci = e & 127;
            int t = t0 - 8 + r;
            if (t < 0 || t >= T_) {
                unsigned byte = ((unsigned)(r*128 + ci))*2u ^ ((unsigned)((r & 15) << 4));
                *(uint2*)((char*)i1s + byte) = make_uint2(0u, 0u);
            }
        }
        __syncthreads();
    }

    // ---- phase 1: conv2 over all 144 local rows -> s = conv2 + bc2 + 2*i1 ----
    {
        f32x4 acc[9];
        const f32x4 z = {0.f,0.f,0.f,0.f};
#pragma unroll
        for (int m = 0; m < 9; ++m) acc[m] = z;
#pragma unroll
        for (int k = 0; k < 3; ++k) {
#pragma unroll
            for (int cb = 0; cb < 4; ++cb) {
                size_t off = ((((size_t)k*4 + cb)*8 + wid)*64 + lane)*8;
                bf16x8 bh = *(const bf16x8*)(W2h + off);
                bf16x8 bl = *(const bf16x8*)(W2l + off);
#pragma unroll
                for (int m = 0; m < 9; ++m) {
                    int r = m*16 + l16 + k*3 - 3;
                    r = min(max(r, 0), 143);  // garbage edge rows; never consumed
                    unsigned byte = ((unsigned)(r*128 + cb*32 + l4*8))*2u
                                  ^ ((unsigned)((r & 15) << 4));
                    bf16x8 ah = *(const bf16x8*)((const char*)i1s + byte);
                    acc[m] = __builtin_amdgcn_mfma_f32_16x16x32_bf16(ah, bh, acc[m], 0, 0, 0);
                    acc[m] = __builtin_amdgcn_mfma_f32_16x16x32_bf16(ah, bl, acc[m], 0, 0, 0);
                }
            }
        }
        const int c = wid*16 + l16;
        const float bv = bc2[c];
#pragma unroll
        for (int m = 0; m < 9; ++m) {
#pragma unroll
            for (int rg = 0; rg < 4; ++rg) {
                int rl = m*16 + l4*4 + rg;
                int t  = t0 - 8 + rl;
                float v = 0.0f;
                unsigned byte = ((unsigned)(rl*128 + c))*2u ^ ((unsigned)((rl & 15) << 4));
                if (t >= 0 && t < T_) {
                    float cen = bf2f(*(const ushort_t*)((const char*)i1s + byte));
                    v = acc[m][rg] + bv + 2.0f*cen;
                }
                *(ushort_t*)((char*)ss_ + byte) = f2bf(v);
            }
        }
    }
    __syncthreads();

    // ---- phase 2: conv3 + residual into REGISTERS (reads s) ----
    float i3r[8][4];
    {
        f32x4 acc[8];
        const f32x4 z = {0.f,0.f,0.f,0.f};
#pragma unroll
        for (int m = 0; m < 8; ++m) acc[m] = z;
#pragma unroll
        for (int k = 0; k < 3; ++k) {
#pragma unroll
            for (int cb = 0; cb < 4; ++cb) {
                size_t off = ((((size_t)k*4 + cb)*8 + wid)*64 + lane)*8;
                bf16x8 bh = *(const bf16x8*)(W3h + off);
                bf16x8 bl = *(const bf16x8*)(W3l + off);
#pragma unroll
                for (int m = 0; m < 8; ++m) {
                    int r = 8 + m*16 + l16 + k*4 - 4;  // in [4,139]
                    unsigned byte = ((unsigned)(r*128 + cb*32 + l4*8))*2u
                                  ^ ((unsigned)((r & 15) << 4));
                    bf16x8 ah = *(const bf16x8*)((const char*)ss_ + byte);
                    acc[m] = __builtin_amdgcn_mfma_f32_16x16x32_bf16(ah, bh, acc[m], 0, 0, 0);
                    acc[m] = __builtin_amdgcn_mfma_f32_16x16x32_bf16(ah, bl, acc[m], 0, 0, 0);
                }
            }
        }
        const int c = wid*16 + l16;
        const float bv = bc3[c];
#pragma unroll
        for (int m = 0; m < 8; ++m)
#pragma unroll
            for (int rg = 0; rg < 4; ++rg) {
                int rl = 8 + m*16 + l4*4 + rg;         // in [8,136)
                unsigned byte = ((unsigned)(rl*128 + c))*2u ^ ((unsigned)((rl & 15) << 4));
                float cen = bf2f(*(const ushort_t*)((const char*)ss_ + byte));
                i3r[m][rg] = acc[m][rg] + bv + cen;
            }
    }
    __syncthreads();                       // all s reads complete
    // write i3 over s (rows [8,136) = t [t0, t0+128))
    {
        const int c = wid*16 + l16;
#pragma unroll
        for (int m = 0; m < 8; ++m)
#pragma unroll
            for (int rg = 0; rg < 4; ++rg) {
                int rl = 8 + m*16 + l4*4 + rg;
                unsigned byte = ((unsigned)(rl*128 + c))*2u ^ ((unsigned)((rl & 15) << 4));
                *(ushort_t*)((char*)ss_ + byte) = f2bf(i3r[m][rg]);
            }
    }
    __syncthreads();                       // i3 tile ready (and i1 dead)

    // ---- ASP stage 1: v = tanh(i3 @ wa1^T + ba1)  (wave: rowhalf x coltile) ----
    {
        const int wy = wid >> 2;          // 0..1: rows wy*64 + m*16
        const int wx = wid & 3;           // 0..3: cols wx*16
        f32x4 acc1[4];
        const f32x4 z = {0.f,0.f,0.f,0.f};
#pragma unroll
        for (int m = 0; m < 4; ++m) acc1[m] = z;
#pragma unroll
        for (int kc = 0; kc < 4; ++kc) {
            size_t off = (((size_t)kc*4 + wx)*64 + lane)*8;
            bf16x8 bh = *(const bf16x8*)(Wa1h + off);
            bf16x8 bl = *(const bf16x8*)(Wa1l + off);
#pragma unroll
            for (int m = 0; m < 4; ++m) {
                int rl = 8 + wy*64 + m*16 + l16;       // i3 row
                unsigned byte = ((unsigned)(rl*128 + kc*32 + l4*8))*2u
                              ^ ((unsigned)((rl & 15) << 4));
                bf16x8 ah = *(const bf16x8*)((const char*)ss_ + byte);
                acc1[m] = __builtin_amdgcn_mfma_f32_16x16x32_bf16(ah, bh, acc1[m], 0, 0, 0);
                acc1[m] = __builtin_amdgcn_mfma_f32_16x16x32_bf16(ah, bl, acc1[m], 0, 0, 0);
            }
        }
        const int c = wx*16 + l16;
        const float bv = ba1[c];
#pragma unroll
        for (int m = 0; m < 4; ++m)
#pragma unroll
            for (int rg = 0; rg < 4; ++rg) {
                float v = fast_tanh(acc1[m][rg] + bv);
                int r = wy*64 + m*16 + l4*4 + rg;      // t row in [0,128)
                unsigned byte = ((unsigned)(r*64 + c))*2u ^ ((unsigned)((r & 7) << 4));
                *(ushort_t*)((char*)vs_ + byte) = f2bf(v);
            }
    }
    __syncthreads();

    // ---- ASP stage 2 + softmax partials + weighted stats ----
    {
        f32x4 acc2[8];
        const f32x4 z = {0.f,0.f,0.f,0.f};
#pragma unroll
        for (int j = 0; j < 8; ++j) acc2[j] = z;
#pragma unroll
        for (int kc = 0; kc < 2; ++kc) {
            size_t off = (((size_t)kc*8 + wid)*64 + lane)*8;
            bf16x8 awh = *(const bf16x8*)(Wa2h + off);
            bf16x8 awl = *(const bf16x8*)(Wa2l + off);
#pragma unroll
            for (int j = 0; j < 8; ++j) {
                int t = j*16 + l16;
                unsigned byte = ((unsigned)(t*64 + kc*32 + l4*8))*2u
                              ^ ((unsigned)((t & 7) << 4));
                bf16x8 bv_ = *(const bf16x8*)((const char*)vs_ + byte);
                acc2[j] = __builtin_amdgcn_mfma_f32_16x16x32_bf16(awh, bv_, acc2[j], 0, 0, 0);
                acc2[j] = __builtin_amdgcn_mfma_f32_16x16x32_bf16(awl, bv_, acc2[j], 0, 0, 0);
            }
        }
        const float4 bvv = *(const float4*)&ba2[wid*16 + l4*4];
        const float bva[4] = {bvv.x, bvv.y, bvv.z, bvv.w};
#pragma unroll
        for (int rg = 0; rg < 4; ++rg) {
            const int n = wid*16 + l4*4 + rg;
            float mx = -INFINITY;
#pragma unroll
            for (int j = 0; j < 8; ++j) {
                int tg = t0 + j*16 + l16;
                if (tg < T_) mx = fmaxf(mx, acc2[j][rg] + bva[rg]);
            }
            mx = fmaxf(mx, __shfl_xor(mx, 1));
            mx = fmaxf(mx, __shfl_xor(mx, 2));
            mx = fmaxf(mx, __shfl_xor(mx, 4));
            mx = fmaxf(mx, __shfl_xor(mx, 8));
            float se = 0.0f, am = 0.0f, aq = 0.0f;
#pragma unroll
            for (int j = 0; j < 8; ++j) {
                int tl = j*16 + l16;
                int tg = t0 + tl;
                if (tg < T_) {
                    float p = __expf(acc2[j][rg] + bva[rg] - mx);
                    int rl = tl + 8;
                    unsigned byte = ((unsigned)(rl*128 + n))*2u ^ ((unsigned)((rl & 15) << 4));
                    float x = bf2f(*(const ushort_t*)((const char*)ss_ + byte));
                    se += p; am += p*x; aq += p*x*x;
                }
            }
#pragma unroll
            for (int d = 1; d <= 8; d <<= 1) {
                se += __shfl_xor(se, d);
                am += __shfl_xor(am, d);
                aq += __shfl_xor(aq, d);
            }
            if (l16 == 0) {
                size_t o = ((size_t)b*NCH + ch)*128 + n;
                pm[o]  = mx;
                ps[o]  = se;
                pcm[o] = am;
                pcq[o] = aq;
            }
        }
    }
}

// ---------------------------------------------------------------------------
// final: global softmax combine + stats + layernorm(256) + coalesced linear.
__launch_bounds__(256)
__global__ void final_kernel(const float* __restrict__ pcm, const float* __restrict__ pcq,
                             const float* __restrict__ pm, const float* __restrict__ ps,
                             const float* __restrict__ gamma, const float* __restrict__ beta,
                             const float* __restrict__ w2t, const float* __restrict__ b2,
                             float* __restrict__ out) {
    __shared__ float row[256];
    __shared__ float nrm[256];
    __shared__ float red[8];
    const int tid = threadIdx.x, b = blockIdx.x;
    if (tid < 128) {
        float M = -INFINITY;
        for (int ch = 0; ch < NCH; ++ch)
            M = fmaxf(M, pm[((size_t)b*NCH + ch)*128 + tid]);
        float S = 0.0f, sm = 0.0f, sq = 0.0f;
        for (int ch = 0; ch < NCH; ++ch) {
            size_t o = ((size_t)b*NCH + ch)*128 + tid;
            float m = pm[o];
            if (m > -INFINITY) {
                float e = expf(m - M);
                S  += ps[o]*e;
                sm += pcm[o]*e;
                sq += pcq[o]*e;
            }
        }
        float mean = sm / S;
        float q    = sq / S;
        float resid = q - mean*mean;
        float stdv  = sqrtf(fmaxf(resid, 1e-9f));
        row[tid]       = mean;
        row[128 + tid] = stdv;
    }
    __syncthreads();
    float v  = row[tid];
    float s1 = v, s2 = v*v;
    for (int off = 32; off >= 1; off >>= 1) {
        s1 += __shfl_down(s1, off, 64);
        s2 += __shfl_down(s2, off, 64);
    }
    if ((tid & 63) == 0) { red[tid >> 6] = s1; red[4 + (tid >> 6)] = s2; }
    __syncthreads();
    float S1 = red[0] + red[1] + red[2] + red[3];
    float S2 = red[4] + red[5] + red[6] + red[7];
    float mu  = S1 / 256.0f;
    float var = S2 / 256.0f - mu*mu;
    float inv = 1.0f / sqrtf(var + 1e-5f);
    nrm[tid] = (v - mu)*inv*gamma[tid] + beta[tid];
    __syncthreads();
    float acc0 = b2[tid], acc1 = b2[tid + 256];
#pragma unroll 4
    for (int j = 0; j < 256; ++j) {
        float nv = nrm[j];
        const float* wr = w2t + (size_t)j*512;
        acc0 += wr[tid]       * nv;
        acc1 += wr[tid + 256] * nv;
    }
    out[(size_t)b*512 + tid]       = acc0;
    out[(size_t)b*512 + tid + 256] = acc1;
}

// ---------------------------------------------------------------------------
extern "C" void kernel_launch(void* const* d_in, const int* in_sizes, int n_in,
                              void* d_out, int out_size, void* d_ws, size_t ws_size,
                              hipStream_t stream) {
    const float* x      = (const float*)d_in[0];
    const float* bp     = (const float*)d_in[1];
    const float* w_lin1 = (const float*)d_in[2];
    const float* b_lin1 = (const float*)d_in[3];
    const float* wc1    = (const float*)d_in[4];
    const float* bc1    = (const float*)d_in[5];
    const float* wc2    = (const float*)d_in[6];
    const float* bc2    = (const float*)d_in[7];
    const float* wc3    = (const float*)d_in[8];
    const float* bc3    = (const float*)d_in[9];
    const float* wa1    = (const float*)d_in[10];
    const float* ba1    = (const float*)d_in[11];
    const float* wa2    = (const float*)d_in[12];
    const float* ba2    = (const float*)d_in[13];
    const float* gamma  = (const float*)d_in[14];
    const float* beta   = (const float*)d_in[15];
    const float* wl2    = (const float*)d_in[16];
    const float* bl2    = (const float*)d_in[17];

    float* ws   = (float*)d_ws;
    float* bs   = ws + OFF_BS;
    ushort_t* weh  = (ushort_t*)(ws + OFF_WEFF);
    ushort_t* wel  = weh + 64*320;
    float* wtail   = ws + OFF_WTAIL;
    ushort_t* w1h  = (ushort_t*)(ws + OFF_W1);
    ushort_t* w1l  = w1h + 3*128*64;
    ushort_t* w2h  = (ushort_t*)(ws + OFF_W2);
    ushort_t* w2l  = w2h + 3*128*128;
    ushort_t* w3h  = (ushort_t*)(ws + OFF_W3);
    ushort_t* w3l  = w3h + 3*128*128;
    ushort_t* wa1h = (ushort_t*)(ws + OFF_WA1);
    ushort_t* wa1l = wa1h + 64*128;
    ushort_t* wa2h = (ushort_t*)(ws + OFF_WA2);
    ushort_t* wa2l = wa2h + 128*64;
    float* pm   = ws + OFF_PM;
    float* ps   = ws + OFF_PS;
    float* pcm  = ws + OFF_PCM;
    float* pcq  = ws + OFF_PCQ;
    ushort_t* Hs = (ushort_t*)(ws + OFF_HS);
    ushort_t* As = (ushort_t*)(ws + OFF_AS);
    float* wl2t  = ws + OFF_WL2T;

    sort_kernel<<<dim3(1), dim3(64), 0, stream>>>(bp, bs);
    prep_kernel<<<dim3(1136), dim3(256), 0, stream>>>(bs, w_lin1, wc1, wc2, wc3, wa1, wa2,
                                                      wl2, weh, wel, wtail, w1h, w1l,
                                                      w2h, w2l, w3h, w3l, wa1h, wa1l,
                                                      wa2h, wa2l, wl2t);
    // h = relu(x @ Weff^T + b_lin1) -> single bf16 plane
    lin1_mfma<<<dim3(R_/128), dim3(256), 0, stream>>>(x, weh, wel, wtail, b_lin1, Hs);
    // i1 = conv1(h) + b
    dconv1_mfma<<<dim3(47, B_), dim3(256), 0, stream>>>(Hs, w1h, w1l, bc1, As);
    // conv2+conv3+ASP fused, per (128-chunk, b); i3 never leaves LDS
    dconv23_asp<<<dim3(NCH, B_), dim3(512), 0, stream>>>(As, w2h, w2l, w3h, w3l,
                                                         bc2, bc3, wa1h, wa1l,
                                                         wa2h, wa2l, ba1, ba2,
                                                         pm, ps, pcm, pcq);
    // global combine + stats + LN + coalesced 256->512 linear
    final_kernel<<<dim3(B_), dim3(256), 0, stream>>>(pcm, pcq, pm, ps, gamma, beta,
                                                     wl2t, bl2, (float*)d_out);
}

// Round 19
// 262.434 us; speedup vs baseline: 1.9017x; 1.1037x over previous
//
#include <hip/hip_runtime.h>
#include <math.h>

// ---------------------------------------------------------------------------
// ResCNN_ASP_SpeakerEncoder — v18: conv1 fused into dconv23_asp (i1 never
// leaves LDS; h staged instead, half the bytes). LDS total unchanged at
// 73.7KB via aliasing (hs < ss_ region, both dead/live disjoint). v17 base.
// ---------------------------------------------------------------------------

constexpr int B_  = 64;
constexpr int T_  = 3000;
constexpr int NB_ = 257;   // NBINS
constexpr int R_  = B_ * T_;           // 192000 rows
constexpr int NCH = 24;                // chunks (24 x 128)

// workspace layout (float offsets)
constexpr size_t OFF_BS    = 0;
constexpr size_t OFF_WEFF  = 128;                          // ushort hi[64*320]+lo
constexpr size_t OFF_WTAIL = OFF_WEFF + 20480;
constexpr size_t OFF_W1    = OFF_WTAIL + 128;              // ushort hi+lo 3*128*64
constexpr size_t OFF_W2    = OFF_W1  + 3*64*128;
constexpr size_t OFF_W3    = OFF_W2  + 3*128*128;
constexpr size_t OFF_WA1   = OFF_W3  + 3*128*128;
constexpr size_t OFF_WA2   = OFF_WA1 + 8192;
constexpr size_t SZ_P      = (size_t)B_*NCH*128;
constexpr size_t OFF_PM    = OFF_WA2 + 8192;
constexpr size_t OFF_PS    = OFF_PM  + SZ_P;
constexpr size_t OFF_PCM   = OFF_PS  + SZ_P;
constexpr size_t OFF_PCQ   = OFF_PCM + SZ_P;
// single bf16 planes
constexpr size_t OFF_HS    = OFF_PCQ + SZ_P;               // h  [R*64]u
constexpr size_t OFF_AS    = OFF_HS  + (size_t)R_*32;      // slack (DMA overrun)
constexpr size_t OFF_WL2T  = OFF_AS  + (size_t)R_*64 + 4096; // fp32 [256][512]

typedef __attribute__((ext_vector_type(8))) short  bf16x8;
typedef __attribute__((ext_vector_type(4))) float  f32x4;
typedef __attribute__((ext_vector_type(4), aligned(4))) float float4a;
typedef unsigned short ushort_t;

typedef __attribute__((address_space(3))) unsigned int        as3_u32;
typedef const __attribute__((address_space(1))) unsigned int  as1_u32c;
__device__ __forceinline__ void gload16(const void* g, void* l) {
    __builtin_amdgcn_global_load_lds((as1_u32c*)g, (as3_u32*)l, 16, 0, 0);
}

__device__ inline ushort_t f2bf(float f) {                // RNE f32->bf16
    unsigned u = __float_as_uint(f);
    unsigned r = u + 0x7FFFu + ((u >> 16) & 1u);
    return (ushort_t)(r >> 16);
}
__device__ inline float bf2f(ushort_t h) {
    return __uint_as_float(((unsigned)h) << 16);
}
__device__ inline void split2(float v, ushort_t &h, ushort_t &l) {
    h = f2bf(v);
    l = f2bf(v - bf2f(h));
}

// fast tanh: (e^{2x}-1)/(e^{2x}+1), clamp +-15
__device__ inline float fast_tanh(float x) {
    float cx = fminf(fmaxf(x, -15.0f), 15.0f);
    float e  = __expf(2.0f * cx);
    return __fdividef(e - 1.0f, e + 1.0f);
}

// pack 4 f32 -> 4 bf16 (RNE, 2 u32)
__device__ inline void pack_hi4(float x, float y, float z, float w, uint2 &ph) {
    unsigned hx, hy;
    asm("v_cvt_pk_bf16_f32 %0, %1, %2" : "=v"(hx) : "v"(x), "v"(y));
    asm("v_cvt_pk_bf16_f32 %0, %1, %2" : "=v"(hy) : "v"(z), "v"(w));
    ph.x = hx; ph.y = hy;
}

// ---------------------------------------------------------------------------
__global__ void sort_kernel(const float* __restrict__ bp, float* __restrict__ bs) {
    if (threadIdx.x == 0) {
        float tmp[82];
        for (int i = 0; i < 82; ++i) tmp[i] = bp[i];
        for (int i = 1; i < 82; ++i) {
            float key = tmp[i];
            int j = i - 1;
            while (j >= 0 && tmp[j] > key) { tmp[j+1] = tmp[j]; --j; }
            tmp[j+1] = key;
        }
        for (int i = 0; i < 82; ++i) bs[i] = tmp[i];
    }
}

// Fragment-order packing (B: lane&15=col, lane>>4=k-octet; A: lane&15=row),
// plus fp32 wl2 transpose [256 j][512 o].
__global__ void prep_kernel(const float* __restrict__ bs, const float* __restrict__ wl1,
                            const float* __restrict__ wc1, const float* __restrict__ wc2,
                            const float* __restrict__ wc3, const float* __restrict__ wa1,
                            const float* __restrict__ wa2, const float* __restrict__ wl2,
                            ushort_t* __restrict__ weh, ushort_t* __restrict__ wel,
                            float* __restrict__ wtail,
                            ushort_t* __restrict__ w1h, ushort_t* __restrict__ w1l,
                            ushort_t* __restrict__ w2h, ushort_t* __restrict__ w2l,
                            ushort_t* __restrict__ w3h, ushort_t* __restrict__ w3l,
                            ushort_t* __restrict__ wa1h, ushort_t* __restrict__ wa1l,
                            ushort_t* __restrict__ wa2h, ushort_t* __restrict__ wa2l,
                            float* __restrict__ wl2t) {
    int gid = blockIdx.x * 256 + threadIdx.x;
    if (gid < 64*320) {                            // Weff[o][f]
        int o = gid / 320, f = gid % 320;
        if (f > 256) return;
        float acc = 0.0f;
        if (f == 0) acc = wl1[o*80];               // filt[:,:,0] = x[:,:,0]
        else {
            for (int n = 1; n < 79; ++n) {
                float bn = bs[n], bn1 = bs[n+1], bn2 = bs[n+2];
                int ibn  = (int)floorf(bn);
                int ibn1 = (int)floorf(bn1);
                int ibn2 = (int)floorf(bn2);
                float fbv = 0.0f;
                if (f >= ibn && f < ibn1) {
                    float d = (bn1-bn)*(bn1-bn);
                    fbv = ((float)f - bn) / (d > 0.0f ? d : 1.0f);
                } else if (f >= ibn1 && f < ibn2) {
                    float d = (bn2-bn1)*(bn2-bn1);
                    fbv = (bn2 - (float)f) / (d > 0.0f ? d : 1.0f);
                }
                acc += wl1[o*80 + n] * fbv;
            }
        }
        if (f == 256) { wtail[o] = acc; return; }
        int kc = f >> 5, lane = ((f & 31) >> 3)*16 + (o & 15), e = f & 7;
        size_t dst = (((size_t)kc*4 + (o >> 4))*64 + lane)*8 + e;
        split2(acc, weh[dst], wel[dst]);
        return;
    }
    gid -= 64*320;
    if (gid < 3*128*64) {                          // conv1: [k][c][ci=64]
        int k = gid / (128*64), rem = gid % (128*64);
        int c = rem >> 6, ci = rem & 63;
        float v = wc1[(c*64 + ci)*3 + k];
        int lane = ((ci & 31) >> 3)*16 + (c & 15), e = ci & 7;
        size_t dst = ((((size_t)k*2 + (ci >> 5))*8 + (c >> 4))*64 + lane)*8 + e;
        split2(v, w1h[dst], w1l[dst]);
        return;
    }
    gid -= 3*128*64;
    if (gid < 3*128*128) {                         // conv2
        int k = gid / (128*128), rem = gid % (128*128);
        int c = rem >> 7, ci = rem & 127;
        float v = wc2[(c*128 + ci)*3 + k];
        int lane = ((ci & 31) >> 3)*16 + (c & 15), e = ci & 7;
        size_t dst = ((((size_t)k*4 + (ci >> 5))*8 + (c >> 4))*64 + lane)*8 + e;
        split2(v, w2h[dst], w2l[dst]);
        return;
    }
    gid -= 3*128*128;
    if (gid < 3*128*128) {                         // conv3
        int k = gid / (128*128), rem = gid % (128*128);
        int c = rem >> 7, ci = rem & 127;
        float v = wc3[(c*128 + ci)*3 + k];
        int lane = ((ci & 31) >> 3)*16 + (c & 15), e = ci & 7;
        size_t dst = ((((size_t)k*4 + (ci >> 5))*8 + (c >> 4))*64 + lane)*8 + e;
        split2(v, w3h[dst], w3l[dst]);
        return;
    }
    gid -= 3*128*128;
    if (gid < 64*128) {                            // wa1 [c=64][ci=128]
        int c = gid >> 7, ci = gid & 127;
        float v = wa1[gid];
        int lane = ((ci & 31) >> 3)*16 + (c & 15), e = ci & 7;
        size_t dst = (((size_t)(ci >> 5)*4 + (c >> 4))*64 + lane)*8 + e;
        split2(v, wa1h[dst], wa1l[dst]);
        return;
    }
    gid -= 64*128;
    if (gid < 128*64) {                            // wa2 [n=128][ci=64] (A op)
        int n = gid >> 6, ci = gid & 63;
        float v = wa2[gid];
        int lane = ((ci & 31) >> 3)*16 + (n & 15), e = ci & 7;
        size_t dst = (((size_t)(ci >> 5)*8 + (n >> 4))*64 + lane)*8 + e;
        split2(v, wa2h[dst], wa2l[dst]);
        return;
    }
    gid -= 128*64;
    if (gid < 256*512) {                           // wl2T[j][o] <- wl2[o][j]
        int j = gid >> 9, o = gid & 511;
        wl2t[gid] = wl2[(size_t)o*256 + j];
        return;
    }
}

// ---------------------------------------------------------------------------
// lin1: h = relu(x @ Weff^T + b); x staged as single bf16; 2-pass MFMA.
__launch_bounds__(256)
__global__ void lin1_mfma(const float* __restrict__ X,
                          const ushort_t* __restrict__ Wh, const ushort_t* __restrict__ Wl,
                          const float* __restrict__ wtail,
                          const float* __restrict__ bias,
                          ushort_t* __restrict__ Hs) {
    __shared__ __align__(16) ushort_t ash[128*64];
    __shared__ float xs[128];
    __shared__ float wts[64];
    const int tid  = threadIdx.x;
    const int lane = tid & 63;
    const int wid  = tid >> 6;
    const int wy   = wid >> 1, wx = wid & 1;
    const int l16  = lane & 15, l4 = lane >> 4;
    const int r0   = blockIdx.x * 128;

    if (tid < 128)       xs[tid] = X[(size_t)(r0 + tid)*NB_ + 256];
    else if (tid < 192)  wts[tid - 128] = wtail[tid - 128];

#define LIN1_LOAD(dst, k0)                                            \
    _Pragma("unroll")                                                 \
    for (int i = 0; i < 8; ++i) {                                     \
        int q = tid + i*256; int r = q >> 4, cc = (q & 15) << 2;      \
        dst[i] = *(const float4a*)(X + (size_t)(r0 + r)*NB_ + (k0) + cc); \
    }
#define LIN1_CW(src)                                                  \
    _Pragma("unroll")                                                 \
    for (int i = 0; i < 8; ++i) {                                     \
        int q = tid + i*256; int r = q >> 4, cc = (q & 15) << 2;      \
        uint2 ph;                                                     \
        pack_hi4(src[i].x, src[i].y, src[i].z, src[i].w, ph);         \
        unsigned byte = ((unsigned)(r*64 + cc))*2u ^ ((unsigned)((r & 7) << 4)); \
        *(uint2*)((char*)ash + byte) = ph;                            \
    }

    float4a bufA[8], bufB[8];
    LIN1_LOAD(bufA, 0);

    f32x4 acc[4][2];
    const f32x4 z = {0.f,0.f,0.f,0.f};
#pragma unroll
    for (int m = 0; m < 4; ++m) { acc[m][0] = z; acc[m][1] = z; }

#pragma unroll
    for (int ck = 0; ck < 4; ++ck) {
        const float4a* cur = (ck & 1) ? bufB : bufA;
        float4a*       nxt = (ck & 1) ? bufA : bufB;
        if (ck < 3) LIN1_LOAD(nxt, (ck + 1)*64);
        LIN1_CW(cur);
        __syncthreads();
#pragma unroll
        for (int kk = 0; kk < 64; kk += 32) {
            bf16x8 bh[2], bl[2];
#pragma unroll
            for (int n = 0; n < 2; ++n) {
                size_t off = (((size_t)(ck*2 + (kk >> 5))*4 + wx*2 + n)*64 + lane)*8;
                bh[n] = *(const bf16x8*)(Wh + off);
                bl[n] = *(const bf16x8*)(Wl + off);
            }
            bf16x8 fh[4];
#pragma unroll
            for (int m = 0; m < 4; ++m) {
                int r = wy*64 + m*16 + l16;
                unsigned byte = ((unsigned)(r*64 + kk + l4*8))*2u ^ ((unsigned)((r & 7) << 4));
                fh[m] = *(const bf16x8*)((const char*)ash + byte);
            }
#pragma unroll
            for (int m = 0; m < 4; ++m)
#pragma unroll
                for (int n = 0; n < 2; ++n) {
                    acc[m][n] = __builtin_amdgcn_mfma_f32_16x16x32_bf16(fh[m], bh[n], acc[m][n], 0, 0, 0);
                    acc[m][n] = __builtin_amdgcn_mfma_f32_16x16x32_bf16(fh[m], bl[n], acc[m][n], 0, 0, 0);
                }
        }
        __syncthreads();
    }
#undef LIN1_LOAD
#undef LIN1_CW

#pragma unroll
    for (int m = 0; m < 4; ++m)
#pragma unroll
        for (int n = 0; n < 2; ++n) {
            int c = wx*32 + n*16 + l16;
            float bv = bias[c];
            float wc = wts[c];
            int rbl = wy*64 + m*16 + l4*4;
#pragma unroll
            for (int rg = 0; rg < 4; ++rg) {
                int rl = rbl + rg;
                float v = fmaxf(acc[m][n][rg] + bv + xs[rl]*wc, 0.0f);
                Hs[(size_t)(r0 + rl)*64 + c] = f2bf(v);
            }
        }
}

// ---------------------------------------------------------------------------
// Fused conv1+conv2+conv3+ASP, TT=128 per (chunk, b).
// hs [148][64] (rows t0-10..t0+137) aliased under ss_; i1s [144][128];
// ss_ [144][128] holds s then i3 in-place; vs_ aliases dead i1s.
__launch_bounds__(512)
__global__ void dconv123_asp(const ushort_t* __restrict__ Hs,
                             const ushort_t* __restrict__ W1h, const ushort_t* __restrict__ W1l,
                             const ushort_t* __restrict__ W2h, const ushort_t* __restrict__ W2l,
                             const ushort_t* __restrict__ W3h, const ushort_t* __restrict__ W3l,
                             const float* __restrict__ bc1, const float* __restrict__ bc2,
                             const float* __restrict__ bc3,
                             const ushort_t* __restrict__ Wa1h, const ushort_t* __restrict__ Wa1l,
                             const ushort_t* __restrict__ Wa2h, const ushort_t* __restrict__ Wa2l,
                             const float* __restrict__ ba1, const float* __restrict__ ba2,
                             float* __restrict__ pm, float* __restrict__ ps,
                             float* __restrict__ pcm, float* __restrict__ pcq) {
    __shared__ __align__(16) char smem[73728];
    ushort_t* hs_ = (ushort_t*)smem;               // [148][64] rows t0-10..t0+137
    ushort_t* ss_ = (ushort_t*)smem;               // s/i3 [144][128] (hs dead first)
    ushort_t* i1s = (ushort_t*)(smem + 36864);     // i1 [144][128]
    ushort_t* vs_ = (ushort_t*)(smem + 36864);     // v [128][64] (i1 dead)

    const int tid  = threadIdx.x;
    const int lane = tid & 63;
    const int wid  = tid >> 6;            // 0..7
    const int l16  = lane & 15, l4 = lane >> 4;
    const int ch   = blockIdx.x;
    const int b    = blockIdx.y;
    const int t0   = ch * 128;

    // ---- stage h rows [t0-10, t0+138): 148 rows x 64ch, (r&7) pre-swizzle ----
    const long long rowbase_h = ((long long)b*T_ + (t0 - 10)) * 64;
    for (int c0 = wid*64; c0 < 1280; c0 += 512) {  // 1184 real chunks, pad 1280
        int ck = c0 + lane;
        int r  = ck >> 3;
        int sc = ck ^ (r & 7);
        gload16(Hs + rowbase_h + (long long)sc*8, (char*)hs_ + (size_t)c0*16);
    }
    __syncthreads();
    if (t0 < 10 || t0 + 138 > T_) {                // zero OOB-global h rows
        for (int idx = tid; idx < 148*64/4; idx += 512) {
            int e = idx << 2;
            int r = e >> 6, ci = e & 63;
            int t = t0 - 10 + r;
            if (t < 0 || t >= T_) {
                unsigned byte = ((unsigned)(r*64 + ci))*2u ^ ((unsigned)((r & 7) << 4));
                *(uint2*)((char*)hs_ + byte) = make_uint2(0u, 0u);
            }
        }
        __syncthreads();
    }

    // ---- phase 0: conv1 over 144 i1 rows (reads hs) -> i1s (OOB t -> 0) ----
    {
        f32x4 acc[9];
        const f32x4 z = {0.f,0.f,0.f,0.f};
#pragma unroll
        for (int m = 0; m < 9; ++m) acc[m] = z;
#pragma unroll
        for (int k = 0; k < 3; ++k) {
#pragma unroll
            for (int cb = 0; cb < 2; ++cb) {
                size_t off = ((((size_t)k*2 + cb)*8 + wid)*64 + lane)*8;
                bf16x8 bh = *(const bf16x8*)(W1h + off);
                bf16x8 bl = *(const bf16x8*)(W1l + off);
#pragma unroll
                for (int m = 0; m < 9; ++m) {
                    int r = m*16 + l16 + 2*k;          // hs row, in [0,147]
                    unsigned byte = ((unsigned)(r*64 + cb*32 + l4*8))*2u
                                  ^ ((unsigned)((r & 7) << 4));
                    bf16x8 ah = *(const bf16x8*)((const char*)hs_ + byte);
                    acc[m] = __builtin_amdgcn_mfma_f32_16x16x32_bf16(ah, bh, acc[m], 0, 0, 0);
                    acc[m] = __builtin_amdgcn_mfma_f32_16x16x32_bf16(ah, bl, acc[m], 0, 0, 0);
                }
            }
        }
        const int c = wid*16 + l16;
        const float bv = bc1[c];
#pragma unroll
        for (int m = 0; m < 9; ++m) {
#pragma unroll
            for (int rg = 0; rg < 4; ++rg) {
                int rl = m*16 + l4*4 + rg;             // i1 local row 0..143
                int t  = t0 - 8 + rl;
                float v = (t >= 0 && t < T_) ? (acc[m][rg] + bv) : 0.0f;
                unsigned byte = ((unsigned)(rl*128 + c))*2u ^ ((unsigned)((rl & 15) << 4));
                *(ushort_t*)((char*)i1s + byte) = f2bf(v);
            }
        }
    }
    __syncthreads();                       // hs reads done; i1s ready

    // ---- phase 1: conv2 over all 144 local rows -> s = conv2 + bc2 + 2*i1 ----
    {
        f32x4 acc[9];
        const f32x4 z = {0.f,0.f,0.f,0.f};
#pragma unroll
        for (int m = 0; m < 9; ++m) acc[m] = z;
#pragma unroll
        for (int k = 0; k < 3; ++k) {
#pragma unroll
            for (int cb = 0; cb < 4; ++cb) {
                size_t off = ((((size_t)k*4 + cb)*8 + wid)*64 + lane)*8;
                bf16x8 bh = *(const bf16x8*)(W2h + off);
                bf16x8 bl = *(const bf16x8*)(W2l + off);
#pragma unroll
                for (int m = 0; m < 9; ++m) {
                    int r = m*16 + l16 + k*3 - 3;
                    r = min(max(r, 0), 143);  // garbage edge rows; never consumed
                    unsigned byte = ((unsigned)(r*128 + cb*32 + l4*8))*2u
                                  ^ ((unsigned)((r & 15) << 4));
                    bf16x8 ah = *(const bf16x8*)((const char*)i1s + byte);
                    acc[m] = __builtin_amdgcn_mfma_f32_16x16x32_bf16(ah, bh, acc[m], 0, 0, 0);
                    acc[m] = __builtin_amdgcn_mfma_f32_16x16x32_bf16(ah, bl, acc[m], 0, 0, 0);
                }
            }
        }
        const int c = wid*16 + l16;
        const float bv = bc2[c];
#pragma unroll
        for (int m = 0; m < 9; ++m) {
#pragma unroll
            for (int rg = 0; rg < 4; ++rg) {
                int rl = m*16 + l4*4 + rg;
                int t  = t0 - 8 + rl;
                float v = 0.0f;
                unsigned byte = ((unsigned)(rl*128 + c))*2u ^ ((unsigned)((rl & 15) << 4));
                if (t >= 0 && t < T_) {
                    float cen = bf2f(*(const ushort_t*)((const char*)i1s + byte));
                    v = acc[m][rg] + bv + 2.0f*cen;
                }
                *(ushort_t*)((char*)ss_ + byte) = f2bf(v);
            }
        }
    }
    __syncthreads();

    // ---- phase 2: conv3 + residual into REGISTERS (reads s) ----
    float i3r[8][4];
    {
        f32x4 acc[8];
        const f32x4 z = {0.f,0.f,0.f,0.f};
#pragma unroll
        for (int m = 0; m < 8; ++m) acc[m] = z;
#pragma unroll
        for (int k = 0; k < 3; ++k) {
#pragma unroll
            for (int cb = 0; cb < 4; ++cb) {
                size_t off = ((((size_t)k*4 + cb)*8 + wid)*64 + lane)*8;
                bf16x8 bh = *(const bf16x8*)(W3h + off);
                bf16x8 bl = *(const bf16x8*)(W3l + off);
#pragma unroll
                for (int m = 0; m < 8; ++m) {
                    int r = 8 + m*16 + l16 + k*4 - 4;  // in [4,139]
                    unsigned byte = ((unsigned)(r*128 + cb*32 + l4*8))*2u
                                  ^ ((unsigned)((r & 15) << 4));
                    bf16x8 ah = *(const bf16x8*)((const char*)ss_ + byte);
                    acc[m] = __builtin_amdgcn_mfma_f32_16x16x32_bf16(ah, bh, acc[m], 0, 0, 0);
                    acc[m] = __builtin_amdgcn_mfma_f32_16x16x32_bf16(ah, bl, acc[m], 0, 0, 0);
                }
            }
        }
        const int c = wid*16 + l16;
        const float bv = bc3[c];
#pragma unroll
        for (int m = 0; m < 8; ++m)
#pragma unroll
            for (int rg = 0; rg < 4; ++rg) {
                int rl = 8 + m*16 + l4*4 + rg;         // in [8,136)
                unsigned byte = ((unsigned)(rl*128 + c))*2u ^ ((unsigned)((rl & 15) << 4));
                float cen = bf2f(*(const ushort_t*)((const char*)ss_ + byte));
                i3r[m][rg] = acc[m][rg] + bv + cen;
            }
    }
    __syncthreads();                       // all s reads complete
    // write i3 over s (rows [8,136) = t [t0, t0+128))
    {
        const int c = wid*16 + l16;
#pragma unroll
        for (int m = 0; m < 8; ++m)
#pragma unroll
            for (int rg = 0; rg < 4; ++rg) {
                int rl = 8 + m*16 + l4*4 + rg;
                unsigned byte = ((unsigned)(rl*128 + c))*2u ^ ((unsigned)((rl & 15) << 4));
                *(ushort_t*)((char*)ss_ + byte) = f2bf(i3r[m][rg]);
            }
    }
    __syncthreads();                       // i3 tile ready (i1 dead)

    // ---- ASP stage 1: v = tanh(i3 @ wa1^T + ba1)  (wave: rowhalf x coltile) ----
    {
        const int wy = wid >> 2;          // 0..1: rows wy*64 + m*16
        const int wx = wid & 3;           // 0..3: cols wx*16
        f32x4 acc1[4];
        const f32x4 z = {0.f,0.f,0.f,0.f};
#pragma unroll
        for (int m = 0; m < 4; ++m) acc1[m] = z;
#pragma unroll
        for (int kc = 0; kc < 4; ++kc) {
            size_t off = (((size_t)kc*4 + wx)*64 + lane)*8;
            bf16x8 bh = *(const bf16x8*)(Wa1h + off);
            bf16x8 bl = *(const bf16x8*)(Wa1l + off);
#pragma unroll
            for (int m = 0; m < 4; ++m) {
                int rl = 8 + wy*64 + m*16 + l16;       // i3 row
                unsigned byte = ((unsigned)(rl*128 + kc*32 + l4*8))*2u
                              ^ ((unsigned)((rl & 15) << 4));
                bf16x8 ah = *(const bf16x8*)((const char*)ss_ + byte);
                acc1[m] = __builtin_amdgcn_mfma_f32_16x16x32_bf16(ah, bh, acc1[m], 0, 0, 0);
                acc1[m] = __builtin_amdgcn_mfma_f32_16x16x32_bf16(ah, bl, acc1[m], 0, 0, 0);
            }
        }
        const int c = wx*16 + l16;
        const float bv = ba1[c];
#pragma unroll
        for (int m = 0; m < 4; ++m)
#pragma unroll
            for (int rg = 0; rg < 4; ++rg) {
                float v = fast_tanh(acc1[m][rg] + bv);
                int r = wy*64 + m*16 + l4*4 + rg;      // t row in [0,128)
                unsigned byte = ((unsigned)(r*64 + c))*2u ^ ((unsigned)((r & 7) << 4));
                *(ushort_t*)((char*)vs_ + byte) = f2bf(v);
            }
    }
    __syncthreads();

    // ---- ASP stage 2 + softmax partials + weighted stats ----
    {
        f32x4 acc2[8];
        const f32x4 z = {0.f,0.f,0.f,0.f};
#pragma unroll
        for (int j = 0; j < 8; ++j) acc2[j] = z;
#pragma unroll
        for (int kc = 0; kc < 2; ++kc) {
            size_t off = (((size_t)kc*8 + wid)*64 + lane)*8;
            bf16x8 awh = *(const bf16x8*)(Wa2h + off);
            bf16x8 awl = *(const bf16x8*)(Wa2l + off);
#pragma unroll
            for (int j = 0; j < 8; ++j) {
                int t = j*16 + l16;
                unsigned byte = ((unsigned)(t*64 + kc*32 + l4*8))*2u
                              ^ ((unsigned)((t & 7) << 4));
                bf16x8 bv_ = *(const bf16x8*)((const char*)vs_ + byte);
                acc2[j] = __builtin_amdgcn_mfma_f32_16x16x32_bf16(awh, bv_, acc2[j], 0, 0, 0);
                acc2[j] = __builtin_amdgcn_mfma_f32_16x16x32_bf16(awl, bv_, acc2[j], 0, 0, 0);
            }
        }
        const float4 bvv = *(const float4*)&ba2[wid*16 + l4*4];
        const float bva[4] = {bvv.x, bvv.y, bvv.z, bvv.w};
#pragma unroll
        for (int rg = 0; rg < 4; ++rg) {
            const int n = wid*16 + l4*4 + rg;
            float mx = -INFINITY;
#pragma unroll
            for (int j = 0; j < 8; ++j) {
                int tg = t0 + j*16 + l16;
                if (tg < T_) mx = fmaxf(mx, acc2[j][rg] + bva[rg]);
            }
            mx = fmaxf(mx, __shfl_xor(mx, 1));
            mx = fmaxf(mx, __shfl_xor(mx, 2));
            mx = fmaxf(mx, __shfl_xor(mx, 4));
            mx = fmaxf(mx, __shfl_xor(mx, 8));
            float se = 0.0f, am = 0.0f, aq = 0.0f;
#pragma unroll
            for (int j = 0; j < 8; ++j) {
                int tl = j*16 + l16;
                int tg = t0 + tl;
                if (tg < T_) {
                    float p = __expf(acc2[j][rg] + bva[rg] - mx);
                    int rl = tl + 8;
                    unsigned byte = ((unsigned)(rl*128 + n))*2u ^ ((unsigned)((rl & 15) << 4));
                    float x = bf2f(*(const ushort_t*)((const char*)ss_ + byte));
                    se += p; am += p*x; aq += p*x*x;
                }
            }
#pragma unroll
            for (int d = 1; d <= 8; d <<= 1) {
                se += __shfl_xor(se, d);
                am += __shfl_xor(am, d);
                aq += __shfl_xor(aq, d);
            }
            if (l16 == 0) {
                size_t o = ((size_t)b*NCH + ch)*128 + n;
                pm[o]  = mx;
                ps[o]  = se;
                pcm[o] = am;
                pcq[o] = aq;
            }
        }
    }
}

// ---------------------------------------------------------------------------
// final: global softmax combine + stats + layernorm(256) + coalesced linear.
__launch_bounds__(256)
__global__ void final_kernel(const float* __restrict__ pcm, const float* __restrict__ pcq,
                             const float* __restrict__ pm, const float* __restrict__ ps,
                             const float* __restrict__ gamma, const float* __restrict__ beta,
                             const float* __restrict__ w2t, const float* __restrict__ b2,
                             float* __restrict__ out) {
    __shared__ float row[256];
    __shared__ float nrm[256];
    __shared__ float red[8];
    const int tid = threadIdx.x, b = blockIdx.x;
    if (tid < 128) {
        float M = -INFINITY;
        for (int ch = 0; ch < NCH; ++ch)
            M = fmaxf(M, pm[((size_t)b*NCH + ch)*128 + tid]);
        float S = 0.0f, sm = 0.0f, sq = 0.0f;
        for (int ch = 0; ch < NCH; ++ch) {
            size_t o = ((size_t)b*NCH + ch)*128 + tid;
            float m = pm[o];
            if (m > -INFINITY) {
                float e = expf(m - M);
                S  += ps[o]*e;
                sm += pcm[o]*e;
                sq += pcq[o]*e;
            }
        }
        float mean = sm / S;
        float q    = sq / S;
        float resid = q - mean*mean;
        float stdv  = sqrtf(fmaxf(resid, 1e-9f));
        row[tid]       = mean;
        row[128 + tid] = stdv;
    }
    __syncthreads();
    float v  = row[tid];
    float s1 = v, s2 = v*v;
    for (int off = 32; off >= 1; off >>= 1) {
        s1 += __shfl_down(s1, off, 64);
        s2 += __shfl_down(s2, off, 64);
    }
    if ((tid & 63) == 0) { red[tid >> 6] = s1; red[4 + (tid >> 6)] = s2; }
    __syncthreads();
    float S1 = red[0] + red[1] + red[2] + red[3];
    float S2 = red[4] + red[5] + red[6] + red[7];
    float mu  = S1 / 256.0f;
    float var = S2 / 256.0f - mu*mu;
    float inv = 1.0f / sqrtf(var + 1e-5f);
    nrm[tid] = (v - mu)*inv*gamma[tid] + beta[tid];
    __syncthreads();
    float acc0 = b2[tid], acc1 = b2[tid + 256];
#pragma unroll 4
    for (int j = 0; j < 256; ++j) {
        float nv = nrm[j];
        const float* wr = w2t + (size_t)j*512;
        acc0 += wr[tid]       * nv;
        acc1 += wr[tid + 256] * nv;
    }
    out[(size_t)b*512 + tid]       = acc0;
    out[(size_t)b*512 + tid + 256] = acc1;
}

// ---------------------------------------------------------------------------
extern "C" void kernel_launch(void* const* d_in, const int* in_sizes, int n_in,
                              void* d_out, int out_size, void* d_ws, size_t ws_size,
                              hipStream_t stream) {
    const float* x      = (const float*)d_in[0];
    const float* bp     = (const float*)d_in[1];
    const float* w_lin1 = (const float*)d_in[2];
    const float* b_lin1 = (const float*)d_in[3];
    const float* wc1    = (const float*)d_in[4];
    const float* bc1    = (const float*)d_in[5];
    const float* wc2    = (const float*)d_in[6];
    const float* bc2    = (const float*)d_in[7];
    const float* wc3    = (const float*)d_in[8];
    const float* bc3    = (const float*)d_in[9];
    const float* wa1    = (const float*)d_in[10];
    const float* ba1    = (const float*)d_in[11];
    const float* wa2    = (const float*)d_in[12];
    const float* ba2    = (const float*)d_in[13];
    const float* gamma  = (const float*)d_in[14];
    const float* beta   = (const float*)d_in[15];
    const float* wl2    = (const float*)d_in[16];
    const float* bl2    = (const float*)d_in[17];

    float* ws   = (float*)d_ws;
    float* bs   = ws + OFF_BS;
    ushort_t* weh  = (ushort_t*)(ws + OFF_WEFF);
    ushort_t* wel  = weh + 64*320;
    float* wtail   = ws + OFF_WTAIL;
    ushort_t* w1h  = (ushort_t*)(ws + OFF_W1);
    ushort_t* w1l  = w1h + 3*128*64;
    ushort_t* w2h  = (ushort_t*)(ws + OFF_W2);
    ushort_t* w2l  = w2h + 3*128*128;
    ushort_t* w3h  = (ushort_t*)(ws + OFF_W3);
    ushort_t* w3l  = w3h + 3*128*128;
    ushort_t* wa1h = (ushort_t*)(ws + OFF_WA1);
    ushort_t* wa1l = wa1h + 64*128;
    ushort_t* wa2h = (ushort_t*)(ws + OFF_WA2);
    ushort_t* wa2l = wa2h + 128*64;
    float* pm   = ws + OFF_PM;
    float* ps   = ws + OFF_PS;
    float* pcm  = ws + OFF_PCM;
    float* pcq  = ws + OFF_PCQ;
    ushort_t* Hs = (ushort_t*)(ws + OFF_HS);
    float* wl2t  = ws + OFF_WL2T;

    sort_kernel<<<dim3(1), dim3(64), 0, stream>>>(bp, bs);
    prep_kernel<<<dim3(1136), dim3(256), 0, stream>>>(bs, w_lin1, wc1, wc2, wc3, wa1, wa2,
                                                      wl2, weh, wel, wtail, w1h, w1l,
                                                      w2h, w2l, w3h, w3l, wa1h, wa1l,
                                                      wa2h, wa2l, wl2t);
    // h = relu(x @ Weff^T + b_lin1) -> single bf16 plane
    lin1_mfma<<<dim3(R_/128), dim3(256), 0, stream>>>(x, weh, wel, wtail, b_lin1, Hs);
    // conv1+conv2+conv3+ASP fused, per (128-chunk, b); i1 and i3 never leave LDS
    dconv123_asp<<<dim3(NCH, B_), dim3(512), 0, stream>>>(Hs, w1h, w1l, w2h, w2l,
                                                          w3h, w3l, bc1, bc2, bc3,
                                                          wa1h, wa1l, wa2h, wa2l,
                                                          ba1, ba2, pm, ps, pcm, pcq);
    // global combine + stats + LN + coalesced 256->512 linear
    final_kernel<<<dim3(B_), dim3(256), 0, stream>>>(pcm, pcq, pm, ps, gamma, beta,
                                                     wl2t, bl2, (float*)d_out);
}